// Round 1
// baseline (1028.893 us; speedup 1.0000x reference)
//
#include <hip/hip_runtime.h>
#include <math.h>

// ---------------- constants ----------------
constexpr int kT   = 2048;
constexpr int kHID = 1024;
constexpr int kH   = 16;
constexpr int kD   = 64;
constexpr int kNB  = 32;

__device__ __forceinline__ float wred_sum(float v) {
#pragma unroll
  for (int m = 1; m < 64; m <<= 1) v += __shfl_xor(v, m, 64);
  return v;
}
__device__ __forceinline__ float wred_max(float v) {
#pragma unroll
  for (int m = 1; m < 64; m <<= 1) v = fmaxf(v, __shfl_xor(v, m, 64));
  return v;
}

// ---------------- GEMM: C(M,N) = A(M,K) @ B(K,N), fp32, 64x64 tile ----------------
__global__ __launch_bounds__(256) void gemm_64x64(const float* __restrict__ A,
                                                  const float* __restrict__ B,
                                                  float* __restrict__ C,
                                                  int M, int N, int K) {
  __shared__ float As[16][68];  // [k][m], pad 68 keeps float4 alignment, 2-way banks (free)
  __shared__ float Bs[16][68];  // [k][n]
  const int bm = blockIdx.y * 64, bn = blockIdx.x * 64;
  const int tid = threadIdx.x;
  const int tx = tid & 15, ty = tid >> 4;
  const int ar = tid >> 2, ac = (tid & 3) << 2;   // A tile loader: row, col4
  const int br = tid >> 4, bc2 = (tid & 15) << 2; // B tile loader
  float acc[4][4] = {};
  for (int k0 = 0; k0 < K; k0 += 16) {
    float4 av = *(const float4*)(A + (size_t)(bm + ar) * K + k0 + ac);
    float4 bv = *(const float4*)(B + (size_t)(k0 + br) * N + bn + bc2);
    As[ac + 0][ar] = av.x; As[ac + 1][ar] = av.y;
    As[ac + 2][ar] = av.z; As[ac + 3][ar] = av.w;
    *(float4*)(&Bs[br][bc2]) = bv;
    __syncthreads();
#pragma unroll
    for (int kk = 0; kk < 16; ++kk) {
      float4 a4 = *(const float4*)(&As[kk][ty << 2]);
      float4 b4 = *(const float4*)(&Bs[kk][tx << 2]);
      acc[0][0] += a4.x * b4.x; acc[0][1] += a4.x * b4.y; acc[0][2] += a4.x * b4.z; acc[0][3] += a4.x * b4.w;
      acc[1][0] += a4.y * b4.x; acc[1][1] += a4.y * b4.y; acc[1][2] += a4.y * b4.z; acc[1][3] += a4.y * b4.w;
      acc[2][0] += a4.z * b4.x; acc[2][1] += a4.z * b4.y; acc[2][2] += a4.z * b4.z; acc[2][3] += a4.z * b4.w;
      acc[3][0] += a4.w * b4.x; acc[3][1] += a4.w * b4.y; acc[3][2] += a4.w * b4.z; acc[3][3] += a4.w * b4.w;
    }
    __syncthreads();
  }
#pragma unroll
  for (int i = 0; i < 4; ++i) {
    float4 r = make_float4(acc[i][0], acc[i][1], acc[i][2], acc[i][3]);
    *(float4*)(C + (size_t)(bm + ty * 4 + i) * N + bn + tx * 4) = r;
  }
}

// ---------------- strategy: sigmoid(x @ Ws + bs), (T,48) ----------------
__global__ __launch_bounds__(256) void strat_kernel(const float* __restrict__ x,
                                                    const float* __restrict__ Wsp,
                                                    const float* __restrict__ bsp,
                                                    float* __restrict__ strat) {
  int idx = blockIdx.x * 256 + threadIdx.x;   // 0..98303
  int t = idx / 48, n = idx - t * 48;
  float acc = bsp[n];
#pragma unroll 4
  for (int c = 0; c < kHID; ++c) acc += x[(size_t)t * kHID + c] * Wsp[(size_t)c * 48 + n];
  strat[idx] = 1.f / (1.f + __expf(-acc));
}

// ---------------- compression: kc/vc = gelu(blk_vec @ Wc + bc) ----------------
__global__ __launch_bounds__(256) void compress_kernel(const float* __restrict__ kk,
                                                       const float* __restrict__ vv,
                                                       const float* __restrict__ Wc,
                                                       const float* __restrict__ bc,
                                                       float* __restrict__ kc,
                                                       float* __restrict__ vc) {
  const int blk = blockIdx.x, h = blockIdx.y;
  const float* src = blockIdx.z ? vv : kk;
  float* dst = blockIdx.z ? vc : kc;
  const int lane = threadIdx.x & 63, g = threadIdx.x >> 6;
  float acc = 0.f;
#pragma unroll 4
  for (int kidx = g * 1024; kidx < (g + 1) * 1024; ++kidx) {
    int s = kidx >> 6, dd = kidx & 63;
    float a = src[((size_t)blk * 64 + s) * kHID + h * 64 + dd];  // broadcast
    acc += a * Wc[(size_t)kidx * 64 + lane];                     // coalesced
  }
  __shared__ float red[4][64];
  red[g][lane] = acc;
  __syncthreads();
  if (threadIdx.x < 64) {
    float sum = red[0][lane] + red[1][lane] + red[2][lane] + red[3][lane] + bc[lane];
    float gel = 0.5f * sum * (1.f + erff(sum * 0.70710678118654752f));
    dst[((size_t)h * kNB + blk) * 64 + lane] = gel;
  }
}

// ---------------- sliding-window attention; merged = st0 * slide ----------------
__global__ __launch_bounds__(256) void sliding_kernel(const float* __restrict__ q,
                                                      const float* __restrict__ k,
                                                      const float* __restrict__ v,
                                                      const float* __restrict__ strat,
                                                      float* __restrict__ merged) {
  __shared__ float kw[128][65];  // prev||cur window keys, pad 65: conflict-free scalar
  __shared__ float qs[64][68];   // pad 68: float4-aligned broadcast reads
  const int win = blockIdx.x, h = blockIdx.y;
  const int tid = threadIdx.x;
  {
    int j = tid >> 1, dh = (tid & 1) * 32;
    int t = (win - 1) * 64 + j;          // j<64 -> prev window, j>=64 -> cur window
    bool valid = (t >= 0);
#pragma unroll
    for (int i = 0; i < 8; ++i) {
      float4 val = valid ? *(const float4*)(k + (size_t)t * kHID + h * 64 + dh + i * 4)
                         : make_float4(0.f, 0.f, 0.f, 0.f);
      kw[j][dh + i * 4 + 0] = val.x; kw[j][dh + i * 4 + 1] = val.y;
      kw[j][dh + i * 4 + 2] = val.z; kw[j][dh + i * 4 + 3] = val.w;
    }
    int r = tid >> 2, c0 = (tid & 3) * 16;
#pragma unroll
    for (int i = 0; i < 4; ++i)
      *(float4*)(&qs[r][c0 + i * 4]) =
          *(const float4*)(q + (size_t)(win * 64 + r) * kHID + h * 64 + c0 + i * 4);
  }
  __syncthreads();
  const int wid = tid >> 6, lane = tid & 63;
  const float* vp = v + h * 64 + lane;
  for (int i = 0; i < 16; ++i) {
    const int rr = wid * 16 + i;
    const int t = win * 64 + rr;
    float s0 = 0.f, s1 = 0.f;
#pragma unroll
    for (int d4 = 0; d4 < 16; ++d4) {
      float4 q4 = *(const float4*)(&qs[rr][d4 * 4]);
      s0 += q4.x * kw[lane][d4 * 4 + 0] + q4.y * kw[lane][d4 * 4 + 1] +
            q4.z * kw[lane][d4 * 4 + 2] + q4.w * kw[lane][d4 * 4 + 3];
      s1 += q4.x * kw[lane + 64][d4 * 4 + 0] + q4.y * kw[lane + 64][d4 * 4 + 1] +
            q4.z * kw[lane + 64][d4 * 4 + 2] + q4.w * kw[lane + 64][d4 * 4 + 3];
    }
    s0 *= 0.125f; s1 *= 0.125f;
    if (win == 0) s0 = -1e30f;           // prev window out of range
    if (lane > rr) s1 = -1e30f;          // causal within window
    float mx = wred_max(fmaxf(s0, s1));
    float e0 = __expf(s0 - mx), e1 = __expf(s1 - mx);
    float l = wred_sum(e0 + e1);
    float o = 0.f;
#pragma unroll 8
    for (int j = 0; j < 64; ++j) {
      float p0 = __shfl(e0, j, 64);
      float p1 = __shfl(e1, j, 64);
      int t0 = (win - 1) * 64 + j; if (t0 < 0) t0 = 0;  // p0==0 there
      o += p0 * vp[(size_t)t0 * kHID];
      o += p1 * vp[(size_t)(win * 64 + j) * kHID];
    }
    o /= l;
    merged[(size_t)t * kHID + h * 64 + lane] = strat[t * 48 + h * 3 + 0] * o;
  }
}

// ------- importance (H,T,NB) + compressed attention; merged += st1 * comp -------
__global__ __launch_bounds__(256) void impcomp_kernel(const float* __restrict__ q,
                                                      const float* __restrict__ kc,
                                                      const float* __restrict__ vc,
                                                      const float* __restrict__ strat,
                                                      float* __restrict__ imp,
                                                      float* __restrict__ merged) {
  const int gw = blockIdx.x * 4 + (threadIdx.x >> 6);  // 0..32767
  const int lane = threadIdx.x & 63;
  const int h = gw >> 11, t = gw & 2047;
  const float qv = q[(size_t)t * kHID + h * 64 + lane];
  float sj[32];
  float myimp = 0.f;
#pragma unroll
  for (int j = 0; j < 32; ++j) {
    float p = qv * kc[(h * kNB + j) * 64 + lane];
    p = wred_sum(p) * 0.125f;
    sj[j] = p;
    if (lane == j) myimp = p;
  }
  if (lane < 32) imp[((size_t)h * kT + t) * kNB + lane] = myimp;
  float mx = sj[0];
#pragma unroll
  for (int j = 1; j < 32; ++j) mx = fmaxf(mx, sj[j]);
  float lsum = 0.f;
#pragma unroll
  for (int j = 0; j < 32; ++j) { sj[j] = __expf(sj[j] - mx); lsum += sj[j]; }
  float inv = 1.f / lsum;
  float o = 0.f;
#pragma unroll
  for (int j = 0; j < 32; ++j) o += sj[j] * vc[(h * kNB + j) * 64 + lane];
  o *= inv;
  merged[(size_t)t * kHID + h * 64 + lane] += strat[t * 48 + h * 3 + 1] * o;
}

// ------- block scores -> softmax/entropy/dynamic_k/top-k mask per (h,qblk) -------
__global__ __launch_bounds__(256) void blocksel_kernel(const float* __restrict__ imp,
                                                       const float* __restrict__ kscale_p,
                                                       const float* __restrict__ kbias_p,
                                                       unsigned* __restrict__ maskb,
                                                       float* __restrict__ krb,
                                                       float* __restrict__ neb,
                                                       int* __restrict__ dkb) {
  const int gw = blockIdx.x * 4 + (threadIdx.x >> 6);  // 0..511
  const int lane = threadIdx.x & 63;
  const int h = gw >> 5, qb = gw & 31;
  const int j = lane & 31, half = lane >> 5;
  float acc = 0.f;
#pragma unroll 4
  for (int s2 = 0; s2 < 32; ++s2) {
    int s = half * 32 + s2;
    acc += imp[((size_t)h * kT + qb * 64 + s) * kNB + j];
  }
  acc += __shfl_xor(acc, 32, 64);
  float bsj = acc * (1.f / 64.f);
  // softmax over the 32-group (both halves hold identical data)
  float mx = bsj;
#pragma unroll
  for (int m = 1; m < 32; m <<= 1) mx = fmaxf(mx, __shfl_xor(mx, m, 64));
  float e = expf(bsj - mx);
  float lsum = e;
#pragma unroll
  for (int m = 1; m < 32; m <<= 1) lsum += __shfl_xor(lsum, m, 64);
  float p = e / lsum;
  float ent = p * logf(p + 1e-9f);
#pragma unroll
  for (int m = 1; m < 32; m <<= 1) ent += __shfl_xor(ent, m, 64);
  ent = -ent;
  float ne = ent / (logf(32.f) + 1e-9f);
  float kr = 1.f / (1.f + expf(-(kscale_p[0] * ne + kbias_p[0])));
  int dk = (int)fminf(fmaxf(8.f * kr, 1.f), 8.f);   // trunc like torch .long()
  unsigned mword = 1u << qb;                        // diagonal always selected
  int taken = 0;
  for (int r = 0; r < dk; ++r) {
    float v2 = taken ? -3.4e38f : bsj;
    int idx2 = j;
#pragma unroll
    for (int m = 1; m < 32; m <<= 1) {
      float ov = __shfl_xor(v2, m, 64);
      int oi = __shfl_xor(idx2, m, 64);
      if (ov > v2 || (ov == v2 && oi < idx2)) { v2 = ov; idx2 = oi; }
    }
    mword |= (1u << idx2);
    if (j == idx2) taken = 1;
  }
  if (lane == 0) {
    maskb[h * kNB + qb] = mword;
    krb[h * kNB + qb] = kr;
    neb[h * kNB + qb] = ne;
    dkb[h * kNB + qb] = dk;
  }
}

// ---------------- scalar outputs: avg_k, aux_loss ----------------
__global__ void finalize_kernel(const int* __restrict__ dkb, const float* __restrict__ krb,
                                const float* __restrict__ neb, float* __restrict__ out) {
  __shared__ float s1[512], s2[512], s3[512];
  int t2 = threadIdx.x;
  float fdk = (float)dkb[t2], kr = krb[t2], ne = neb[t2];
  float d = kr - ne;
  s1[t2] = fdk; s2[t2] = d * d; s3[t2] = kr;
  __syncthreads();
  for (int st = 256; st > 0; st >>= 1) {
    if (t2 < st) { s1[t2] += s1[t2 + st]; s2[t2] += s2[t2 + st]; s3[t2] += s3[t2 + st]; }
    __syncthreads();
  }
  if (t2 == 0) {
    out[(size_t)kT * kHID + 0] = s1[0] * (1.f / 512.f);
    out[(size_t)kT * kHID + 1] = 0.01f * (s2[0] * (1.f / 512.f)) + 0.01f * (s3[0] * (1.f / 512.f));
  }
}

// ------- block-sparse fine attention (online softmax); merged += st2 * fine -------
__global__ __launch_bounds__(256) void fine_kernel(const float* __restrict__ q,
                                                   const float* __restrict__ k,
                                                   const float* __restrict__ v,
                                                   const float* __restrict__ strat,
                                                   const unsigned* __restrict__ maskb,
                                                   float* __restrict__ merged) {
  __shared__ float kb[64][65], vb[64][65];
  __shared__ float qs[64][68];
  const int qb = blockIdx.x, h = blockIdx.y;
  const int tid = threadIdx.x;
  const unsigned mword = maskb[h * kNB + qb];
  {
    int r = tid >> 2, c0 = (tid & 3) * 16;
#pragma unroll
    for (int i = 0; i < 4; ++i)
      *(float4*)(&qs[r][c0 + i * 4]) =
          *(const float4*)(q + (size_t)(qb * 64 + r) * kHID + h * 64 + c0 + i * 4);
  }
  const int wid = tid >> 6, lane = tid & 63;
  float m[16], l[16], o[16];
#pragma unroll
  for (int i = 0; i < 16; ++i) { m[i] = -1e30f; l[i] = 0.f; o[i] = 0.f; }
  for (int jb = 0; jb < 32; ++jb) {
    if (!((mword >> jb) & 1u)) continue;   // uniform across block
    __syncthreads();                       // protect kb/vb (and covers qs on first pass)
    {
      int r = tid >> 2, c0 = (tid & 3) * 16;
#pragma unroll
      for (int i2 = 0; i2 < 4; ++i2) {
        float4 kv4 = *(const float4*)(k + (size_t)(jb * 64 + r) * kHID + h * 64 + c0 + i2 * 4);
        float4 vv4 = *(const float4*)(v + (size_t)(jb * 64 + r) * kHID + h * 64 + c0 + i2 * 4);
        kb[r][c0 + i2 * 4 + 0] = kv4.x; kb[r][c0 + i2 * 4 + 1] = kv4.y;
        kb[r][c0 + i2 * 4 + 2] = kv4.z; kb[r][c0 + i2 * 4 + 3] = kv4.w;
        vb[r][c0 + i2 * 4 + 0] = vv4.x; vb[r][c0 + i2 * 4 + 1] = vv4.y;
        vb[r][c0 + i2 * 4 + 2] = vv4.z; vb[r][c0 + i2 * 4 + 3] = vv4.w;
      }
    }
    __syncthreads();
#pragma unroll
    for (int i = 0; i < 16; ++i) {
      const int rr = wid * 16 + i;
      float s = 0.f;
#pragma unroll
      for (int d4 = 0; d4 < 16; ++d4) {
        float4 q4 = *(const float4*)(&qs[rr][d4 * 4]);
        s += q4.x * kb[lane][d4 * 4 + 0] + q4.y * kb[lane][d4 * 4 + 1] +
             q4.z * kb[lane][d4 * 4 + 2] + q4.w * kb[lane][d4 * 4 + 3];
      }
      s *= 0.125f;
      float bm = wred_max(s);
      float mn = fmaxf(m[i], bm);
      float corr = __expf(m[i] - mn);
      float e = __expf(s - mn);
      float ls = wred_sum(e);
      l[i] = l[i] * corr + ls;
      m[i] = mn;
      float acc = 0.f;
#pragma unroll 16
      for (int j2 = 0; j2 < 64; ++j2) {
        float pj = __shfl(e, j2, 64);
        acc += pj * vb[j2][lane];
      }
      o[i] = o[i] * corr + acc;
    }
  }
#pragma unroll
  for (int i = 0; i < 16; ++i) {
    const int rr = wid * 16 + i;
    const int t = qb * 64 + rr;
    merged[(size_t)t * kHID + h * 64 + lane] += strat[t * 48 + h * 3 + 2] * (o[i] / l[i]);
  }
}

// ---------------- launch ----------------
extern "C" void kernel_launch(void* const* d_in, const int* in_sizes, int n_in,
                              void* d_out, int out_size, void* d_ws, size_t ws_size,
                              hipStream_t stream) {
  const float* x      = (const float*)d_in[0];
  const float* Wq     = (const float*)d_in[1];
  const float* Wk     = (const float*)d_in[2];
  const float* Wv     = (const float*)d_in[3];
  const float* Wo     = (const float*)d_in[4];
  const float* Wc     = (const float*)d_in[5];
  const float* bc     = (const float*)d_in[6];
  const float* kscale = (const float*)d_in[7];
  const float* kbias  = (const float*)d_in[8];
  const float* Wsp    = (const float*)d_in[9];
  const float* bsp    = (const float*)d_in[10];
  float* out = (float*)d_out;
  float* ws  = (float*)d_ws;

  float* q      = ws;                 // 2,097,152
  float* k      = ws + 2097152;       // 2,097,152
  float* v      = ws + 4194304;       // 2,097,152
  float* strat  = ws + 6291456;       // 98,304
  float* kc     = ws + 6389760;       // 32,768
  float* vc     = ws + 6422528;       // 32,768
  float* imp    = ws + 6455296;       // 1,048,576
  float* merged = ws + 7503872;       // 2,097,152
  unsigned* maskb = (unsigned*)(ws + 9601024);  // 512
  float* krb    = ws + 9601536;       // 512
  float* neb    = ws + 9602048;       // 512
  int*   dkb    = (int*)(ws + 9602560);         // 512

  dim3 gg(16, 32), bb(256);
  gemm_64x64<<<gg, bb, 0, stream>>>(x, Wq, q, kT, kHID, kHID);
  gemm_64x64<<<gg, bb, 0, stream>>>(x, Wk, k, kT, kHID, kHID);
  gemm_64x64<<<gg, bb, 0, stream>>>(x, Wv, v, kT, kHID, kHID);
  strat_kernel<<<384, 256, 0, stream>>>(x, Wsp, bsp, strat);
  compress_kernel<<<dim3(kNB, kH, 2), 256, 0, stream>>>(k, v, Wc, bc, kc, vc);
  sliding_kernel<<<dim3(32, kH), 256, 0, stream>>>(q, k, v, strat, merged);
  impcomp_kernel<<<8192, 256, 0, stream>>>(q, kc, vc, strat, imp, merged);
  blocksel_kernel<<<128, 256, 0, stream>>>(imp, kscale, kbias, maskb, krb, neb, dkb);
  finalize_kernel<<<1, 512, 0, stream>>>(dkb, krb, neb, out);
  fine_kernel<<<dim3(kNB, kH), 256, 0, stream>>>(q, k, v, strat, maskb, merged);
  gemm_64x64<<<gg, bb, 0, stream>>>(merged, Wo, out, kT, kHID, kHID);
}

// Round 2
// 729.588 us; speedup vs baseline: 1.4102x; 1.4102x over previous
//
#include <hip/hip_runtime.h>
#include <math.h>
#include <stdint.h>

typedef unsigned short u16;
typedef short v8s __attribute__((ext_vector_type(8)));
typedef float v4f __attribute__((ext_vector_type(4)));

constexpr int kT   = 2048;
constexpr int kHID = 1024;
constexpr int kH   = 16;
constexpr int kNB  = 32;

__device__ __forceinline__ float b2f(u16 u) { unsigned x = ((unsigned)u) << 16; return __uint_as_float(x); }
__device__ __forceinline__ u16 f2b(float f) {
  unsigned x = __float_as_uint(f);
  x += 0x7FFFu + ((x >> 16) & 1u);
  return (u16)(x >> 16);
}
__device__ __forceinline__ v4f mfma16(v8s a, v8s b, v4f c) {
  return __builtin_amdgcn_mfma_f32_16x16x32_bf16(a, b, c, 0, 0, 0);
}
__device__ __forceinline__ void gl_lds16(const void* g, void* l) {
  __builtin_amdgcn_global_load_lds((const __attribute__((address_space(1))) uint32_t*)g,
                                   (__attribute__((address_space(3))) uint32_t*)l, 16, 0, 0);
}
__device__ __forceinline__ float wred_sum(float v) {
#pragma unroll
  for (int m = 1; m < 64; m <<= 1) v += __shfl_xor(v, m, 64);
  return v;
}
__device__ __forceinline__ float wred_max(float v) {
#pragma unroll
  for (int m = 1; m < 64; m <<= 1) v = fmaxf(v, __shfl_xor(v, m, 64));
  return v;
}

// ---------------- fp32 -> (hi,lo) bf16 split ----------------
__global__ __launch_bounds__(256) void split_kernel(const float* __restrict__ in,
                                                    u16* __restrict__ hi, u16* __restrict__ lo, int n) {
  int i = blockIdx.x * 256 + threadIdx.x;
  if (i < n) {
    float x = in[i];
    u16 h = f2b(x);
    hi[i] = h;
    lo[i] = f2b(x - b2f(h));
  }
}

// ---------------- W[K][N] fp32 -> out[N][K] bf16 (hi, optional lo) ----------------
__global__ __launch_bounds__(256) void tsplit_kernel(const float* __restrict__ W,
                                                     u16* __restrict__ Hh, u16* __restrict__ Ll,
                                                     int Kd, int Nd) {
  __shared__ float t[32][33];
  const int bx = blockIdx.x * 32, by = blockIdx.y * 32;  // bx: n, by: k
  const int lx = threadIdx.x & 31, ly = threadIdx.x >> 5;
  for (int i = ly; i < 32; i += 8) t[i][lx] = W[(size_t)(by + i) * Nd + bx + lx];
  __syncthreads();
  for (int i = ly; i < 32; i += 8) {
    float x = t[lx][i];                 // = W[by+lx][bx+i]
    size_t idx = (size_t)(bx + i) * Kd + by + lx;
    u16 h = f2b(x);
    Hh[idx] = h;
    if (Ll) Ll[idx] = f2b(x - b2f(h));
  }
}

// ---- C(M,N) = A(M,K)bf16 @ Bt(N,K)bf16^T, fp32 acc; beta accumulate; optional bf16 out ----
__global__ __launch_bounds__(256) void gemm_bf16(const u16* __restrict__ A, const u16* __restrict__ Bt,
                                                 float* __restrict__ C, u16* __restrict__ Cbf,
                                                 int M, int N, int K, int beta) {
  __shared__ u16 As[64 * 64];
  __shared__ u16 Bs[64 * 64];
  const int bm = blockIdx.y * 64, bn = blockIdx.x * 64;
  const int tid = threadIdx.x;
  const int w = tid >> 6, lane = tid & 63;
  const int lg = lane >> 4, l16 = lane & 15;
  const int wr = w >> 1, wc = w & 1;
  v4f acc[2][2] = {};
  for (int k0 = 0; k0 < K; k0 += 64) {
    __syncthreads();
    {
      int s = tid, row = s >> 3, sf = (s & 7) ^ (row & 7);
      gl_lds16(A + (size_t)(bm + row) * K + k0 + sf * 8, (char*)As + s * 16);
      s = tid + 256; row = s >> 3; sf = (s & 7) ^ (row & 7);
      gl_lds16(A + (size_t)(bm + row) * K + k0 + sf * 8, (char*)As + s * 16);
      s = tid; row = s >> 3; sf = (s & 7) ^ (row & 7);
      gl_lds16(Bt + (size_t)(bn + row) * K + k0 + sf * 8, (char*)Bs + s * 16);
      s = tid + 256; row = s >> 3; sf = (s & 7) ^ (row & 7);
      gl_lds16(Bt + (size_t)(bn + row) * K + k0 + sf * 8, (char*)Bs + s * 16);
    }
    __syncthreads();
    v8s a[2][2], b[2][2];
#pragma unroll
    for (int i = 0; i < 2; ++i)
#pragma unroll
      for (int kk = 0; kk < 2; ++kk) {
        int row = wr * 32 + i * 16 + l16;
        a[i][kk] = *(const v8s*)((const char*)As + row * 128 + (((kk * 4 + lg) ^ (row & 7)) * 16));
        int col = wc * 32 + i * 16 + l16;
        b[i][kk] = *(const v8s*)((const char*)Bs + col * 128 + (((kk * 4 + lg) ^ (col & 7)) * 16));
      }
#pragma unroll
    for (int i = 0; i < 2; ++i)
#pragma unroll
      for (int j = 0; j < 2; ++j) {
        acc[i][j] = mfma16(a[i][0], b[j][0], acc[i][j]);
        acc[i][j] = mfma16(a[i][1], b[j][1], acc[i][j]);
      }
  }
#pragma unroll
  for (int i = 0; i < 2; ++i)
#pragma unroll
    for (int j = 0; j < 2; ++j)
#pragma unroll
      for (int r = 0; r < 4; ++r) {
        int row = bm + wr * 32 + i * 16 + lg * 4 + r;
        int col = bn + wc * 32 + j * 16 + l16;
        size_t idx = (size_t)row * N + col;
        float val = acc[i][j][r];
        if (C) { if (beta) val += C[idx]; C[idx] = val; }
        if (Cbf) Cbf[idx] = f2b(val);
      }
}

// ---------------- strategy: sigmoid(x @ Ws + bs), (T,48) ----------------
__global__ __launch_bounds__(256) void strat_kernel(const float* __restrict__ x,
                                                    const float* __restrict__ Wsp,
                                                    const float* __restrict__ bsp,
                                                    float* __restrict__ strat) {
  int idx = blockIdx.x * 256 + threadIdx.x;
  int t = idx / 48, n = idx - t * 48;
  float acc = bsp[n];
#pragma unroll 4
  for (int c = 0; c < kHID; ++c) acc += x[(size_t)t * kHID + c] * Wsp[(size_t)c * 48 + n];
  strat[idx] = 1.f / (1.f + __expf(-acc));
}

// ---------------- compression: kc from fp32 k, vc from bf16 v ----------------
__global__ __launch_bounds__(256) void compress_kernel(const float* __restrict__ kk,
                                                       const u16* __restrict__ vvb,
                                                       const float* __restrict__ Wc,
                                                       const float* __restrict__ bc,
                                                       float* __restrict__ kc,
                                                       float* __restrict__ vc) {
  const int blk = blockIdx.x, h = blockIdx.y;
  float* dst = blockIdx.z ? vc : kc;
  const int lane = threadIdx.x & 63, g = threadIdx.x >> 6;
  float acc = 0.f;
#pragma unroll 4
  for (int kidx = g * 1024; kidx < (g + 1) * 1024; ++kidx) {
    int s = kidx >> 6, dd = kidx & 63;
    size_t off = ((size_t)blk * 64 + s) * kHID + h * 64 + dd;
    float a = blockIdx.z ? b2f(vvb[off]) : kk[off];
    acc += a * Wc[(size_t)kidx * 64 + lane];
  }
  __shared__ float red[4][64];
  red[g][lane] = acc;
  __syncthreads();
  if (threadIdx.x < 64) {
    float sum = red[0][lane] + red[1][lane] + red[2][lane] + red[3][lane] + bc[lane];
    float gel = 0.5f * sum * (1.f + erff(sum * 0.70710678118654752f));
    dst[((size_t)h * kNB + blk) * 64 + lane] = gel;
  }
}

// ---------------- sliding-window attention (bf16 in); merged = st0 * slide ----------------
__global__ __launch_bounds__(256) void sliding_kernel(const u16* __restrict__ q,
                                                      const u16* __restrict__ k,
                                                      const u16* __restrict__ v,
                                                      const float* __restrict__ strat,
                                                      u16* __restrict__ merged) {
  __shared__ float kw[128][65];
  __shared__ float qs[64][68];
  const int win = blockIdx.x, h = blockIdx.y;
  const int tid = threadIdx.x;
  {
    int j = tid >> 1, dh = (tid & 1) * 32;
    int t = (win - 1) * 64 + j;
    bool valid = (t >= 0);
    const u16* src = k + (size_t)t * kHID + h * 64 + dh;
#pragma unroll
    for (int i = 0; i < 4; ++i) {
      union { uint4 u; u16 s[8]; } c;
      c.u = valid ? *(const uint4*)(src + i * 8) : make_uint4(0, 0, 0, 0);
#pragma unroll
      for (int e = 0; e < 8; ++e) kw[j][dh + i * 8 + e] = b2f(c.s[e]);
    }
    int r = tid >> 2, c0 = (tid & 3) * 16;
    const u16* qsrc = q + (size_t)(win * 64 + r) * kHID + h * 64 + c0;
#pragma unroll
    for (int i = 0; i < 2; ++i) {
      union { uint4 u; u16 s[8]; } c;
      c.u = *(const uint4*)(qsrc + i * 8);
#pragma unroll
      for (int e = 0; e < 8; ++e) qs[r][c0 + i * 8 + e] = b2f(c.s[e]);
    }
  }
  __syncthreads();
  const int wid = tid >> 6, lane = tid & 63;
  const u16* vp = v + h * 64 + lane;
  for (int i = 0; i < 16; ++i) {
    const int rr = wid * 16 + i;
    const int t = win * 64 + rr;
    float s0 = 0.f, s1 = 0.f;
#pragma unroll
    for (int d4 = 0; d4 < 16; ++d4) {
      float4 q4 = *(const float4*)(&qs[rr][d4 * 4]);
      s0 += q4.x * kw[lane][d4 * 4 + 0] + q4.y * kw[lane][d4 * 4 + 1] +
            q4.z * kw[lane][d4 * 4 + 2] + q4.w * kw[lane][d4 * 4 + 3];
      s1 += q4.x * kw[lane + 64][d4 * 4 + 0] + q4.y * kw[lane + 64][d4 * 4 + 1] +
            q4.z * kw[lane + 64][d4 * 4 + 2] + q4.w * kw[lane + 64][d4 * 4 + 3];
    }
    s0 *= 0.125f; s1 *= 0.125f;
    if (win == 0) s0 = -1e30f;
    if (lane > rr) s1 = -1e30f;
    float mx = wred_max(fmaxf(s0, s1));
    float e0 = __expf(s0 - mx), e1 = __expf(s1 - mx);
    float l = wred_sum(e0 + e1);
    float o = 0.f;
#pragma unroll 8
    for (int j = 0; j < 64; ++j) {
      float p0 = __shfl(e0, j, 64);
      float p1 = __shfl(e1, j, 64);
      int t0 = (win - 1) * 64 + j; if (t0 < 0) t0 = 0;
      o += p0 * b2f(vp[(size_t)t0 * kHID]);
      o += p1 * b2f(vp[(size_t)(win * 64 + j) * kHID]);
    }
    o /= l;
    merged[(size_t)t * kHID + h * 64 + lane] = f2b(strat[t * 48 + h * 3 + 0] * o);
  }
}

// ------- importance (fp32 path) + compressed attention; merged += st1 * comp -------
__global__ __launch_bounds__(256) void impcomp_kernel(const float* __restrict__ q,
                                                      const float* __restrict__ kc,
                                                      const float* __restrict__ vc,
                                                      const float* __restrict__ strat,
                                                      float* __restrict__ imp,
                                                      u16* __restrict__ merged) {
  const int gw = blockIdx.x * 4 + (threadIdx.x >> 6);
  const int lane = threadIdx.x & 63;
  const int h = gw >> 11, t = gw & 2047;
  const float qv = q[(size_t)t * kHID + h * 64 + lane];
  float sj[32];
  float myimp = 0.f;
#pragma unroll
  for (int j = 0; j < 32; ++j) {
    float p = qv * kc[(h * kNB + j) * 64 + lane];
    p = wred_sum(p) * 0.125f;
    sj[j] = p;
    if (lane == j) myimp = p;
  }
  if (lane < 32) imp[((size_t)h * kT + t) * kNB + lane] = myimp;
  float mx = sj[0];
#pragma unroll
  for (int j = 1; j < 32; ++j) mx = fmaxf(mx, sj[j]);
  float lsum = 0.f;
#pragma unroll
  for (int j = 0; j < 32; ++j) { sj[j] = __expf(sj[j] - mx); lsum += sj[j]; }
  float inv = 1.f / lsum;
  float o = 0.f;
#pragma unroll
  for (int j = 0; j < 32; ++j) o += sj[j] * vc[(h * kNB + j) * 64 + lane];
  o *= inv;
  size_t mi = (size_t)t * kHID + h * 64 + lane;
  merged[mi] = f2b(b2f(merged[mi]) + strat[t * 48 + h * 3 + 1] * o);
}

// ------- block scores -> softmax/entropy/dynamic_k/top-k mask per (h,qblk) -------
__global__ __launch_bounds__(256) void blocksel_kernel(const float* __restrict__ imp,
                                                       const float* __restrict__ kscale_p,
                                                       const float* __restrict__ kbias_p,
                                                       unsigned* __restrict__ maskb,
                                                       float* __restrict__ krb,
                                                       float* __restrict__ neb,
                                                       int* __restrict__ dkb) {
  const int gw = blockIdx.x * 4 + (threadIdx.x >> 6);
  const int lane = threadIdx.x & 63;
  const int h = gw >> 5, qb = gw & 31;
  const int j = lane & 31, half = lane >> 5;
  float acc = 0.f;
#pragma unroll 4
  for (int s2 = 0; s2 < 32; ++s2) {
    int s = half * 32 + s2;
    acc += imp[((size_t)h * kT + qb * 64 + s) * kNB + j];
  }
  acc += __shfl_xor(acc, 32, 64);
  float bsj = acc * (1.f / 64.f);
  float mx = bsj;
#pragma unroll
  for (int m = 1; m < 32; m <<= 1) mx = fmaxf(mx, __shfl_xor(mx, m, 64));
  float e = expf(bsj - mx);
  float lsum = e;
#pragma unroll
  for (int m = 1; m < 32; m <<= 1) lsum += __shfl_xor(lsum, m, 64);
  float p = e / lsum;
  float ent = p * logf(p + 1e-9f);
#pragma unroll
  for (int m = 1; m < 32; m <<= 1) ent += __shfl_xor(ent, m, 64);
  ent = -ent;
  float ne = ent / (logf(32.f) + 1e-9f);
  float kr = 1.f / (1.f + expf(-(kscale_p[0] * ne + kbias_p[0])));
  int dk = (int)fminf(fmaxf(8.f * kr, 1.f), 8.f);
  unsigned mword = 1u << qb;
  int taken = 0;
  for (int r = 0; r < dk; ++r) {
    float v2 = taken ? -3.4e38f : bsj;
    int idx2 = j;
#pragma unroll
    for (int m = 1; m < 32; m <<= 1) {
      float ov = __shfl_xor(v2, m, 64);
      int oi = __shfl_xor(idx2, m, 64);
      if (ov > v2 || (ov == v2 && oi < idx2)) { v2 = ov; idx2 = oi; }
    }
    mword |= (1u << idx2);
    if (j == idx2) taken = 1;
  }
  if (lane == 0) {
    maskb[h * kNB + qb] = mword;
    krb[h * kNB + qb] = kr;
    neb[h * kNB + qb] = ne;
    dkb[h * kNB + qb] = dk;
  }
}

// ---------------- scalar outputs: avg_k, aux_loss ----------------
__global__ void finalize_kernel(const int* __restrict__ dkb, const float* __restrict__ krb,
                                const float* __restrict__ neb, float* __restrict__ out) {
  __shared__ float s1[512], s2[512], s3[512];
  int t2 = threadIdx.x;
  float fdk = (float)dkb[t2], kr = krb[t2], ne = neb[t2];
  float d = kr - ne;
  s1[t2] = fdk; s2[t2] = d * d; s3[t2] = kr;
  __syncthreads();
  for (int st = 256; st > 0; st >>= 1) {
    if (t2 < st) { s1[t2] += s1[t2 + st]; s2[t2] += s2[t2 + st]; s3[t2] += s3[t2 + st]; }
    __syncthreads();
  }
  if (t2 == 0) {
    out[(size_t)kT * kHID + 0] = s1[0] * (1.f / 512.f);
    out[(size_t)kT * kHID + 1] = 0.01f * (s2[0] * (1.f / 512.f)) + 0.01f * (s3[0] * (1.f / 512.f));
  }
}

// ------- block-sparse fine attention, MFMA flash-style; merged += st2 * fine -------
__global__ __launch_bounds__(256) void fine_mfma(const u16* __restrict__ qb_, const u16* __restrict__ kb_,
                                                 const u16* __restrict__ vb_, const float* __restrict__ strat,
                                                 const unsigned* __restrict__ maskb, u16* __restrict__ merged) {
  __shared__ u16 Kb[64 * 64];        // [key][d], XOR-swizzled 16B segs
  __shared__ u16 Vt[64 * 64];        // [d][key], XOR-swizzled
  __shared__ u16 Pl[4][16 * 64];     // per-wave P, swizzled
  const int qb = blockIdx.x, h = blockIdx.y;
  const unsigned mword = maskb[h * kNB + qb];
  const int tid = threadIdx.x, w = tid >> 6, lane = tid & 63;
  const int lg = lane >> 4, l16 = lane & 15;
  v8s aq[2];
  {
    const u16* qrow = qb_ + (size_t)(qb * 64 + w * 16 + l16) * kHID + h * 64;
    aq[0] = *(const v8s*)(qrow + lg * 8);
    aq[1] = *(const v8s*)(qrow + 32 + lg * 8);
  }
  float m_run[4], l_run[4];
  v4f o_acc[4] = {};
#pragma unroll
  for (int j = 0; j < 4; ++j) { m_run[j] = -1e30f; l_run[j] = 0.f; }
  for (int jb = 0; jb < 32; ++jb) {
    if (!((mword >> jb) & 1u)) continue;
    __syncthreads();
#pragma unroll
    for (int ss = 0; ss < 2; ++ss) {
      int s = tid + ss * 256;
      int key = s >> 3, sf = (s & 7) ^ (key & 7);
      *(uint4*)((char*)Kb + s * 16) =
          *(const uint4*)(kb_ + (size_t)(jb * 64 + key) * kHID + h * 64 + sf * 8);
    }
    {
      int key = tid & 63, d0 = (tid >> 6) * 16;
      const u16* vsrc = vb_ + (size_t)(jb * 64 + key) * kHID + h * 64 + d0;
      union { uint4 u[2]; u16 s[16]; } c;
      c.u[0] = *(const uint4*)(vsrc);
      c.u[1] = *(const uint4*)(vsrc + 8);
#pragma unroll
      for (int i = 0; i < 16; ++i) {
        int d = d0 + i;
        *((u16*)((char*)Vt + d * 128 + (((key >> 3) ^ (d & 7)) * 16)) + (key & 7)) = c.s[i];
      }
    }
    __syncthreads();
    v4f sa[4] = {};
#pragma unroll
    for (int ct = 0; ct < 4; ++ct) {
      int key = ct * 16 + l16;
#pragma unroll
      for (int kk = 0; kk < 2; ++kk) {
        v8s bk = *(const v8s*)((const char*)Kb + key * 128 + (((kk * 4 + lg) ^ (key & 7)) * 16));
        sa[ct] = mfma16(aq[kk], bk, sa[ct]);
      }
    }
#pragma unroll
    for (int ct = 0; ct < 4; ++ct)
#pragma unroll
      for (int j = 0; j < 4; ++j) sa[ct][j] *= 0.125f;
    float corr[4];
#pragma unroll
    for (int j = 0; j < 4; ++j) {
      float t = fmaxf(fmaxf(sa[0][j], sa[1][j]), fmaxf(sa[2][j], sa[3][j]));
#pragma unroll
      for (int mm = 1; mm < 16; mm <<= 1) t = fmaxf(t, __shfl_xor(t, mm, 64));
      float mn = fmaxf(m_run[j], t);
      corr[j] = __expf(m_run[j] - mn);
      m_run[j] = mn;
    }
    float rs[4] = {0.f, 0.f, 0.f, 0.f};
    float pv[4][4];
#pragma unroll
    for (int ct = 0; ct < 4; ++ct)
#pragma unroll
      for (int j = 0; j < 4; ++j) {
        float e = __expf(sa[ct][j] - m_run[j]);
        pv[ct][j] = e;
        rs[j] += e;
      }
#pragma unroll
    for (int j = 0; j < 4; ++j) {
#pragma unroll
      for (int mm = 1; mm < 16; mm <<= 1) rs[j] += __shfl_xor(rs[j], mm, 64);
      l_run[j] = l_run[j] * corr[j] + rs[j];
    }
#pragma unroll
    for (int ct = 0; ct < 4; ++ct)
#pragma unroll
      for (int j = 0; j < 4; ++j) {
        int row = lg * 4 + j;
        int seg = ct * 2 + (l16 >> 3);
        *((u16*)((char*)Pl + w * 2048 + row * 128 + ((seg ^ (row & 7)) * 16)) + (l16 & 7)) = f2b(pv[ct][j]);
      }
#pragma unroll
    for (int dt = 0; dt < 4; ++dt)
#pragma unroll
      for (int j = 0; j < 4; ++j) o_acc[dt][j] *= corr[j];
#pragma unroll
    for (int dt = 0; dt < 4; ++dt) {
      int d = dt * 16 + l16;
#pragma unroll
      for (int kk = 0; kk < 2; ++kk) {
        v8s pa = *(const v8s*)((const char*)Pl + w * 2048 + l16 * 128 + (((kk * 4 + lg) ^ (l16 & 7)) * 16));
        v8s vb2 = *(const v8s*)((const char*)Vt + d * 128 + (((kk * 4 + lg) ^ (d & 7)) * 16));
        o_acc[dt] = mfma16(pa, vb2, o_acc[dt]);
      }
    }
  }
#pragma unroll
  for (int dt = 0; dt < 4; ++dt)
#pragma unroll
    for (int j = 0; j < 4; ++j) {
      int row = lg * 4 + j;
      int t = qb * 64 + w * 16 + row;
      int d = dt * 16 + l16;
      size_t idx = (size_t)t * kHID + h * 64 + d;
      float o = o_acc[dt][j] / l_run[j];
      merged[idx] = f2b(b2f(merged[idx]) + strat[t * 48 + h * 3 + 2] * o);
    }
}

// ---------------- launch ----------------
extern "C" void kernel_launch(void* const* d_in, const int* in_sizes, int n_in,
                              void* d_out, int out_size, void* d_ws, size_t ws_size,
                              hipStream_t stream) {
  const float* x      = (const float*)d_in[0];
  const float* Wq     = (const float*)d_in[1];
  const float* Wk     = (const float*)d_in[2];
  const float* Wv     = (const float*)d_in[3];
  const float* Wo     = (const float*)d_in[4];
  const float* Wc     = (const float*)d_in[5];
  const float* bc     = (const float*)d_in[6];
  const float* kscale = (const float*)d_in[7];
  const float* kbias  = (const float*)d_in[8];
  const float* Wsp    = (const float*)d_in[9];
  const float* bsp    = (const float*)d_in[10];
  float* out = (float*)d_out;
  char* W = (char*)d_ws;

  // byte offsets (see analysis): total ~48.6 MB
  float* q      = (float*)(W + 0);           // 8 MB
  float* k      = (float*)(W + 8388608);     // 8 MB
  float* strat  = (float*)(W + 16777216);    // 384 KB
  float* kc     = (float*)(W + 17170432);    // 128 KB
  float* vc     = (float*)(W + 17301504);    // 128 KB
  unsigned* maskb = (unsigned*)(W + 17432576);
  float* krb    = (float*)(W + 17434624);
  float* neb    = (float*)(W + 17436672);
  int*   dkb    = (int*)(W + 17438720);
  u16* xh    = (u16*)(W + 17440768);         // 4 MB
  u16* xl    = (u16*)(W + 21635072);         // 4 MB (imp aliases after last use)
  float* imp = (float*)(W + 21635072);       // alias of xl
  u16* WqtH  = (u16*)(W + 25829376);         // 2 MB
  u16* WktH  = (u16*)(W + 27926528);         // 2 MB
  u16* WqtL  = (u16*)(W + 30023680);         // 2 MB
  u16* WktL  = (u16*)(W + 32120832);         // 2 MB
  u16* qbf   = (u16*)(W + 30023680);         // alias of WqtL+WktL (both consumed first)
  u16* WvtH  = (u16*)(W + 34217984);         // 2 MB
  u16* WotH  = (u16*)(W + 36315136);         // 2 MB
  u16* kbf   = (u16*)(W + 38412288);         // 4 MB
  u16* vbf   = (u16*)(W + 42606592);         // 4 MB
  u16* merged= (u16*)(W + 46800896);         // 4 MB

  dim3 b256(256);
  // conversions
  split_kernel<<<8192, b256, 0, stream>>>(x, xh, xl, kT * kHID);
  dim3 tg(32, 32);
  tsplit_kernel<<<tg, b256, 0, stream>>>(Wq, WqtH, WqtL, kHID, kHID);
  tsplit_kernel<<<tg, b256, 0, stream>>>(Wk, WktH, WktL, kHID, kHID);
  tsplit_kernel<<<tg, b256, 0, stream>>>(Wv, WvtH, nullptr, kHID, kHID);
  tsplit_kernel<<<tg, b256, 0, stream>>>(Wo, WotH, nullptr, kHID, kHID);

  dim3 gg(16, 32);
  // K projection: 3-pass split (fp32-accurate for selection path)
  gemm_bf16<<<gg, b256, 0, stream>>>(xh, WktH, k, nullptr, kT, kHID, kHID, 0);
  gemm_bf16<<<gg, b256, 0, stream>>>(xh, WktL, k, nullptr, kT, kHID, kHID, 1);
  gemm_bf16<<<gg, b256, 0, stream>>>(xl, WktH, k, kbf,     kT, kHID, kHID, 1);
  // Q projection: 3-pass split; pass3 writes qbf (over WqtL/WktL, already consumed)
  gemm_bf16<<<gg, b256, 0, stream>>>(xh, WqtH, q, nullptr, kT, kHID, kHID, 0);
  gemm_bf16<<<gg, b256, 0, stream>>>(xh, WqtL, q, nullptr, kT, kHID, kHID, 1);
  gemm_bf16<<<gg, b256, 0, stream>>>(xl, WqtH, q, qbf,     kT, kHID, kHID, 1);
  // V projection: single pass, bf16 out only
  gemm_bf16<<<gg, b256, 0, stream>>>(xh, WvtH, nullptr, vbf, kT, kHID, kHID, 0);

  strat_kernel<<<384, b256, 0, stream>>>(x, Wsp, bsp, strat);
  compress_kernel<<<dim3(kNB, kH, 2), b256, 0, stream>>>(k, vbf, Wc, bc, kc, vc);
  sliding_kernel<<<dim3(32, kH), b256, 0, stream>>>(qbf, kbf, vbf, strat, merged);
  impcomp_kernel<<<8192, b256, 0, stream>>>(q, kc, vc, strat, imp, merged);
  blocksel_kernel<<<128, b256, 0, stream>>>(imp, kscale, kbias, maskb, krb, neb, dkb);
  finalize_kernel<<<1, 512, 0, stream>>>(dkb, krb, neb, out);
  fine_mfma<<<dim3(kNB, kH), b256, 0, stream>>>(qbf, kbf, vbf, strat, maskb, merged);
  // output projection
  gemm_bf16<<<gg, b256, 0, stream>>>(merged, WotH, out, nullptr, kT, kHID, kHID, 0);
}

// Round 3
// 292.429 us; speedup vs baseline: 3.5184x; 2.4949x over previous
//
#include <hip/hip_runtime.h>
#include <math.h>
#include <stdint.h>

typedef unsigned short u16;
typedef short v8s __attribute__((ext_vector_type(8)));
typedef float v4f __attribute__((ext_vector_type(4)));

constexpr int kT   = 2048;
constexpr int kHID = 1024;
constexpr int kH   = 16;
constexpr int kNB  = 32;

__device__ __forceinline__ float b2f(u16 u) { unsigned x = ((unsigned)u) << 16; return __uint_as_float(x); }
__device__ __forceinline__ u16 f2b(float f) {
  unsigned x = __float_as_uint(f);
  x += 0x7FFFu + ((x >> 16) & 1u);
  return (u16)(x >> 16);
}
__device__ __forceinline__ v4f mfma16(v8s a, v8s b, v4f c) {
  return __builtin_amdgcn_mfma_f32_16x16x32_bf16(a, b, c, 0, 0, 0);
}
__device__ __forceinline__ void gl_lds16(const void* g, void* l) {
  __builtin_amdgcn_global_load_lds((const __attribute__((address_space(1))) uint32_t*)g,
                                   (__attribute__((address_space(3))) uint32_t*)l, 16, 0, 0);
}
__device__ __forceinline__ float wred_sum(float v) {
#pragma unroll
  for (int m = 1; m < 64; m <<= 1) v += __shfl_xor(v, m, 64);
  return v;
}
__device__ __forceinline__ v8s pack8(const float* p) {
  float4 a = *(const float4*)p, b = *(const float4*)(p + 4);
  v8s r;
  r[0] = (short)f2b(a.x); r[1] = (short)f2b(a.y); r[2] = (short)f2b(a.z); r[3] = (short)f2b(a.w);
  r[4] = (short)f2b(b.x); r[5] = (short)f2b(b.y); r[6] = (short)f2b(b.z); r[7] = (short)f2b(b.w);
  return r;
}

// ---------------- fp32 -> (hi,lo) bf16 split ----------------
__global__ __launch_bounds__(256) void split_kernel(const float* __restrict__ in,
                                                    u16* __restrict__ hi, u16* __restrict__ lo, int n) {
  int i = blockIdx.x * 256 + threadIdx.x;
  if (i < n) {
    float x = in[i];
    u16 h = f2b(x);
    hi[i] = h;
    lo[i] = f2b(x - b2f(h));
  }
}

// ---------------- W[K][N] fp32 -> out[N][K] bf16 (hi, optional lo) ----------------
__global__ __launch_bounds__(256) void tsplit_kernel(const float* __restrict__ W,
                                                     u16* __restrict__ Hh, u16* __restrict__ Ll,
                                                     int Kd, int Nd) {
  __shared__ float t[32][33];
  const int bx = blockIdx.x * 32, by = blockIdx.y * 32;  // bx: n, by: k
  const int lx = threadIdx.x & 31, ly = threadIdx.x >> 5;
  for (int i = ly; i < 32; i += 8) t[i][lx] = W[(size_t)(by + i) * Nd + bx + lx];
  __syncthreads();
  for (int i = ly; i < 32; i += 8) {
    float x = t[lx][i];                 // = W[by+lx][bx+i]
    size_t idx = (size_t)(bx + i) * Kd + by + lx;
    u16 h = f2b(x);
    Hh[idx] = h;
    if (Ll) Ll[idx] = f2b(x - b2f(h));
  }
}

// ---- C(M,N) = A(M,K)bf16 @ Bt(N,K)^T, fp32 acc, single combo ----
__global__ __launch_bounds__(256) void gemm_bf16(const u16* __restrict__ A, const u16* __restrict__ Bt,
                                                 float* __restrict__ C, u16* __restrict__ Cbf,
                                                 int M, int N, int K) {
  __shared__ u16 As[64 * 64];
  __shared__ u16 Bs[64 * 64];
  const int bm = blockIdx.y * 64, bn = blockIdx.x * 64;
  const int tid = threadIdx.x;
  const int w = tid >> 6, lane = tid & 63;
  const int lg = lane >> 4, l16 = lane & 15;
  const int wr = w >> 1, wc = w & 1;
  v4f acc[2][2] = {};
  for (int k0 = 0; k0 < K; k0 += 64) {
    __syncthreads();
#pragma unroll
    for (int ss = 0; ss < 2; ++ss) {
      int s = tid + ss * 256, row = s >> 3, sf = (s & 7) ^ (row & 7);
      gl_lds16(A + (size_t)(bm + row) * K + k0 + sf * 8, (char*)As + s * 16);
      gl_lds16(Bt + (size_t)(bn + row) * K + k0 + sf * 8, (char*)Bs + s * 16);
    }
    __syncthreads();
    v8s a[2][2], b[2][2];
#pragma unroll
    for (int i = 0; i < 2; ++i)
#pragma unroll
      for (int kk = 0; kk < 2; ++kk) {
        int row = wr * 32 + i * 16 + l16;
        a[i][kk] = *(const v8s*)((const char*)As + row * 128 + (((kk * 4 + lg) ^ (row & 7)) * 16));
        int col = wc * 32 + i * 16 + l16;
        b[i][kk] = *(const v8s*)((const char*)Bs + col * 128 + (((kk * 4 + lg) ^ (col & 7)) * 16));
      }
#pragma unroll
    for (int i = 0; i < 2; ++i)
#pragma unroll
      for (int j = 0; j < 2; ++j) {
        acc[i][j] = mfma16(a[i][0], b[j][0], acc[i][j]);
        acc[i][j] = mfma16(a[i][1], b[j][1], acc[i][j]);
      }
  }
#pragma unroll
  for (int i = 0; i < 2; ++i)
#pragma unroll
    for (int j = 0; j < 2; ++j)
#pragma unroll
      for (int r = 0; r < 4; ++r) {
        int row = bm + wr * 32 + i * 16 + lg * 4 + r;
        int col = bn + wc * 32 + j * 16 + l16;
        size_t idx = (size_t)row * N + col;
        float val = acc[i][j][r];
        if (C) C[idx] = val;
        if (Cbf) Cbf[idx] = f2b(val);
      }
}

// ---- three-combo split GEMM: C = Ah·Bh^T + Ah·Bl^T + Al·Bh^T (fp32-accurate) ----
__global__ __launch_bounds__(256) void gemm3_bf16(const u16* __restrict__ Ah, const u16* __restrict__ Al,
                                                  const u16* __restrict__ Bh, const u16* __restrict__ Bl,
                                                  float* __restrict__ C, u16* __restrict__ Cbf,
                                                  int M, int N, int K) {
  __shared__ u16 AsH[64 * 64], BsH[64 * 64], AsL[64 * 64], BsL[64 * 64];
  const int bm = blockIdx.y * 64, bn = blockIdx.x * 64;
  const int tid = threadIdx.x;
  const int w = tid >> 6, lane = tid & 63;
  const int lg = lane >> 4, l16 = lane & 15;
  const int wr = w >> 1, wc = w & 1;
  v4f acc[2][2] = {};
  for (int k0 = 0; k0 < K; k0 += 64) {
    __syncthreads();
#pragma unroll
    for (int ss = 0; ss < 2; ++ss) {
      int s = tid + ss * 256, row = s >> 3, sf = (s & 7) ^ (row & 7);
      gl_lds16(Ah + (size_t)(bm + row) * K + k0 + sf * 8, (char*)AsH + s * 16);
      gl_lds16(Bh + (size_t)(bn + row) * K + k0 + sf * 8, (char*)BsH + s * 16);
      gl_lds16(Al + (size_t)(bm + row) * K + k0 + sf * 8, (char*)AsL + s * 16);
      gl_lds16(Bl + (size_t)(bn + row) * K + k0 + sf * 8, (char*)BsL + s * 16);
    }
    __syncthreads();
    v8s ah[2][2], al[2][2], bh[2][2], bl[2][2];
#pragma unroll
    for (int i = 0; i < 2; ++i)
#pragma unroll
      for (int kk = 0; kk < 2; ++kk) {
        int row = wr * 32 + i * 16 + l16;
        int ao = row * 128 + (((kk * 4 + lg) ^ (row & 7)) * 16);
        ah[i][kk] = *(const v8s*)((const char*)AsH + ao);
        al[i][kk] = *(const v8s*)((const char*)AsL + ao);
        int col = wc * 32 + i * 16 + l16;
        int bo = col * 128 + (((kk * 4 + lg) ^ (col & 7)) * 16);
        bh[i][kk] = *(const v8s*)((const char*)BsH + bo);
        bl[i][kk] = *(const v8s*)((const char*)BsL + bo);
      }
#pragma unroll
    for (int i = 0; i < 2; ++i)
#pragma unroll
      for (int j = 0; j < 2; ++j)
#pragma unroll
        for (int kk = 0; kk < 2; ++kk) {
          acc[i][j] = mfma16(ah[i][kk], bh[j][kk], acc[i][j]);
          acc[i][j] = mfma16(ah[i][kk], bl[j][kk], acc[i][j]);
          acc[i][j] = mfma16(al[i][kk], bh[j][kk], acc[i][j]);
        }
  }
#pragma unroll
  for (int i = 0; i < 2; ++i)
#pragma unroll
    for (int j = 0; j < 2; ++j)
#pragma unroll
      for (int r = 0; r < 4; ++r) {
        int row = bm + wr * 32 + i * 16 + lg * 4 + r;
        int col = bn + wc * 32 + j * 16 + l16;
        size_t idx = (size_t)row * N + col;
        float val = acc[i][j][r];
        if (C) C[idx] = val;
        if (Cbf) Cbf[idx] = f2b(val);
      }
}

// ---- gather k (fp32) into compress-A layout, hi/lo split: rows=(h*32+nb), K=(s*64+d) ----
__global__ __launch_bounds__(256) void gsplit_kernel(const float* __restrict__ k,
                                                     u16* __restrict__ Ah, u16* __restrict__ Al) {
  int idx = blockIdx.x * 256 + threadIdx.x;   // 512*1024 threads, 4 floats each
  int row = idx >> 10;
  int c4 = (idx & 1023) * 4;
  int h = row >> 5, nb = row & 31;
  int s = c4 >> 6, d = c4 & 63;
  const float* src = k + (size_t)(nb * 64 + s) * kHID + h * 64 + d;
  float4 v = *(const float4*)src;
  size_t o = (size_t)row * 4096 + c4;
  u16 h0 = f2b(v.x), h1 = f2b(v.y), h2 = f2b(v.z), h3 = f2b(v.w);
  Ah[o + 0] = h0; Ah[o + 1] = h1; Ah[o + 2] = h2; Ah[o + 3] = h3;
  Al[o + 0] = f2b(v.x - b2f(h0)); Al[o + 1] = f2b(v.y - b2f(h1));
  Al[o + 2] = f2b(v.z - b2f(h2)); Al[o + 3] = f2b(v.w - b2f(h3));
}

// ---- gather v (bf16) into compress-A layout ----
__global__ __launch_bounds__(256) void vgather_kernel(const u16* __restrict__ vbf,
                                                      u16* __restrict__ vbg) {
  int idx = blockIdx.x * 256 + threadIdx.x;   // 512*512 threads, 8 elems each
  int row = idx >> 9;
  int c8 = (idx & 511) * 8;
  int h = row >> 5, nb = row & 31;
  int s = c8 >> 6, d = c8 & 63;
  *(uint4*)(vbg + (size_t)row * 4096 + c8) =
      *(const uint4*)(vbf + (size_t)(nb * 64 + s) * kHID + h * 64 + d);
}

// ---- compress GEMM, split-K partials: P[ks][512][64]; three-combo optional ----
__global__ __launch_bounds__(256) void cgemm_splitk(const u16* __restrict__ Ah, const u16* __restrict__ Al,
                                                    const u16* __restrict__ Bh, const u16* __restrict__ Bl,
                                                    float* __restrict__ P, int three) {
  __shared__ u16 AsH[64 * 64], BsH[64 * 64], AsL[64 * 64], BsL[64 * 64];
  const int bm = blockIdx.y * 64;
  const int ks = blockIdx.z;
  const int K = 4096;
  const int tid = threadIdx.x;
  const int w = tid >> 6, lane = tid & 63;
  const int lg = lane >> 4, l16 = lane & 15;
  const int wr = w >> 1, wc = w & 1;
  v4f acc[2][2] = {};
  for (int k0 = ks * 512; k0 < ks * 512 + 512; k0 += 64) {
    __syncthreads();
#pragma unroll
    for (int ss = 0; ss < 2; ++ss) {
      int s = tid + ss * 256, row = s >> 3, sf = (s & 7) ^ (row & 7);
      gl_lds16(Ah + (size_t)(bm + row) * K + k0 + sf * 8, (char*)AsH + s * 16);
      gl_lds16(Bh + (size_t)row * K + k0 + sf * 8, (char*)BsH + s * 16);
      if (three) {
        gl_lds16(Al + (size_t)(bm + row) * K + k0 + sf * 8, (char*)AsL + s * 16);
        gl_lds16(Bl + (size_t)row * K + k0 + sf * 8, (char*)BsL + s * 16);
      }
    }
    __syncthreads();
    v8s ah[2][2], bh[2][2];
#pragma unroll
    for (int i = 0; i < 2; ++i)
#pragma unroll
      for (int kk = 0; kk < 2; ++kk) {
        int row = wr * 32 + i * 16 + l16;
        ah[i][kk] = *(const v8s*)((const char*)AsH + row * 128 + (((kk * 4 + lg) ^ (row & 7)) * 16));
        int col = wc * 32 + i * 16 + l16;
        bh[i][kk] = *(const v8s*)((const char*)BsH + col * 128 + (((kk * 4 + lg) ^ (col & 7)) * 16));
      }
#pragma unroll
    for (int i = 0; i < 2; ++i)
#pragma unroll
      for (int j = 0; j < 2; ++j) {
        acc[i][j] = mfma16(ah[i][0], bh[j][0], acc[i][j]);
        acc[i][j] = mfma16(ah[i][1], bh[j][1], acc[i][j]);
      }
    if (three) {
      v8s al[2][2], bl[2][2];
#pragma unroll
      for (int i = 0; i < 2; ++i)
#pragma unroll
        for (int kk = 0; kk < 2; ++kk) {
          int row = wr * 32 + i * 16 + l16;
          al[i][kk] = *(const v8s*)((const char*)AsL + row * 128 + (((kk * 4 + lg) ^ (row & 7)) * 16));
          int col = wc * 32 + i * 16 + l16;
          bl[i][kk] = *(const v8s*)((const char*)BsL + col * 128 + (((kk * 4 + lg) ^ (col & 7)) * 16));
        }
#pragma unroll
      for (int i = 0; i < 2; ++i)
#pragma unroll
        for (int j = 0; j < 2; ++j)
#pragma unroll
          for (int kk = 0; kk < 2; ++kk) {
            acc[i][j] = mfma16(ah[i][kk], bl[j][kk], acc[i][j]);
            acc[i][j] = mfma16(al[i][kk], bh[j][kk], acc[i][j]);
          }
    }
  }
#pragma unroll
  for (int i = 0; i < 2; ++i)
#pragma unroll
    for (int j = 0; j < 2; ++j)
#pragma unroll
      for (int r = 0; r < 4; ++r) {
        int row = bm + wr * 32 + i * 16 + lg * 4 + r;
        int col = wc * 32 + j * 16 + l16;
        P[(size_t)ks * 32768 + (size_t)row * 64 + col] = acc[i][j][r];
      }
}

// ---- reduce split-K partials + bias + exact-erf GELU -> kc, vc ----
__global__ __launch_bounds__(256) void creduce_kernel(const float* __restrict__ Pk,
                                                      const float* __restrict__ Pv,
                                                      const float* __restrict__ bc,
                                                      float* __restrict__ kc, float* __restrict__ vc) {
  int idx = blockIdx.x * 256 + threadIdx.x;   // 0..65535
  int which = idx >> 15;
  int e = idx & 32767;
  const float* P = which ? Pv : Pk;
  float s = 0.f;
#pragma unroll
  for (int ks = 0; ks < 8; ++ks) s += P[(size_t)ks * 32768 + e];
  s += bc[e & 63];
  float g = 0.5f * s * (1.f + erff(s * 0.70710678118654752f));
  (which ? vc : kc)[e] = g;
}

// ---------------- strategy: sigmoid(x @ Ws + bs), (T,48) ----------------
__global__ __launch_bounds__(256) void strat_kernel(const float* __restrict__ x,
                                                    const float* __restrict__ Wsp,
                                                    const float* __restrict__ bsp,
                                                    float* __restrict__ strat) {
  int idx = blockIdx.x * 256 + threadIdx.x;
  int t = idx / 48, n = idx - t * 48;
  float acc = bsp[n];
#pragma unroll 4
  for (int c = 0; c < kHID; ++c) acc += x[(size_t)t * kHID + c] * Wsp[(size_t)c * 48 + n];
  strat[idx] = 1.f / (1.f + __expf(-acc));
}

// ---- sliding-window attention, MFMA flash over <=2 tiles; merged = st0 * slide ----
__global__ __launch_bounds__(256) void slide_mfma(const float* __restrict__ qf,
                                                  const u16* __restrict__ kb_,
                                                  const u16* __restrict__ vb_,
                                                  const float* __restrict__ strat,
                                                  u16* __restrict__ merged) {
  __shared__ u16 Kb[64 * 64];
  __shared__ u16 Vt[64 * 64];
  __shared__ u16 Pl[4][16 * 64];
  const int win = blockIdx.x, h = blockIdx.y;
  const int tid = threadIdx.x, w = tid >> 6, lane = tid & 63;
  const int lg = lane >> 4, l16 = lane & 15;
  v8s aq[2];
  {
    const float* qrow = qf + (size_t)(win * 64 + w * 16 + l16) * kHID + h * 64;
    aq[0] = pack8(qrow + lg * 8);
    aq[1] = pack8(qrow + 32 + lg * 8);
  }
  float m_run[4], l_run[4];
  v4f o_acc[4] = {};
#pragma unroll
  for (int j = 0; j < 4; ++j) { m_run[j] = -1e30f; l_run[j] = 0.f; }
  for (int ti = 0; ti < 2; ++ti) {
    int jb = win - 1 + ti;
    if (jb < 0) continue;
    __syncthreads();
#pragma unroll
    for (int ss = 0; ss < 2; ++ss) {
      int s = tid + ss * 256;
      int key = s >> 3, sf = (s & 7) ^ (key & 7);
      *(uint4*)((char*)Kb + s * 16) =
          *(const uint4*)(kb_ + (size_t)(jb * 64 + key) * kHID + h * 64 + sf * 8);
    }
    {
      int key = tid & 63, d0 = (tid >> 6) * 16;
      const u16* vsrc = vb_ + (size_t)(jb * 64 + key) * kHID + h * 64 + d0;
      union { uint4 u[2]; u16 s[16]; } c;
      c.u[0] = *(const uint4*)(vsrc);
      c.u[1] = *(const uint4*)(vsrc + 8);
#pragma unroll
      for (int i = 0; i < 16; ++i) {
        int d = d0 + i;
        *((u16*)((char*)Vt + d * 128 + (((key >> 3) ^ (d & 7)) * 16)) + (key & 7)) = c.s[i];
      }
    }
    __syncthreads();
    v4f sa[4] = {};
#pragma unroll
    for (int ct = 0; ct < 4; ++ct) {
      int key = ct * 16 + l16;
#pragma unroll
      for (int kk = 0; kk < 2; ++kk) {
        v8s bk = *(const v8s*)((const char*)Kb + key * 128 + (((kk * 4 + lg) ^ (key & 7)) * 16));
        sa[ct] = mfma16(aq[kk], bk, sa[ct]);
      }
    }
#pragma unroll
    for (int ct = 0; ct < 4; ++ct)
#pragma unroll
      for (int j = 0; j < 4; ++j) {
        float val = sa[ct][j] * 0.125f;
        if (ti == 1) {
          int key = ct * 16 + l16;
          int qp = w * 16 + lg * 4 + j;
          if (key > qp) val = -1e30f;
        }
        sa[ct][j] = val;
      }
    float corr[4];
#pragma unroll
    for (int j = 0; j < 4; ++j) {
      float t = fmaxf(fmaxf(sa[0][j], sa[1][j]), fmaxf(sa[2][j], sa[3][j]));
#pragma unroll
      for (int mm = 1; mm < 16; mm <<= 1) t = fmaxf(t, __shfl_xor(t, mm, 64));
      float mn = fmaxf(m_run[j], t);
      corr[j] = __expf(m_run[j] - mn);
      m_run[j] = mn;
    }
    float rs[4] = {0.f, 0.f, 0.f, 0.f};
    float pv[4][4];
#pragma unroll
    for (int ct = 0; ct < 4; ++ct)
#pragma unroll
      for (int j = 0; j < 4; ++j) {
        float e = __expf(sa[ct][j] - m_run[j]);
        pv[ct][j] = e;
        rs[j] += e;
      }
#pragma unroll
    for (int j = 0; j < 4; ++j) {
#pragma unroll
      for (int mm = 1; mm < 16; mm <<= 1) rs[j] += __shfl_xor(rs[j], mm, 64);
      l_run[j] = l_run[j] * corr[j] + rs[j];
    }
#pragma unroll
    for (int ct = 0; ct < 4; ++ct)
#pragma unroll
      for (int j = 0; j < 4; ++j) {
        int row = lg * 4 + j;
        int seg = ct * 2 + (l16 >> 3);
        *((u16*)((char*)Pl + w * 2048 + row * 128 + ((seg ^ (row & 7)) * 16)) + (l16 & 7)) = f2b(pv[ct][j]);
      }
#pragma unroll
    for (int dt = 0; dt < 4; ++dt)
#pragma unroll
      for (int j = 0; j < 4; ++j) o_acc[dt][j] *= corr[j];
#pragma unroll
    for (int dt = 0; dt < 4; ++dt) {
      int d = dt * 16 + l16;
#pragma unroll
      for (int kk = 0; kk < 2; ++kk) {
        v8s pa = *(const v8s*)((const char*)Pl + w * 2048 + l16 * 128 + (((kk * 4 + lg) ^ (l16 & 7)) * 16));
        v8s vb2 = *(const v8s*)((const char*)Vt + d * 128 + (((kk * 4 + lg) ^ (d & 7)) * 16));
        o_acc[dt] = mfma16(pa, vb2, o_acc[dt]);
      }
    }
  }
#pragma unroll
  for (int dt = 0; dt < 4; ++dt)
#pragma unroll
    for (int j = 0; j < 4; ++j) {
      int row = lg * 4 + j;
      int t = win * 64 + w * 16 + row;
      int d = dt * 16 + l16;
      size_t idx = (size_t)t * kHID + h * 64 + d;
      float o = o_acc[dt][j] / l_run[j];
      merged[idx] = f2b(strat[t * 48 + h * 3 + 0] * o);
    }
}

// ------- importance (fp32 path) + compressed attention; merged += st1 * comp -------
__global__ __launch_bounds__(256) void impcomp_kernel(const float* __restrict__ q,
                                                      const float* __restrict__ kc,
                                                      const float* __restrict__ vc,
                                                      const float* __restrict__ strat,
                                                      float* __restrict__ imp,
                                                      u16* __restrict__ merged) {
  const int gw = blockIdx.x * 4 + (threadIdx.x >> 6);
  const int lane = threadIdx.x & 63;
  const int h = gw >> 11, t = gw & 2047;
  const float qv = q[(size_t)t * kHID + h * 64 + lane];
  float sj[32];
  float myimp = 0.f;
#pragma unroll
  for (int j = 0; j < 32; ++j) {
    float p = qv * kc[(h * kNB + j) * 64 + lane];
    p = wred_sum(p) * 0.125f;
    sj[j] = p;
    if (lane == j) myimp = p;
  }
  if (lane < 32) imp[((size_t)h * kT + t) * kNB + lane] = myimp;
  float mx = sj[0];
#pragma unroll
  for (int j = 1; j < 32; ++j) mx = fmaxf(mx, sj[j]);
  float lsum = 0.f;
#pragma unroll
  for (int j = 0; j < 32; ++j) { sj[j] = __expf(sj[j] - mx); lsum += sj[j]; }
  float inv = 1.f / lsum;
  float o = 0.f;
#pragma unroll
  for (int j = 0; j < 32; ++j) o += sj[j] * vc[(h * kNB + j) * 64 + lane];
  o *= inv;
  size_t mi = (size_t)t * kHID + h * 64 + lane;
  merged[mi] = f2b(b2f(merged[mi]) + strat[t * 48 + h * 3 + 1] * o);
}

// ------- block scores -> softmax/entropy/dynamic_k/top-k mask per (h,qblk) -------
__global__ __launch_bounds__(256) void blocksel_kernel(const float* __restrict__ imp,
                                                       const float* __restrict__ kscale_p,
                                                       const float* __restrict__ kbias_p,
                                                       unsigned* __restrict__ maskb,
                                                       float* __restrict__ krb,
                                                       float* __restrict__ neb,
                                                       int* __restrict__ dkb) {
  const int gw = blockIdx.x * 4 + (threadIdx.x >> 6);
  const int lane = threadIdx.x & 63;
  const int h = gw >> 5, qb = gw & 31;
  const int j = lane & 31, half = lane >> 5;
  float acc = 0.f;
#pragma unroll 4
  for (int s2 = 0; s2 < 32; ++s2) {
    int s = half * 32 + s2;
    acc += imp[((size_t)h * kT + qb * 64 + s) * kNB + j];
  }
  acc += __shfl_xor(acc, 32, 64);
  float bsj = acc * (1.f / 64.f);
  float mx = bsj;
#pragma unroll
  for (int m = 1; m < 32; m <<= 1) mx = fmaxf(mx, __shfl_xor(mx, m, 64));
  float e = expf(bsj - mx);
  float lsum = e;
#pragma unroll
  for (int m = 1; m < 32; m <<= 1) lsum += __shfl_xor(lsum, m, 64);
  float p = e / lsum;
  float ent = p * logf(p + 1e-9f);
#pragma unroll
  for (int m = 1; m < 32; m <<= 1) ent += __shfl_xor(ent, m, 64);
  ent = -ent;
  float ne = ent / (logf(32.f) + 1e-9f);
  float kr = 1.f / (1.f + expf(-(kscale_p[0] * ne + kbias_p[0])));
  int dk = (int)fminf(fmaxf(8.f * kr, 1.f), 8.f);
  unsigned mword = 1u << qb;
  int taken = 0;
  for (int r = 0; r < dk; ++r) {
    float v2 = taken ? -3.4e38f : bsj;
    int idx2 = j;
#pragma unroll
    for (int m = 1; m < 32; m <<= 1) {
      float ov = __shfl_xor(v2, m, 64);
      int oi = __shfl_xor(idx2, m, 64);
      if (ov > v2 || (ov == v2 && oi < idx2)) { v2 = ov; idx2 = oi; }
    }
    mword |= (1u << idx2);
    if (j == idx2) taken = 1;
  }
  if (lane == 0) {
    maskb[h * kNB + qb] = mword;
    krb[h * kNB + qb] = kr;
    neb[h * kNB + qb] = ne;
    dkb[h * kNB + qb] = dk;
  }
}

// ---------------- scalar outputs: avg_k, aux_loss ----------------
__global__ void finalize_kernel(const int* __restrict__ dkb, const float* __restrict__ krb,
                                const float* __restrict__ neb, float* __restrict__ out) {
  __shared__ float s1[512], s2[512], s3[512];
  int t2 = threadIdx.x;
  float fdk = (float)dkb[t2], kr = krb[t2], ne = neb[t2];
  float d = kr - ne;
  s1[t2] = fdk; s2[t2] = d * d; s3[t2] = kr;
  __syncthreads();
  for (int st = 256; st > 0; st >>= 1) {
    if (t2 < st) { s1[t2] += s1[t2 + st]; s2[t2] += s2[t2 + st]; s3[t2] += s3[t2 + st]; }
    __syncthreads();
  }
  if (t2 == 0) {
    out[(size_t)kT * kHID + 0] = s1[0] * (1.f / 512.f);
    out[(size_t)kT * kHID + 1] = 0.01f * (s2[0] * (1.f / 512.f)) + 0.01f * (s3[0] * (1.f / 512.f));
  }
}

// ------- block-sparse fine attention, MFMA flash-style; merged += st2 * fine -------
__global__ __launch_bounds__(256) void fine_mfma(const float* __restrict__ qf, const u16* __restrict__ kb_,
                                                 const u16* __restrict__ vb_, const float* __restrict__ strat,
                                                 const unsigned* __restrict__ maskb, u16* __restrict__ merged) {
  __shared__ u16 Kb[64 * 64];
  __shared__ u16 Vt[64 * 64];
  __shared__ u16 Pl[4][16 * 64];
  const int qb = blockIdx.x, h = blockIdx.y;
  const unsigned mword = maskb[h * kNB + qb];
  const int tid = threadIdx.x, w = tid >> 6, lane = tid & 63;
  const int lg = lane >> 4, l16 = lane & 15;
  v8s aq[2];
  {
    const float* qrow = qf + (size_t)(qb * 64 + w * 16 + l16) * kHID + h * 64;
    aq[0] = pack8(qrow + lg * 8);
    aq[1] = pack8(qrow + 32 + lg * 8);
  }
  float m_run[4], l_run[4];
  v4f o_acc[4] = {};
#pragma unroll
  for (int j = 0; j < 4; ++j) { m_run[j] = -1e30f; l_run[j] = 0.f; }
  for (int jb = 0; jb < 32; ++jb) {
    if (!((mword >> jb) & 1u)) continue;
    __syncthreads();
#pragma unroll
    for (int ss = 0; ss < 2; ++ss) {
      int s = tid + ss * 256;
      int key = s >> 3, sf = (s & 7) ^ (key & 7);
      *(uint4*)((char*)Kb + s * 16) =
          *(const uint4*)(kb_ + (size_t)(jb * 64 + key) * kHID + h * 64 + sf * 8);
    }
    {
      int key = tid & 63, d0 = (tid >> 6) * 16;
      const u16* vsrc = vb_ + (size_t)(jb * 64 + key) * kHID + h * 64 + d0;
      union { uint4 u[2]; u16 s[16]; } c;
      c.u[0] = *(const uint4*)(vsrc);
      c.u[1] = *(const uint4*)(vsrc + 8);
#pragma unroll
      for (int i = 0; i < 16; ++i) {
        int d = d0 + i;
        *((u16*)((char*)Vt + d * 128 + (((key >> 3) ^ (d & 7)) * 16)) + (key & 7)) = c.s[i];
      }
    }
    __syncthreads();
    v4f sa[4] = {};
#pragma unroll
    for (int ct = 0; ct < 4; ++ct) {
      int key = ct * 16 + l16;
#pragma unroll
      for (int kk = 0; kk < 2; ++kk) {
        v8s bk = *(const v8s*)((const char*)Kb + key * 128 + (((kk * 4 + lg) ^ (key & 7)) * 16));
        sa[ct] = mfma16(aq[kk], bk, sa[ct]);
      }
    }
#pragma unroll
    for (int ct = 0; ct < 4; ++ct)
#pragma unroll
      for (int j = 0; j < 4; ++j) sa[ct][j] *= 0.125f;
    float corr[4];
#pragma unroll
    for (int j = 0; j < 4; ++j) {
      float t = fmaxf(fmaxf(sa[0][j], sa[1][j]), fmaxf(sa[2][j], sa[3][j]));
#pragma unroll
      for (int mm = 1; mm < 16; mm <<= 1) t = fmaxf(t, __shfl_xor(t, mm, 64));
      float mn = fmaxf(m_run[j], t);
      corr[j] = __expf(m_run[j] - mn);
      m_run[j] = mn;
    }
    float rs[4] = {0.f, 0.f, 0.f, 0.f};
    float pv[4][4];
#pragma unroll
    for (int ct = 0; ct < 4; ++ct)
#pragma unroll
      for (int j = 0; j < 4; ++j) {
        float e = __expf(sa[ct][j] - m_run[j]);
        pv[ct][j] = e;
        rs[j] += e;
      }
#pragma unroll
    for (int j = 0; j < 4; ++j) {
#pragma unroll
      for (int mm = 1; mm < 16; mm <<= 1) rs[j] += __shfl_xor(rs[j], mm, 64);
      l_run[j] = l_run[j] * corr[j] + rs[j];
    }
#pragma unroll
    for (int ct = 0; ct < 4; ++ct)
#pragma unroll
      for (int j = 0; j < 4; ++j) {
        int row = lg * 4 + j;
        int seg = ct * 2 + (l16 >> 3);
        *((u16*)((char*)Pl + w * 2048 + row * 128 + ((seg ^ (row & 7)) * 16)) + (l16 & 7)) = f2b(pv[ct][j]);
      }
#pragma unroll
    for (int dt = 0; dt < 4; ++dt)
#pragma unroll
      for (int j = 0; j < 4; ++j) o_acc[dt][j] *= corr[j];
#pragma unroll
    for (int dt = 0; dt < 4; ++dt) {
      int d = dt * 16 + l16;
#pragma unroll
      for (int kk = 0; kk < 2; ++kk) {
        v8s pa = *(const v8s*)((const char*)Pl + w * 2048 + l16 * 128 + (((kk * 4 + lg) ^ (l16 & 7)) * 16));
        v8s vb2 = *(const v8s*)((const char*)Vt + d * 128 + (((kk * 4 + lg) ^ (d & 7)) * 16));
        o_acc[dt] = mfma16(pa, vb2, o_acc[dt]);
      }
    }
  }
#pragma unroll
  for (int dt = 0; dt < 4; ++dt)
#pragma unroll
    for (int j = 0; j < 4; ++j) {
      int row = lg * 4 + j;
      int t = qb * 64 + w * 16 + row;
      int d = dt * 16 + l16;
      size_t idx = (size_t)t * kHID + h * 64 + d;
      float o = o_acc[dt][j] / l_run[j];
      merged[idx] = f2b(b2f(merged[idx]) + strat[t * 48 + h * 3 + 2] * o);
    }
}

// ---------------- launch ----------------
extern "C" void kernel_launch(void* const* d_in, const int* in_sizes, int n_in,
                              void* d_out, int out_size, void* d_ws, size_t ws_size,
                              hipStream_t stream) {
  const float* x      = (const float*)d_in[0];
  const float* Wq     = (const float*)d_in[1];
  const float* Wk     = (const float*)d_in[2];
  const float* Wv     = (const float*)d_in[3];
  const float* Wo     = (const float*)d_in[4];
  const float* Wc     = (const float*)d_in[5];
  const float* bc     = (const float*)d_in[6];
  const float* kscale = (const float*)d_in[7];
  const float* kbias  = (const float*)d_in[8];
  const float* Wsp    = (const float*)d_in[9];
  const float* bsp    = (const float*)d_in[10];
  float* out = (float*)d_out;
  char* W = (char*)d_ws;

  // lifetime-based layout, peak 50,995,200 bytes (same as prior round)
  float* q      = (float*)(W + 0);           // 8 MB   [Q proj -> impcomp/slide/fine]
  float* k      = (float*)(W + 8388608);     // 8 MB   [K proj -> gsplit]; then:
  float* Pk     = (float*)(W + 8388608);     //   1 MB [cgemm -> creduce]
  float* Pv     = (float*)(W + 9437184);     //   1 MB
  float* strat  = (float*)(W + 16777216);    // 384 KB
  float* kc     = (float*)(W + 17170432);    // 128 KB
  float* vc     = (float*)(W + 17301504);    // 128 KB
  unsigned* maskb = (unsigned*)(W + 17432576);
  float* krb    = (float*)(W + 17434624);
  float* neb    = (float*)(W + 17436672);
  int*   dkb    = (int*)(W + 17438720);
  u16* xh    = (u16*)(W + 17440768);         // 4 MB [split -> V proj]; then Agh
  u16* Agh   = (u16*)(W + 17440768);
  u16* xl    = (u16*)(W + 21635072);         // 4 MB [split -> Q proj]; then Agl; then imp
  u16* Agl   = (u16*)(W + 21635072);
  float* imp = (float*)(W + 21635072);       // 4 MB [impcomp -> blocksel]
  u16* WqtH  = (u16*)(W + 25829376);         // 2 MB [-> Q proj]; vbg spans WqtH+WktH after
  u16* vbg   = (u16*)(W + 25829376);         // 4 MB [vgather -> cgemm vc]
  u16* WktH  = (u16*)(W + 27926528);         // 2 MB [-> K proj]
  u16* WqtL  = (u16*)(W + 30023680);         // 2 MB [-> Q proj]; then WctH/WctL
  u16* WctH  = (u16*)(W + 30023680);         // 512 KB
  u16* WctL  = (u16*)(W + 30547968);         // 512 KB
  u16* WktL  = (u16*)(W + 32120832);         // 2 MB [-> K proj]
  u16* WvtH  = (u16*)(W + 34217984);         // 2 MB [-> V proj]
  u16* WotH  = (u16*)(W + 36315136);         // 2 MB [-> final gemm]
  u16* kbf   = (u16*)(W + 38412288);         // 4 MB
  u16* vbf   = (u16*)(W + 42606592);         // 4 MB
  u16* merged= (u16*)(W + 46800896);         // 4 MB

  dim3 b256(256);
  split_kernel<<<8192, b256, 0, stream>>>(x, xh, xl, kT * kHID);
  dim3 tg(32, 32);
  tsplit_kernel<<<tg, b256, 0, stream>>>(Wq, WqtH, WqtL, kHID, kHID);
  tsplit_kernel<<<tg, b256, 0, stream>>>(Wk, WktH, WktL, kHID, kHID);
  tsplit_kernel<<<tg, b256, 0, stream>>>(Wv, WvtH, nullptr, kHID, kHID);
  tsplit_kernel<<<tg, b256, 0, stream>>>(Wo, WotH, nullptr, kHID, kHID);

  dim3 gg(16, 32);
  gemm3_bf16<<<gg, b256, 0, stream>>>(xh, xl, WktH, WktL, k, kbf, kT, kHID, kHID);
  gemm3_bf16<<<gg, b256, 0, stream>>>(xh, xl, WqtH, WqtL, q, nullptr, kT, kHID, kHID);
  gemm_bf16<<<gg, b256, 0, stream>>>(xh, WvtH, nullptr, vbf, kT, kHID, kHID);

  // compress path (after projections: xh/xl/Wq*/Wk* regions reusable)
  tsplit_kernel<<<dim3(2, 128), b256, 0, stream>>>(Wc, WctH, WctL, 4096, 64);
  gsplit_kernel<<<2048, b256, 0, stream>>>(k, Agh, Agl);
  vgather_kernel<<<1024, b256, 0, stream>>>(vbf, vbg);
  cgemm_splitk<<<dim3(1, 8, 8), b256, 0, stream>>>(Agh, Agl, WctH, WctL, Pk, 1);
  cgemm_splitk<<<dim3(1, 8, 8), b256, 0, stream>>>(vbg, nullptr, WctH, nullptr, Pv, 0);
  creduce_kernel<<<256, b256, 0, stream>>>(Pk, Pv, bc, kc, vc);

  strat_kernel<<<384, b256, 0, stream>>>(x, Wsp, bsp, strat);
  slide_mfma<<<dim3(32, kH), b256, 0, stream>>>(q, kbf, vbf, strat, merged);
  impcomp_kernel<<<8192, b256, 0, stream>>>(q, kc, vc, strat, imp, merged);
  blocksel_kernel<<<128, b256, 0, stream>>>(imp, kscale, kbias, maskb, krb, neb, dkb);
  finalize_kernel<<<1, 512, 0, stream>>>(dkb, krb, neb, out);
  fine_mfma<<<dim3(kNB, kH), b256, 0, stream>>>(q, kbf, vbf, strat, maskb, merged);
  gemm_bf16<<<gg, b256, 0, stream>>>(merged, WotH, out, nullptr, kT, kHID, kHID);
}

// Round 4
// 178.732 us; speedup vs baseline: 5.7566x; 1.6361x over previous
//
#include <hip/hip_runtime.h>
#include <math.h>
#include <stdint.h>

typedef unsigned short u16;
typedef short v8s __attribute__((ext_vector_type(8)));
typedef float v4f __attribute__((ext_vector_type(4)));

constexpr int kT   = 2048;
constexpr int kHID = 1024;
constexpr int kH   = 16;
constexpr int kNB  = 32;

__device__ __forceinline__ float b2f(u16 u) { unsigned x = ((unsigned)u) << 16; return __uint_as_float(x); }
__device__ __forceinline__ u16 f2b(float f) {
  unsigned x = __float_as_uint(f);
  x += 0x7FFFu + ((x >> 16) & 1u);
  return (u16)(x >> 16);
}
__device__ __forceinline__ v4f mfma16(v8s a, v8s b, v4f c) {
  return __builtin_amdgcn_mfma_f32_16x16x32_bf16(a, b, c, 0, 0, 0);
}
__device__ __forceinline__ void gl_lds16(const void* g, void* l) {
  __builtin_amdgcn_global_load_lds((const __attribute__((address_space(1))) uint32_t*)g,
                                   (__attribute__((address_space(3))) uint32_t*)l, 16, 0, 0);
}
__device__ __forceinline__ v8s pack8(const float* p) {
  float4 a = *(const float4*)p, b = *(const float4*)(p + 4);
  v8s r;
  r[0] = (short)f2b(a.x); r[1] = (short)f2b(a.y); r[2] = (short)f2b(a.z); r[3] = (short)f2b(a.w);
  r[4] = (short)f2b(b.x); r[5] = (short)f2b(b.y); r[6] = (short)f2b(b.z); r[7] = (short)f2b(b.w);
  return r;
}
__device__ __forceinline__ void pack8hl(const float* p, v8s& hv, v8s& lv) {
  float4 a = *(const float4*)p, b = *(const float4*)(p + 4);
  float t[8] = {a.x, a.y, a.z, a.w, b.x, b.y, b.z, b.w};
#pragma unroll
  for (int i = 0; i < 8; ++i) {
    u16 h = f2b(t[i]);
    hv[i] = (short)h;
    lv[i] = (short)f2b(t[i] - b2f(h));
  }
}

// ---------------- fp32 -> (hi,lo) bf16 split ----------------
__global__ __launch_bounds__(256) void split_kernel(const float* __restrict__ in,
                                                    u16* __restrict__ hi, u16* __restrict__ lo, int n) {
  int i = blockIdx.x * 256 + threadIdx.x;
  if (i < n) {
    float x = in[i];
    u16 h = f2b(x);
    hi[i] = h;
    lo[i] = f2b(x - b2f(h));
  }
}

// ---------------- W[K][N] fp32 -> out[N][K] bf16 (hi, optional lo) ----------------
__global__ __launch_bounds__(256) void tsplit_kernel(const float* __restrict__ W,
                                                     u16* __restrict__ Hh, u16* __restrict__ Ll,
                                                     int Kd, int Nd) {
  __shared__ float t[32][33];
  const int bx = blockIdx.x * 32, by = blockIdx.y * 32;  // bx: n, by: k
  const int lx = threadIdx.x & 31, ly = threadIdx.x >> 5;
  for (int i = ly; i < 32; i += 8) t[i][lx] = W[(size_t)(by + i) * Nd + bx + lx];
  __syncthreads();
  for (int i = ly; i < 32; i += 8) {
    float x = t[lx][i];                 // = W[by+lx][bx+i]
    size_t idx = (size_t)(bx + i) * Kd + by + lx;
    u16 h = f2b(x);
    Hh[idx] = h;
    if (Ll) Ll[idx] = f2b(x - b2f(h));
  }
}

// ---- Ws (1024,48) fp32 -> Wst (64,1024) bf16, rows 48..63 zero ----
__global__ __launch_bounds__(256) void wst_kernel(const float* __restrict__ Ws, u16* __restrict__ Wst) {
  int i = blockIdx.x * 256 + threadIdx.x;   // 65536
  int n = i >> 10, k2 = i & 1023;
  float v = (n < 48) ? Ws[(size_t)k2 * 48 + n] : 0.f;
  Wst[(size_t)n * 1024 + k2] = f2b(v);
}

// ---- C(M,N) = A(M,K)bf16 @ Bt(N,K)^T, fp32 acc, single combo ----
__global__ __launch_bounds__(256) void gemm_bf16(const u16* __restrict__ A, const u16* __restrict__ Bt,
                                                 float* __restrict__ C, u16* __restrict__ Cbf,
                                                 int M, int N, int K) {
  __shared__ u16 As[64 * 64];
  __shared__ u16 Bs[64 * 64];
  const int bm = blockIdx.y * 64, bn = blockIdx.x * 64;
  const int tid = threadIdx.x;
  const int w = tid >> 6, lane = tid & 63;
  const int lg = lane >> 4, l16 = lane & 15;
  const int wr = w >> 1, wc = w & 1;
  v4f acc[2][2] = {};
  for (int k0 = 0; k0 < K; k0 += 64) {
    __syncthreads();
#pragma unroll
    for (int ss = 0; ss < 2; ++ss) {
      int s = tid + ss * 256, row = s >> 3, sf = (s & 7) ^ (row & 7);
      gl_lds16(A + (size_t)(bm + row) * K + k0 + sf * 8, (char*)As + s * 16);
      gl_lds16(Bt + (size_t)(bn + row) * K + k0 + sf * 8, (char*)Bs + s * 16);
    }
    __syncthreads();
    v8s a[2][2], b[2][2];
#pragma unroll
    for (int i = 0; i < 2; ++i)
#pragma unroll
      for (int kk = 0; kk < 2; ++kk) {
        int row = wr * 32 + i * 16 + l16;
        a[i][kk] = *(const v8s*)((const char*)As + row * 128 + (((kk * 4 + lg) ^ (row & 7)) * 16));
        int col = wc * 32 + i * 16 + l16;
        b[i][kk] = *(const v8s*)((const char*)Bs + col * 128 + (((kk * 4 + lg) ^ (col & 7)) * 16));
      }
#pragma unroll
    for (int i = 0; i < 2; ++i)
#pragma unroll
      for (int j = 0; j < 2; ++j) {
        acc[i][j] = mfma16(a[i][0], b[j][0], acc[i][j]);
        acc[i][j] = mfma16(a[i][1], b[j][1], acc[i][j]);
      }
  }
#pragma unroll
  for (int i = 0; i < 2; ++i)
#pragma unroll
    for (int j = 0; j < 2; ++j)
#pragma unroll
      for (int r = 0; r < 4; ++r) {
        int row = bm + wr * 32 + i * 16 + lg * 4 + r;
        int col = bn + wc * 32 + j * 16 + l16;
        size_t idx = (size_t)row * N + col;
        float val = acc[i][j][r];
        if (C) C[idx] = val;
        if (Cbf) Cbf[idx] = f2b(val);
      }
}

// ---- strategy GEMM: strat(T,48) = sigmoid(x @ Ws + bs), A=xh, Bt=Wst(64,1024) ----
__global__ __launch_bounds__(256) void strat_gemm(const u16* __restrict__ A, const u16* __restrict__ Bt,
                                                  const float* __restrict__ bsp, float* __restrict__ strat) {
  __shared__ u16 As[64 * 64];
  __shared__ u16 Bs[64 * 64];
  const int bm = blockIdx.x * 64;
  const int tid = threadIdx.x;
  const int w = tid >> 6, lane = tid & 63;
  const int lg = lane >> 4, l16 = lane & 15;
  const int wr = w >> 1, wc = w & 1;
  const int K = 1024;
  v4f acc[2][2] = {};
  for (int k0 = 0; k0 < K; k0 += 64) {
    __syncthreads();
#pragma unroll
    for (int ss = 0; ss < 2; ++ss) {
      int s = tid + ss * 256, row = s >> 3, sf = (s & 7) ^ (row & 7);
      gl_lds16(A + (size_t)(bm + row) * K + k0 + sf * 8, (char*)As + s * 16);
      gl_lds16(Bt + (size_t)row * K + k0 + sf * 8, (char*)Bs + s * 16);
    }
    __syncthreads();
    v8s a[2][2], b[2][2];
#pragma unroll
    for (int i = 0; i < 2; ++i)
#pragma unroll
      for (int kk = 0; kk < 2; ++kk) {
        int row = wr * 32 + i * 16 + l16;
        a[i][kk] = *(const v8s*)((const char*)As + row * 128 + (((kk * 4 + lg) ^ (row & 7)) * 16));
        int col = wc * 32 + i * 16 + l16;
        b[i][kk] = *(const v8s*)((const char*)Bs + col * 128 + (((kk * 4 + lg) ^ (col & 7)) * 16));
      }
#pragma unroll
    for (int i = 0; i < 2; ++i)
#pragma unroll
      for (int j = 0; j < 2; ++j) {
        acc[i][j] = mfma16(a[i][0], b[j][0], acc[i][j]);
        acc[i][j] = mfma16(a[i][1], b[j][1], acc[i][j]);
      }
  }
#pragma unroll
  for (int i = 0; i < 2; ++i)
#pragma unroll
    for (int j = 0; j < 2; ++j)
#pragma unroll
      for (int r = 0; r < 4; ++r) {
        int row = bm + wr * 32 + i * 16 + lg * 4 + r;
        int col = wc * 32 + j * 16 + l16;
        if (col < 48) {
          float val = acc[i][j][r] + bsp[col];
          strat[(size_t)row * 48 + col] = 1.f / (1.f + expf(-val));
        }
      }
}

// ---- three-combo split GEMM: C = Ah·Bh^T + Ah·Bl^T + Al·Bh^T (fp32-accurate) ----
__global__ __launch_bounds__(256) void gemm3_bf16(const u16* __restrict__ Ah, const u16* __restrict__ Al,
                                                  const u16* __restrict__ Bh, const u16* __restrict__ Bl,
                                                  float* __restrict__ C, u16* __restrict__ Cbf,
                                                  int M, int N, int K) {
  __shared__ u16 AsH[64 * 64], BsH[64 * 64], AsL[64 * 64], BsL[64 * 64];
  const int bm = blockIdx.y * 64, bn = blockIdx.x * 64;
  const int tid = threadIdx.x;
  const int w = tid >> 6, lane = tid & 63;
  const int lg = lane >> 4, l16 = lane & 15;
  const int wr = w >> 1, wc = w & 1;
  v4f acc[2][2] = {};
  for (int k0 = 0; k0 < K; k0 += 64) {
    __syncthreads();
#pragma unroll
    for (int ss = 0; ss < 2; ++ss) {
      int s = tid + ss * 256, row = s >> 3, sf = (s & 7) ^ (row & 7);
      gl_lds16(Ah + (size_t)(bm + row) * K + k0 + sf * 8, (char*)AsH + s * 16);
      gl_lds16(Bh + (size_t)(bn + row) * K + k0 + sf * 8, (char*)BsH + s * 16);
      gl_lds16(Al + (size_t)(bm + row) * K + k0 + sf * 8, (char*)AsL + s * 16);
      gl_lds16(Bl + (size_t)(bn + row) * K + k0 + sf * 8, (char*)BsL + s * 16);
    }
    __syncthreads();
    v8s ah[2][2], al[2][2], bh[2][2], bl[2][2];
#pragma unroll
    for (int i = 0; i < 2; ++i)
#pragma unroll
      for (int kk = 0; kk < 2; ++kk) {
        int row = wr * 32 + i * 16 + l16;
        int ao = row * 128 + (((kk * 4 + lg) ^ (row & 7)) * 16);
        ah[i][kk] = *(const v8s*)((const char*)AsH + ao);
        al[i][kk] = *(const v8s*)((const char*)AsL + ao);
        int col = wc * 32 + i * 16 + l16;
        int bo = col * 128 + (((kk * 4 + lg) ^ (col & 7)) * 16);
        bh[i][kk] = *(const v8s*)((const char*)BsH + bo);
        bl[i][kk] = *(const v8s*)((const char*)BsL + bo);
      }
#pragma unroll
    for (int i = 0; i < 2; ++i)
#pragma unroll
      for (int j = 0; j < 2; ++j)
#pragma unroll
        for (int kk = 0; kk < 2; ++kk) {
          acc[i][j] = mfma16(ah[i][kk], bh[j][kk], acc[i][j]);
          acc[i][j] = mfma16(ah[i][kk], bl[j][kk], acc[i][j]);
          acc[i][j] = mfma16(al[i][kk], bh[j][kk], acc[i][j]);
        }
  }
#pragma unroll
  for (int i = 0; i < 2; ++i)
#pragma unroll
    for (int j = 0; j < 2; ++j)
#pragma unroll
      for (int r = 0; r < 4; ++r) {
        int row = bm + wr * 32 + i * 16 + lg * 4 + r;
        int col = bn + wc * 32 + j * 16 + l16;
        size_t idx = (size_t)row * N + col;
        float val = acc[i][j][r];
        if (C) C[idx] = val;
        if (Cbf) Cbf[idx] = f2b(val);
      }
}

// ---- gather k (fp32) into compress-A layout, hi/lo split: rows=(h*32+nb), K=(s*64+d) ----
__global__ __launch_bounds__(256) void gsplit_kernel(const float* __restrict__ k,
                                                     u16* __restrict__ Ah, u16* __restrict__ Al) {
  int idx = blockIdx.x * 256 + threadIdx.x;   // 512*1024 threads, 4 floats each
  int row = idx >> 10;
  int c4 = (idx & 1023) * 4;
  int h = row >> 5, nb = row & 31;
  int s = c4 >> 6, d = c4 & 63;
  const float* src = k + (size_t)(nb * 64 + s) * kHID + h * 64 + d;
  float4 v = *(const float4*)src;
  size_t o = (size_t)row * 4096 + c4;
  u16 h0 = f2b(v.x), h1 = f2b(v.y), h2 = f2b(v.z), h3 = f2b(v.w);
  Ah[o + 0] = h0; Ah[o + 1] = h1; Ah[o + 2] = h2; Ah[o + 3] = h3;
  Al[o + 0] = f2b(v.x - b2f(h0)); Al[o + 1] = f2b(v.y - b2f(h1));
  Al[o + 2] = f2b(v.z - b2f(h2)); Al[o + 3] = f2b(v.w - b2f(h3));
}

// ---- gather v (bf16) into compress-A layout ----
__global__ __launch_bounds__(256) void vgather_kernel(const u16* __restrict__ vbf,
                                                      u16* __restrict__ vbg) {
  int idx = blockIdx.x * 256 + threadIdx.x;   // 512*512 threads, 8 elems each
  int row = idx >> 9;
  int c8 = (idx & 511) * 8;
  int h = row >> 5, nb = row & 31;
  int s = c8 >> 6, d = c8 & 63;
  *(uint4*)(vbg + (size_t)row * 4096 + c8) =
      *(const uint4*)(vbf + (size_t)(nb * 64 + s) * kHID + h * 64 + d);
}

// ---- compress GEMM, split-K partials: P[ks][512][64]; three-combo optional ----
__global__ __launch_bounds__(256) void cgemm_splitk(const u16* __restrict__ Ah, const u16* __restrict__ Al,
                                                    const u16* __restrict__ Bh, const u16* __restrict__ Bl,
                                                    float* __restrict__ P, int three) {
  __shared__ u16 AsH[64 * 64], BsH[64 * 64], AsL[64 * 64], BsL[64 * 64];
  const int bm = blockIdx.y * 64;
  const int ks = blockIdx.z;
  const int K = 4096;
  const int tid = threadIdx.x;
  const int w = tid >> 6, lane = tid & 63;
  const int lg = lane >> 4, l16 = lane & 15;
  const int wr = w >> 1, wc = w & 1;
  v4f acc[2][2] = {};
  for (int k0 = ks * 512; k0 < ks * 512 + 512; k0 += 64) {
    __syncthreads();
#pragma unroll
    for (int ss = 0; ss < 2; ++ss) {
      int s = tid + ss * 256, row = s >> 3, sf = (s & 7) ^ (row & 7);
      gl_lds16(Ah + (size_t)(bm + row) * K + k0 + sf * 8, (char*)AsH + s * 16);
      gl_lds16(Bh + (size_t)row * K + k0 + sf * 8, (char*)BsH + s * 16);
      if (three) {
        gl_lds16(Al + (size_t)(bm + row) * K + k0 + sf * 8, (char*)AsL + s * 16);
        gl_lds16(Bl + (size_t)row * K + k0 + sf * 8, (char*)BsL + s * 16);
      }
    }
    __syncthreads();
    v8s ah[2][2], bh[2][2];
#pragma unroll
    for (int i = 0; i < 2; ++i)
#pragma unroll
      for (int kk = 0; kk < 2; ++kk) {
        int row = wr * 32 + i * 16 + l16;
        ah[i][kk] = *(const v8s*)((const char*)AsH + row * 128 + (((kk * 4 + lg) ^ (row & 7)) * 16));
        int col = wc * 32 + i * 16 + l16;
        bh[i][kk] = *(const v8s*)((const char*)BsH + col * 128 + (((kk * 4 + lg) ^ (col & 7)) * 16));
      }
#pragma unroll
    for (int i = 0; i < 2; ++i)
#pragma unroll
      for (int j = 0; j < 2; ++j) {
        acc[i][j] = mfma16(ah[i][0], bh[j][0], acc[i][j]);
        acc[i][j] = mfma16(ah[i][1], bh[j][1], acc[i][j]);
      }
    if (three) {
      v8s al[2][2], bl[2][2];
#pragma unroll
      for (int i = 0; i < 2; ++i)
#pragma unroll
        for (int kk = 0; kk < 2; ++kk) {
          int row = wr * 32 + i * 16 + l16;
          al[i][kk] = *(const v8s*)((const char*)AsL + row * 128 + (((kk * 4 + lg) ^ (row & 7)) * 16));
          int col = wc * 32 + i * 16 + l16;
          bl[i][kk] = *(const v8s*)((const char*)BsL + col * 128 + (((kk * 4 + lg) ^ (col & 7)) * 16));
        }
#pragma unroll
      for (int i = 0; i < 2; ++i)
#pragma unroll
        for (int j = 0; j < 2; ++j)
#pragma unroll
          for (int kk = 0; kk < 2; ++kk) {
            acc[i][j] = mfma16(ah[i][kk], bl[j][kk], acc[i][j]);
            acc[i][j] = mfma16(al[i][kk], bh[j][kk], acc[i][j]);
          }
    }
  }
#pragma unroll
  for (int i = 0; i < 2; ++i)
#pragma unroll
    for (int j = 0; j < 2; ++j)
#pragma unroll
      for (int r = 0; r < 4; ++r) {
        int row = bm + wr * 32 + i * 16 + lg * 4 + r;
        int col = wc * 32 + j * 16 + l16;
        P[(size_t)ks * 32768 + (size_t)row * 64 + col] = acc[i][j][r];
      }
}

// ---- reduce split-K + bias + exact-erf GELU -> kch/kcl (hi/lo bf16), vct (bf16 transposed) ----
__global__ __launch_bounds__(256) void creduce_kernel(const float* __restrict__ Pk,
                                                      const float* __restrict__ Pv,
                                                      const float* __restrict__ bc,
                                                      u16* __restrict__ kch, u16* __restrict__ kcl,
                                                      u16* __restrict__ vct) {
  int idx = blockIdx.x * 256 + threadIdx.x;   // 0..65535
  int which = idx >> 15;
  int e = idx & 32767;
  const float* P = which ? Pv : Pk;
  float s = 0.f;
#pragma unroll
  for (int ks = 0; ks < 8; ++ks) s += P[(size_t)ks * 32768 + e];
  s += bc[e & 63];
  float g = 0.5f * s * (1.f + erff(s * 0.70710678118654752f));
  if (!which) {
    u16 hh = f2b(g);
    kch[e] = hh;
    kcl[e] = f2b(g - b2f(hh));
  } else {
    int h2 = e >> 11, j = (e >> 6) & 31, d = e & 63;
    vct[(size_t)h2 * 2048 + d * 32 + j] = f2b(g);
  }
}

// ---- sliding-window attention, MFMA flash over <=2 tiles; merged = st0 * slide ----
__global__ __launch_bounds__(256) void slide_mfma(const float* __restrict__ qf,
                                                  const u16* __restrict__ kb_,
                                                  const u16* __restrict__ vb_,
                                                  const float* __restrict__ strat,
                                                  u16* __restrict__ merged) {
  __shared__ u16 Kb[64 * 64];
  __shared__ u16 Vt[64 * 64];
  __shared__ u16 Pl[4][16 * 64];
  const int win = blockIdx.x, h = blockIdx.y;
  const int tid = threadIdx.x, w = tid >> 6, lane = tid & 63;
  const int lg = lane >> 4, l16 = lane & 15;
  v8s aq[2];
  {
    const float* qrow = qf + (size_t)(win * 64 + w * 16 + l16) * kHID + h * 64;
    aq[0] = pack8(qrow + lg * 8);
    aq[1] = pack8(qrow + 32 + lg * 8);
  }
  float m_run[4], l_run[4];
  v4f o_acc[4] = {};
#pragma unroll
  for (int j = 0; j < 4; ++j) { m_run[j] = -1e30f; l_run[j] = 0.f; }
  for (int ti = 0; ti < 2; ++ti) {
    int jb = win - 1 + ti;
    if (jb < 0) continue;
    __syncthreads();
#pragma unroll
    for (int ss = 0; ss < 2; ++ss) {
      int s = tid + ss * 256;
      int key = s >> 3, sf = (s & 7) ^ (key & 7);
      *(uint4*)((char*)Kb + s * 16) =
          *(const uint4*)(kb_ + (size_t)(jb * 64 + key) * kHID + h * 64 + sf * 8);
    }
    {
      int key = tid & 63, d0 = (tid >> 6) * 16;
      const u16* vsrc = vb_ + (size_t)(jb * 64 + key) * kHID + h * 64 + d0;
      union { uint4 u[2]; u16 s[16]; } c;
      c.u[0] = *(const uint4*)(vsrc);
      c.u[1] = *(const uint4*)(vsrc + 8);
#pragma unroll
      for (int i = 0; i < 16; ++i) {
        int d = d0 + i;
        *((u16*)((char*)Vt + d * 128 + (((key >> 3) ^ (d & 7)) * 16)) + (key & 7)) = c.s[i];
      }
    }
    __syncthreads();
    v4f sa[4] = {};
#pragma unroll
    for (int ct = 0; ct < 4; ++ct) {
      int key = ct * 16 + l16;
#pragma unroll
      for (int kk = 0; kk < 2; ++kk) {
        v8s bk = *(const v8s*)((const char*)Kb + key * 128 + (((kk * 4 + lg) ^ (key & 7)) * 16));
        sa[ct] = mfma16(aq[kk], bk, sa[ct]);
      }
    }
#pragma unroll
    for (int ct = 0; ct < 4; ++ct)
#pragma unroll
      for (int j = 0; j < 4; ++j) {
        float val = sa[ct][j] * 0.125f;
        if (ti == 1) {
          int key = ct * 16 + l16;
          int qp = w * 16 + lg * 4 + j;
          if (key > qp) val = -1e30f;
        }
        sa[ct][j] = val;
      }
    float corr[4];
#pragma unroll
    for (int j = 0; j < 4; ++j) {
      float t = fmaxf(fmaxf(sa[0][j], sa[1][j]), fmaxf(sa[2][j], sa[3][j]));
#pragma unroll
      for (int mm = 1; mm < 16; mm <<= 1) t = fmaxf(t, __shfl_xor(t, mm, 64));
      float mn = fmaxf(m_run[j], t);
      corr[j] = __expf(m_run[j] - mn);
      m_run[j] = mn;
    }
    float rs[4] = {0.f, 0.f, 0.f, 0.f};
    float pv[4][4];
#pragma unroll
    for (int ct = 0; ct < 4; ++ct)
#pragma unroll
      for (int j = 0; j < 4; ++j) {
        float e = __expf(sa[ct][j] - m_run[j]);
        pv[ct][j] = e;
        rs[j] += e;
      }
#pragma unroll
    for (int j = 0; j < 4; ++j) {
#pragma unroll
      for (int mm = 1; mm < 16; mm <<= 1) rs[j] += __shfl_xor(rs[j], mm, 64);
      l_run[j] = l_run[j] * corr[j] + rs[j];
    }
#pragma unroll
    for (int ct = 0; ct < 4; ++ct)
#pragma unroll
      for (int j = 0; j < 4; ++j) {
        int row = lg * 4 + j;
        int seg = ct * 2 + (l16 >> 3);
        *((u16*)((char*)Pl + w * 2048 + row * 128 + ((seg ^ (row & 7)) * 16)) + (l16 & 7)) = f2b(pv[ct][j]);
      }
#pragma unroll
    for (int dt = 0; dt < 4; ++dt)
#pragma unroll
      for (int j = 0; j < 4; ++j) o_acc[dt][j] *= corr[j];
#pragma unroll
    for (int dt = 0; dt < 4; ++dt) {
      int d = dt * 16 + l16;
#pragma unroll
      for (int kk = 0; kk < 2; ++kk) {
        v8s pa = *(const v8s*)((const char*)Pl + w * 2048 + l16 * 128 + (((kk * 4 + lg) ^ (l16 & 7)) * 16));
        v8s vb2 = *(const v8s*)((const char*)Vt + d * 128 + (((kk * 4 + lg) ^ (d & 7)) * 16));
        o_acc[dt] = mfma16(pa, vb2, o_acc[dt]);
      }
    }
  }
#pragma unroll
  for (int dt = 0; dt < 4; ++dt)
#pragma unroll
    for (int j = 0; j < 4; ++j) {
      int row = lg * 4 + j;
      int t = win * 64 + w * 16 + row;
      int d = dt * 16 + l16;
      size_t idx = (size_t)t * kHID + h * 64 + d;
      float o = o_acc[dt][j] / l_run[j];
      merged[idx] = f2b(strat[t * 48 + h * 3 + 0] * o);
    }
}

// ------- importance (hi/lo MFMA, fp32-accurate) + compressed attn; merged += st1*comp -------
__global__ __launch_bounds__(256) void impcomp_mfma(const float* __restrict__ q,
                                                    const u16* __restrict__ kch,
                                                    const u16* __restrict__ kcl,
                                                    const u16* __restrict__ vct,
                                                    const float* __restrict__ strat,
                                                    float* __restrict__ imp,
                                                    u16* __restrict__ merged) {
  __shared__ u16 Pl[4][16 * 32];
  const int tt = blockIdx.x, h = blockIdx.y;
  const int tid = threadIdx.x, w = tid >> 6, lane = tid & 63;
  const int lg = lane >> 4, l16 = lane & 15;
  const float* qrow = q + (size_t)(tt * 64 + w * 16 + l16) * kHID + h * 64;
  v8s ah[2], al[2];
  pack8hl(qrow + lg * 8, ah[0], al[0]);
  pack8hl(qrow + 32 + lg * 8, ah[1], al[1]);
  v4f sa[2] = {};
#pragma unroll
  for (int ct = 0; ct < 2; ++ct) {
    int col = ct * 16 + l16;
#pragma unroll
    for (int kk = 0; kk < 2; ++kk) {
      v8s bh = *(const v8s*)(kch + ((size_t)h * 32 + col) * 64 + kk * 32 + lg * 8);
      v8s bl = *(const v8s*)(kcl + ((size_t)h * 32 + col) * 64 + kk * 32 + lg * 8);
      sa[ct] = mfma16(ah[kk], bh, sa[ct]);
      sa[ct] = mfma16(ah[kk], bl, sa[ct]);
      sa[ct] = mfma16(al[kk], bh, sa[ct]);
    }
  }
#pragma unroll
  for (int ct = 0; ct < 2; ++ct)
#pragma unroll
    for (int j = 0; j < 4; ++j) sa[ct][j] *= 0.125f;
  // write importance (fp32)
#pragma unroll
  for (int j = 0; j < 4; ++j) {
    int t = tt * 64 + w * 16 + lg * 4 + j;
    imp[((size_t)h * kT + t) * kNB + l16] = sa[0][j];
    imp[((size_t)h * kT + t) * kNB + 16 + l16] = sa[1][j];
  }
  // row softmax over 32 (values live across l16 x 2 regs)
  float linv[4];
#pragma unroll
  for (int j = 0; j < 4; ++j) {
    float m = fmaxf(sa[0][j], sa[1][j]);
#pragma unroll
    for (int mm = 1; mm < 16; mm <<= 1) m = fmaxf(m, __shfl_xor(m, mm, 64));
    float e0 = __expf(sa[0][j] - m), e1 = __expf(sa[1][j] - m);
    float s = e0 + e1;
#pragma unroll
    for (int mm = 1; mm < 16; mm <<= 1) s += __shfl_xor(s, mm, 64);
    linv[j] = 1.f / s;
    int row = lg * 4 + j;
    Pl[w][row * 32 + l16] = f2b(e0);
    Pl[w][row * 32 + 16 + l16] = f2b(e1);
  }
  // PV: A = P (16 rows x K=32), B = vct (d x key)
  v8s pa = *(const v8s*)(&Pl[w][l16 * 32 + lg * 8]);
  v4f o[4] = {};
#pragma unroll
  for (int dt = 0; dt < 4; ++dt) {
    v8s b = *(const v8s*)(vct + ((size_t)h * 64 + dt * 16 + l16) * 32 + lg * 8);
    o[dt] = mfma16(pa, b, o[dt]);
  }
#pragma unroll
  for (int dt = 0; dt < 4; ++dt)
#pragma unroll
    for (int j = 0; j < 4; ++j) {
      int t = tt * 64 + w * 16 + lg * 4 + j;
      int d = dt * 16 + l16;
      size_t mi = (size_t)t * kHID + h * 64 + d;
      float val = o[dt][j] * linv[j];
      merged[mi] = f2b(b2f(merged[mi]) + strat[t * 48 + h * 3 + 1] * val);
    }
}

// ------- block scores -> softmax/entropy/dynamic_k/top-k mask per (h,qblk) -------
__global__ __launch_bounds__(256) void blocksel_kernel(const float* __restrict__ imp,
                                                       const float* __restrict__ kscale_p,
                                                       const float* __restrict__ kbias_p,
                                                       unsigned* __restrict__ maskb,
                                                       float* __restrict__ krb,
                                                       float* __restrict__ neb,
                                                       int* __restrict__ dkb) {
  const int gw = blockIdx.x * 4 + (threadIdx.x >> 6);
  const int lane = threadIdx.x & 63;
  const int h = gw >> 5, qb = gw & 31;
  const int j = lane & 31, half = lane >> 5;
  float acc = 0.f;
#pragma unroll 4
  for (int s2 = 0; s2 < 32; ++s2) {
    int s = half * 32 + s2;
    acc += imp[((size_t)h * kT + qb * 64 + s) * kNB + j];
  }
  acc += __shfl_xor(acc, 32, 64);
  float bsj = acc * (1.f / 64.f);
  float mx = bsj;
#pragma unroll
  for (int m = 1; m < 32; m <<= 1) mx = fmaxf(mx, __shfl_xor(mx, m, 64));
  float e = expf(bsj - mx);
  float lsum = e;
#pragma unroll
  for (int m = 1; m < 32; m <<= 1) lsum += __shfl_xor(lsum, m, 64);
  float p = e / lsum;
  float ent = p * logf(p + 1e-9f);
#pragma unroll
  for (int m = 1; m < 32; m <<= 1) ent += __shfl_xor(ent, m, 64);
  ent = -ent;
  float ne = ent / (logf(32.f) + 1e-9f);
  float kr = 1.f / (1.f + expf(-(kscale_p[0] * ne + kbias_p[0])));
  int dk = (int)fminf(fmaxf(8.f * kr, 1.f), 8.f);
  unsigned mword = 1u << qb;
  int taken = 0;
  for (int r = 0; r < dk; ++r) {
    float v2 = taken ? -3.4e38f : bsj;
    int idx2 = j;
#pragma unroll
    for (int m = 1; m < 32; m <<= 1) {
      float ov = __shfl_xor(v2, m, 64);
      int oi = __shfl_xor(idx2, m, 64);
      if (ov > v2 || (ov == v2 && oi < idx2)) { v2 = ov; idx2 = oi; }
    }
    mword |= (1u << idx2);
    if (j == idx2) taken = 1;
  }
  if (lane == 0) {
    maskb[h * kNB + qb] = mword;
    krb[h * kNB + qb] = kr;
    neb[h * kNB + qb] = ne;
    dkb[h * kNB + qb] = dk;
  }
}

// ---------------- scalar outputs: avg_k, aux_loss ----------------
__global__ void finalize_kernel(const int* __restrict__ dkb, const float* __restrict__ krb,
                                const float* __restrict__ neb, float* __restrict__ out) {
  __shared__ float s1[512], s2[512], s3[512];
  int t2 = threadIdx.x;
  float fdk = (float)dkb[t2], kr = krb[t2], ne = neb[t2];
  float d = kr - ne;
  s1[t2] = fdk; s2[t2] = d * d; s3[t2] = kr;
  __syncthreads();
  for (int st = 256; st > 0; st >>= 1) {
    if (t2 < st) { s1[t2] += s1[t2 + st]; s2[t2] += s2[t2 + st]; s3[t2] += s3[t2 + st]; }
    __syncthreads();
  }
  if (t2 == 0) {
    out[(size_t)kT * kHID + 0] = s1[0] * (1.f / 512.f);
    out[(size_t)kT * kHID + 1] = 0.01f * (s2[0] * (1.f / 512.f)) + 0.01f * (s3[0] * (1.f / 512.f));
  }
}

// ------- block-sparse fine attention, MFMA flash-style; merged += st2 * fine -------
__global__ __launch_bounds__(256) void fine_mfma(const float* __restrict__ qf, const u16* __restrict__ kb_,
                                                 const u16* __restrict__ vb_, const float* __restrict__ strat,
                                                 const unsigned* __restrict__ maskb, u16* __restrict__ merged) {
  __shared__ u16 Kb[64 * 64];
  __shared__ u16 Vt[64 * 64];
  __shared__ u16 Pl[4][16 * 64];
  const int qb = blockIdx.x, h = blockIdx.y;
  const unsigned mword = maskb[h * kNB + qb];
  const int tid = threadIdx.x, w = tid >> 6, lane = tid & 63;
  const int lg = lane >> 4, l16 = lane & 15;
  v8s aq[2];
  {
    const float* qrow = qf + (size_t)(qb * 64 + w * 16 + l16) * kHID + h * 64;
    aq[0] = pack8(qrow + lg * 8);
    aq[1] = pack8(qrow + 32 + lg * 8);
  }
  float m_run[4], l_run[4];
  v4f o_acc[4] = {};
#pragma unroll
  for (int j = 0; j < 4; ++j) { m_run[j] = -1e30f; l_run[j] = 0.f; }
  for (int jb = 0; jb < 32; ++jb) {
    if (!((mword >> jb) & 1u)) continue;
    __syncthreads();
#pragma unroll
    for (int ss = 0; ss < 2; ++ss) {
      int s = tid + ss * 256;
      int key = s >> 3, sf = (s & 7) ^ (key & 7);
      *(uint4*)((char*)Kb + s * 16) =
          *(const uint4*)(kb_ + (size_t)(jb * 64 + key) * kHID + h * 64 + sf * 8);
    }
    {
      int key = tid & 63, d0 = (tid >> 6) * 16;
      const u16* vsrc = vb_ + (size_t)(jb * 64 + key) * kHID + h * 64 + d0;
      union { uint4 u[2]; u16 s[16]; } c;
      c.u[0] = *(const uint4*)(vsrc);
      c.u[1] = *(const uint4*)(vsrc + 8);
#pragma unroll
      for (int i = 0; i < 16; ++i) {
        int d = d0 + i;
        *((u16*)((char*)Vt + d * 128 + (((key >> 3) ^ (d & 7)) * 16)) + (key & 7)) = c.s[i];
      }
    }
    __syncthreads();
    v4f sa[4] = {};
#pragma unroll
    for (int ct = 0; ct < 4; ++ct) {
      int key = ct * 16 + l16;
#pragma unroll
      for (int kk = 0; kk < 2; ++kk) {
        v8s bk = *(const v8s*)((const char*)Kb + key * 128 + (((kk * 4 + lg) ^ (key & 7)) * 16));
        sa[ct] = mfma16(aq[kk], bk, sa[ct]);
      }
    }
#pragma unroll
    for (int ct = 0; ct < 4; ++ct)
#pragma unroll
      for (int j = 0; j < 4; ++j) sa[ct][j] *= 0.125f;
    float corr[4];
#pragma unroll
    for (int j = 0; j < 4; ++j) {
      float t = fmaxf(fmaxf(sa[0][j], sa[1][j]), fmaxf(sa[2][j], sa[3][j]));
#pragma unroll
      for (int mm = 1; mm < 16; mm <<= 1) t = fmaxf(t, __shfl_xor(t, mm, 64));
      float mn = fmaxf(m_run[j], t);
      corr[j] = __expf(m_run[j] - mn);
      m_run[j] = mn;
    }
    float rs[4] = {0.f, 0.f, 0.f, 0.f};
    float pv[4][4];
#pragma unroll
    for (int ct = 0; ct < 4; ++ct)
#pragma unroll
      for (int j = 0; j < 4; ++j) {
        float e = __expf(sa[ct][j] - m_run[j]);
        pv[ct][j] = e;
        rs[j] += e;
      }
#pragma unroll
    for (int j = 0; j < 4; ++j) {
#pragma unroll
      for (int mm = 1; mm < 16; mm <<= 1) rs[j] += __shfl_xor(rs[j], mm, 64);
      l_run[j] = l_run[j] * corr[j] + rs[j];
    }
#pragma unroll
    for (int ct = 0; ct < 4; ++ct)
#pragma unroll
      for (int j = 0; j < 4; ++j) {
        int row = lg * 4 + j;
        int seg = ct * 2 + (l16 >> 3);
        *((u16*)((char*)Pl + w * 2048 + row * 128 + ((seg ^ (row & 7)) * 16)) + (l16 & 7)) = f2b(pv[ct][j]);
      }
#pragma unroll
    for (int dt = 0; dt < 4; ++dt)
#pragma unroll
      for (int j = 0; j < 4; ++j) o_acc[dt][j] *= corr[j];
#pragma unroll
    for (int dt = 0; dt < 4; ++dt) {
      int d = dt * 16 + l16;
#pragma unroll
      for (int kk = 0; kk < 2; ++kk) {
        v8s pa = *(const v8s*)((const char*)Pl + w * 2048 + l16 * 128 + (((kk * 4 + lg) ^ (l16 & 7)) * 16));
        v8s vb2 = *(const v8s*)((const char*)Vt + d * 128 + (((kk * 4 + lg) ^ (d & 7)) * 16));
        o_acc[dt] = mfma16(pa, vb2, o_acc[dt]);
      }
    }
  }
#pragma unroll
  for (int dt = 0; dt < 4; ++dt)
#pragma unroll
    for (int j = 0; j < 4; ++j) {
      int row = lg * 4 + j;
      int t = qb * 64 + w * 16 + row;
      int d = dt * 16 + l16;
      size_t idx = (size_t)t * kHID + h * 64 + d;
      float o = o_acc[dt][j] / l_run[j];
      merged[idx] = f2b(b2f(merged[idx]) + strat[t * 48 + h * 3 + 2] * o);
    }
}

// ---------------- launch ----------------
extern "C" void kernel_launch(void* const* d_in, const int* in_sizes, int n_in,
                              void* d_out, int out_size, void* d_ws, size_t ws_size,
                              hipStream_t stream) {
  const float* x      = (const float*)d_in[0];
  const float* Wq     = (const float*)d_in[1];
  const float* Wk     = (const float*)d_in[2];
  const float* Wv     = (const float*)d_in[3];
  const float* Wo     = (const float*)d_in[4];
  const float* Wc     = (const float*)d_in[5];
  const float* bc     = (const float*)d_in[6];
  const float* kscale = (const float*)d_in[7];
  const float* kbias  = (const float*)d_in[8];
  const float* Wsp    = (const float*)d_in[9];
  const float* bsp    = (const float*)d_in[10];
  float* out = (float*)d_out;
  char* W = (char*)d_ws;

  // lifetime-based layout, peak 50,995,200 bytes (unchanged)
  float* q      = (float*)(W + 0);           // 8 MB   [Q proj -> impcomp/slide/fine]
  float* k      = (float*)(W + 8388608);     // 8 MB   [K proj -> gsplit]; then:
  float* Pk     = (float*)(W + 8388608);     //   1 MB [cgemm -> creduce]
  float* Pv     = (float*)(W + 9437184);     //   1 MB
  u16* kchb     = (u16*)(W + 10485760);      //  64 KB [creduce -> impcomp]
  u16* kclb     = (u16*)(W + 10551296);      //  64 KB
  u16* vctb     = (u16*)(W + 10616832);      //  64 KB
  float* strat  = (float*)(W + 16777216);    // 384 KB
  unsigned* maskb = (unsigned*)(W + 17432576);
  float* krb    = (float*)(W + 17434624);
  float* neb    = (float*)(W + 17436672);
  int*   dkb    = (int*)(W + 17438720);
  u16* xh    = (u16*)(W + 17440768);         // 4 MB [split -> projections/strat]; then Agh
  u16* Agh   = (u16*)(W + 17440768);
  u16* xl    = (u16*)(W + 21635072);         // 4 MB [split -> Q/K proj]; then Agl; then imp
  u16* Agl   = (u16*)(W + 21635072);
  float* imp = (float*)(W + 21635072);       // 4 MB [impcomp -> blocksel]
  u16* WqtH  = (u16*)(W + 25829376);         // 2 MB [-> Q proj]; vbg spans WqtH+WktH after
  u16* vbg   = (u16*)(W + 25829376);         // 4 MB [vgather -> cgemm vc]
  u16* WktH  = (u16*)(W + 27926528);         // 2 MB [-> K proj]
  u16* WqtL  = (u16*)(W + 30023680);         // 2 MB [-> Q proj]; then WctH/WctL
  u16* WctH  = (u16*)(W + 30023680);         // 512 KB
  u16* WctL  = (u16*)(W + 30547968);         // 512 KB
  u16* WktL  = (u16*)(W + 32120832);         // 2 MB [-> K proj]; then Wst
  u16* Wst   = (u16*)(W + 32120832);         // 128 KB [wst -> strat_gemm]
  u16* WvtH  = (u16*)(W + 34217984);         // 2 MB [-> V proj]
  u16* WotH  = (u16*)(W + 36315136);         // 2 MB [-> final gemm]
  u16* kbf   = (u16*)(W + 38412288);         // 4 MB
  u16* vbf   = (u16*)(W + 42606592);         // 4 MB
  u16* merged= (u16*)(W + 46800896);         // 4 MB

  dim3 b256(256);
  split_kernel<<<8192, b256, 0, stream>>>(x, xh, xl, kT * kHID);
  dim3 tg(32, 32);
  tsplit_kernel<<<tg, b256, 0, stream>>>(Wq, WqtH, WqtL, kHID, kHID);
  tsplit_kernel<<<tg, b256, 0, stream>>>(Wk, WktH, WktL, kHID, kHID);
  tsplit_kernel<<<tg, b256, 0, stream>>>(Wv, WvtH, nullptr, kHID, kHID);
  tsplit_kernel<<<tg, b256, 0, stream>>>(Wo, WotH, nullptr, kHID, kHID);

  dim3 gg(16, 32);
  gemm3_bf16<<<gg, b256, 0, stream>>>(xh, xl, WktH, WktL, k, kbf, kT, kHID, kHID);
  gemm3_bf16<<<gg, b256, 0, stream>>>(xh, xl, WqtH, WqtL, q, nullptr, kT, kHID, kHID);
  gemm_bf16<<<gg, b256, 0, stream>>>(xh, WvtH, nullptr, vbf, kT, kHID, kHID);

  // strategy gate (uses xh before it is overwritten; Wst reuses dead WktL region)
  wst_kernel<<<256, b256, 0, stream>>>(Wsp, Wst);
  strat_gemm<<<32, b256, 0, stream>>>(xh, Wst, bsp, strat);

  // compress path
  tsplit_kernel<<<dim3(2, 128), b256, 0, stream>>>(Wc, WctH, WctL, 4096, 64);
  gsplit_kernel<<<2048, b256, 0, stream>>>(k, Agh, Agl);
  vgather_kernel<<<1024, b256, 0, stream>>>(vbf, vbg);
  cgemm_splitk<<<dim3(1, 8, 8), b256, 0, stream>>>(Agh, Agl, WctH, WctL, Pk, 1);
  cgemm_splitk<<<dim3(1, 8, 8), b256, 0, stream>>>(vbg, nullptr, WctH, nullptr, Pv, 0);
  creduce_kernel<<<256, b256, 0, stream>>>(Pk, Pv, bc, kchb, kclb, vctb);

  slide_mfma<<<dim3(32, kH), b256, 0, stream>>>(q, kbf, vbf, strat, merged);
  impcomp_mfma<<<dim3(32, kH), b256, 0, stream>>>(q, kchb, kclb, vctb, strat, imp, merged);
  blocksel_kernel<<<128, b256, 0, stream>>>(imp, kscale, kbias, maskb, krb, neb, dkb);
  finalize_kernel<<<1, 512, 0, stream>>>(dkb, krb, neb, out);
  fine_mfma<<<dim3(kNB, kH), b256, 0, stream>>>(q, kbf, vbf, strat, maskb, merged);
  gemm_bf16<<<gg, b256, 0, stream>>>(merged, WotH, out, nullptr, kT, kHID, kHID);
}

// Round 5
// 164.332 us; speedup vs baseline: 6.2611x; 1.0876x over previous
//
#include <hip/hip_runtime.h>
#include <math.h>
#include <stdint.h>

typedef unsigned short u16;
typedef short v8s __attribute__((ext_vector_type(8)));
typedef float v4f __attribute__((ext_vector_type(4)));

constexpr int kT   = 2048;
constexpr int kHID = 1024;
constexpr int kH   = 16;
constexpr int kNB  = 32;
constexpr size_t MB = 1ull << 20;

__device__ __forceinline__ float b2f(u16 u) { unsigned x = ((unsigned)u) << 16; return __uint_as_float(x); }
__device__ __forceinline__ u16 f2b(float f) {
  unsigned x = __float_as_uint(f);
  x += 0x7FFFu + ((x >> 16) & 1u);
  return (u16)(x >> 16);
}
__device__ __forceinline__ v4f mfma16(v8s a, v8s b, v4f c) {
  return __builtin_amdgcn_mfma_f32_16x16x32_bf16(a, b, c, 0, 0, 0);
}
__device__ __forceinline__ void gl_lds16(const void* g, void* l) {
  __builtin_amdgcn_global_load_lds((const __attribute__((address_space(1))) uint32_t*)g,
                                   (__attribute__((address_space(3))) uint32_t*)l, 16, 0, 0);
}

// ---------------- fp32 -> (hi,lo) bf16 split ----------------
__global__ __launch_bounds__(256) void split_kernel(const float* __restrict__ in,
                                                    u16* __restrict__ hi, u16* __restrict__ lo, int n) {
  int i = blockIdx.x * 256 + threadIdx.x;
  if (i < n) {
    float x = in[i];
    u16 h = f2b(x);
    hi[i] = h;
    lo[i] = f2b(x - b2f(h));
  }
}

// ---------------- W[K][N] fp32 -> out[N][K] bf16 (hi, optional lo) ----------------
__global__ __launch_bounds__(256) void tsplit_kernel(const float* __restrict__ W,
                                                     u16* __restrict__ Hh, u16* __restrict__ Ll,
                                                     int Kd, int Nd) {
  __shared__ float t[32][33];
  const int bx = blockIdx.x * 32, by = blockIdx.y * 32;  // bx: n, by: k
  const int lx = threadIdx.x & 31, ly = threadIdx.x >> 5;
  for (int i = ly; i < 32; i += 8) t[i][lx] = W[(size_t)(by + i) * Nd + bx + lx];
  __syncthreads();
  for (int i = ly; i < 32; i += 8) {
    float x = t[lx][i];                 // = W[by+lx][bx+i]
    size_t idx = (size_t)(bx + i) * Kd + by + lx;
    u16 h = f2b(x);
    Hh[idx] = h;
    if (Ll) Ll[idx] = f2b(x - b2f(h));
  }
}

// ---- Ws (1024,48) fp32 -> Wst (64,1024) bf16, rows 48..63 zero ----
__global__ __launch_bounds__(256) void wst_kernel(const float* __restrict__ Ws, u16* __restrict__ Wst) {
  int i = blockIdx.x * 256 + threadIdx.x;   // 65536
  int n = i >> 10, k2 = i & 1023;
  float v = (n < 48) ? Ws[(size_t)k2 * 48 + n] : 0.f;
  Wst[(size_t)n * 1024 + k2] = f2b(v);
}

// ==== Q/K projection, 3-combo split, BM=128 BN=64 BK=64; fused epilogues ====
// z=0: K -> kbf (bf16) + Agh/Agl (compress-A scatter, hi/lo)
// z=1: Q -> qh/ql (bf16 hi/lo)
__global__ __launch_bounds__(256) void qkproj_gemm(const u16* __restrict__ xh, const u16* __restrict__ xl,
                                                   const u16* __restrict__ WkH, const u16* __restrict__ WkL,
                                                   const u16* __restrict__ WqH, const u16* __restrict__ WqL,
                                                   u16* __restrict__ kbf, u16* __restrict__ Agh,
                                                   u16* __restrict__ Agl, u16* __restrict__ qh,
                                                   u16* __restrict__ ql) {
  __shared__ u16 AsH[128 * 64], AsL[128 * 64], BsH[64 * 64], BsL[64 * 64];
  const int bm = blockIdx.y * 128, bn = blockIdx.x * 64;
  const int isK = (blockIdx.z == 0);
  const u16* Bh = isK ? WkH : WqH;
  const u16* Bl = isK ? WkL : WqL;
  const int tid = threadIdx.x, w = tid >> 6, lane = tid & 63;
  const int lg = lane >> 4, l16 = lane & 15;
  const int K = kHID;
  v4f acc[2][4] = {};
  for (int k0 = 0; k0 < K; k0 += 64) {
    __syncthreads();
#pragma unroll
    for (int p = 0; p < 4; ++p) {
      int s = tid + p * 256, row = s >> 3, sf = (s & 7) ^ (row & 7);
      gl_lds16(xh + (size_t)(bm + row) * K + k0 + sf * 8, (char*)AsH + s * 16);
      gl_lds16(xl + (size_t)(bm + row) * K + k0 + sf * 8, (char*)AsL + s * 16);
    }
#pragma unroll
    for (int p = 0; p < 2; ++p) {
      int s = tid + p * 256, row = s >> 3, sf = (s & 7) ^ (row & 7);
      gl_lds16(Bh + (size_t)(bn + row) * K + k0 + sf * 8, (char*)BsH + s * 16);
      gl_lds16(Bl + (size_t)(bn + row) * K + k0 + sf * 8, (char*)BsL + s * 16);
    }
    __syncthreads();
    v8s ah[2][2], al[2][2], bh[4][2], bl[4][2];
#pragma unroll
    for (int i = 0; i < 2; ++i)
#pragma unroll
      for (int kk = 0; kk < 2; ++kk) {
        int row = w * 32 + i * 16 + l16;
        int ao = row * 128 + (((kk * 4 + lg) ^ (row & 7)) * 16);
        ah[i][kk] = *(const v8s*)((const char*)AsH + ao);
        al[i][kk] = *(const v8s*)((const char*)AsL + ao);
      }
#pragma unroll
    for (int j = 0; j < 4; ++j)
#pragma unroll
      for (int kk = 0; kk < 2; ++kk) {
        int col = j * 16 + l16;
        int bo = col * 128 + (((kk * 4 + lg) ^ (col & 7)) * 16);
        bh[j][kk] = *(const v8s*)((const char*)BsH + bo);
        bl[j][kk] = *(const v8s*)((const char*)BsL + bo);
      }
#pragma unroll
    for (int i = 0; i < 2; ++i)
#pragma unroll
      for (int j = 0; j < 4; ++j)
#pragma unroll
        for (int kk = 0; kk < 2; ++kk) {
          acc[i][j] = mfma16(ah[i][kk], bh[j][kk], acc[i][j]);
          acc[i][j] = mfma16(ah[i][kk], bl[j][kk], acc[i][j]);
          acc[i][j] = mfma16(al[i][kk], bh[j][kk], acc[i][j]);
        }
  }
#pragma unroll
  for (int i = 0; i < 2; ++i)
#pragma unroll
    for (int j = 0; j < 4; ++j)
#pragma unroll
      for (int r = 0; r < 4; ++r) {
        int row = bm + w * 32 + i * 16 + lg * 4 + r;   // t
        int col = bn + j * 16 + l16;                   // n = h*64+d
        float val = acc[i][j][r];
        u16 hh = f2b(val);
        u16 ll = f2b(val - b2f(hh));
        if (isK) {
          kbf[(size_t)row * kHID + col] = hh;
          size_t ai = ((size_t)(col >> 6) * 32 + (row >> 6)) * 4096 + (size_t)(row & 63) * 64 + (col & 63);
          Agh[ai] = hh;
          Agl[ai] = ll;
        } else {
          qh[(size_t)row * kHID + col] = hh;
          ql[(size_t)row * kHID + col] = ll;
        }
      }
}

// ==== single-combo GEMM, BM=128 BN=64; outputs: fp32 / bf16 / compress-scatter ====
__global__ __launch_bounds__(256) void gemm1_128(const u16* __restrict__ A, const u16* __restrict__ Bt,
                                                 float* __restrict__ Cf, u16* __restrict__ Cbf,
                                                 u16* __restrict__ Cscat) {
  __shared__ u16 As[128 * 64], Bs[64 * 64];
  const int bm = blockIdx.y * 128, bn = blockIdx.x * 64;
  const int tid = threadIdx.x, w = tid >> 6, lane = tid & 63;
  const int lg = lane >> 4, l16 = lane & 15;
  const int K = kHID;
  v4f acc[2][4] = {};
  for (int k0 = 0; k0 < K; k0 += 64) {
    __syncthreads();
#pragma unroll
    for (int p = 0; p < 4; ++p) {
      int s = tid + p * 256, row = s >> 3, sf = (s & 7) ^ (row & 7);
      gl_lds16(A + (size_t)(bm + row) * K + k0 + sf * 8, (char*)As + s * 16);
    }
#pragma unroll
    for (int p = 0; p < 2; ++p) {
      int s = tid + p * 256, row = s >> 3, sf = (s & 7) ^ (row & 7);
      gl_lds16(Bt + (size_t)(bn + row) * K + k0 + sf * 8, (char*)Bs + s * 16);
    }
    __syncthreads();
    v8s a[2][2], b[4][2];
#pragma unroll
    for (int i = 0; i < 2; ++i)
#pragma unroll
      for (int kk = 0; kk < 2; ++kk) {
        int row = w * 32 + i * 16 + l16;
        a[i][kk] = *(const v8s*)((const char*)As + row * 128 + (((kk * 4 + lg) ^ (row & 7)) * 16));
      }
#pragma unroll
    for (int j = 0; j < 4; ++j)
#pragma unroll
      for (int kk = 0; kk < 2; ++kk) {
        int col = j * 16 + l16;
        b[j][kk] = *(const v8s*)((const char*)Bs + col * 128 + (((kk * 4 + lg) ^ (col & 7)) * 16));
      }
#pragma unroll
    for (int i = 0; i < 2; ++i)
#pragma unroll
      for (int j = 0; j < 4; ++j) {
        acc[i][j] = mfma16(a[i][0], b[j][0], acc[i][j]);
        acc[i][j] = mfma16(a[i][1], b[j][1], acc[i][j]);
      }
  }
#pragma unroll
  for (int i = 0; i < 2; ++i)
#pragma unroll
    for (int j = 0; j < 4; ++j)
#pragma unroll
      for (int r = 0; r < 4; ++r) {
        int row = bm + w * 32 + i * 16 + lg * 4 + r;
        int col = bn + j * 16 + l16;
        float val = acc[i][j][r];
        if (Cf) Cf[(size_t)row * kHID + col] = val;
        if (Cbf) Cbf[(size_t)row * kHID + col] = f2b(val);
        if (Cscat) {
          size_t ai = ((size_t)(col >> 6) * 32 + (row >> 6)) * 4096 + (size_t)(row & 63) * 64 + (col & 63);
          Cscat[ai] = f2b(val);
        }
      }
}

// ---- strategy GEMM: strat(T,48) = sigmoid(x @ Ws + bs), A=xh, Bt=Wst(64,1024) ----
__global__ __launch_bounds__(256) void strat_gemm(const u16* __restrict__ A, const u16* __restrict__ Bt,
                                                  const float* __restrict__ bsp, float* __restrict__ strat) {
  __shared__ u16 As[64 * 64];
  __shared__ u16 Bs[64 * 64];
  const int bm = blockIdx.x * 64;
  const int tid = threadIdx.x;
  const int w = tid >> 6, lane = tid & 63;
  const int lg = lane >> 4, l16 = lane & 15;
  const int wr = w >> 1, wc = w & 1;
  const int K = 1024;
  v4f acc[2][2] = {};
  for (int k0 = 0; k0 < K; k0 += 64) {
    __syncthreads();
#pragma unroll
    for (int ss = 0; ss < 2; ++ss) {
      int s = tid + ss * 256, row = s >> 3, sf = (s & 7) ^ (row & 7);
      gl_lds16(A + (size_t)(bm + row) * K + k0 + sf * 8, (char*)As + s * 16);
      gl_lds16(Bt + (size_t)row * K + k0 + sf * 8, (char*)Bs + s * 16);
    }
    __syncthreads();
    v8s a[2][2], b[2][2];
#pragma unroll
    for (int i = 0; i < 2; ++i)
#pragma unroll
      for (int kk = 0; kk < 2; ++kk) {
        int row = wr * 32 + i * 16 + l16;
        a[i][kk] = *(const v8s*)((const char*)As + row * 128 + (((kk * 4 + lg) ^ (row & 7)) * 16));
        int col = wc * 32 + i * 16 + l16;
        b[i][kk] = *(const v8s*)((const char*)Bs + col * 128 + (((kk * 4 + lg) ^ (col & 7)) * 16));
      }
#pragma unroll
    for (int i = 0; i < 2; ++i)
#pragma unroll
      for (int j = 0; j < 2; ++j) {
        acc[i][j] = mfma16(a[i][0], b[j][0], acc[i][j]);
        acc[i][j] = mfma16(a[i][1], b[j][1], acc[i][j]);
      }
  }
#pragma unroll
  for (int i = 0; i < 2; ++i)
#pragma unroll
    for (int j = 0; j < 2; ++j)
#pragma unroll
      for (int r = 0; r < 4; ++r) {
        int row = bm + wr * 32 + i * 16 + lg * 4 + r;
        int col = wc * 32 + j * 16 + l16;
        if (col < 48) {
          float val = acc[i][j][r] + bsp[col];
          strat[(size_t)row * 48 + col] = 1.f / (1.f + expf(-val));
        }
      }
}

// ---- compress GEMM, split-K partials: P[ks][512][64]; three-combo optional ----
__global__ __launch_bounds__(256) void cgemm_splitk(const u16* __restrict__ Ah, const u16* __restrict__ Al,
                                                    const u16* __restrict__ Bh, const u16* __restrict__ Bl,
                                                    float* __restrict__ P, int three) {
  __shared__ u16 AsH[64 * 64], BsH[64 * 64], AsL[64 * 64], BsL[64 * 64];
  const int bm = blockIdx.y * 64;
  const int ks = blockIdx.z;
  const int K = 4096;
  const int tid = threadIdx.x;
  const int w = tid >> 6, lane = tid & 63;
  const int lg = lane >> 4, l16 = lane & 15;
  const int wr = w >> 1, wc = w & 1;
  v4f acc[2][2] = {};
  for (int k0 = ks * 512; k0 < ks * 512 + 512; k0 += 64) {
    __syncthreads();
#pragma unroll
    for (int ss = 0; ss < 2; ++ss) {
      int s = tid + ss * 256, row = s >> 3, sf = (s & 7) ^ (row & 7);
      gl_lds16(Ah + (size_t)(bm + row) * K + k0 + sf * 8, (char*)AsH + s * 16);
      gl_lds16(Bh + (size_t)row * K + k0 + sf * 8, (char*)BsH + s * 16);
      if (three) {
        gl_lds16(Al + (size_t)(bm + row) * K + k0 + sf * 8, (char*)AsL + s * 16);
        gl_lds16(Bl + (size_t)row * K + k0 + sf * 8, (char*)BsL + s * 16);
      }
    }
    __syncthreads();
    v8s ah[2][2], bh[2][2];
#pragma unroll
    for (int i = 0; i < 2; ++i)
#pragma unroll
      for (int kk = 0; kk < 2; ++kk) {
        int row = wr * 32 + i * 16 + l16;
        ah[i][kk] = *(const v8s*)((const char*)AsH + row * 128 + (((kk * 4 + lg) ^ (row & 7)) * 16));
        int col = wc * 32 + i * 16 + l16;
        bh[i][kk] = *(const v8s*)((const char*)BsH + col * 128 + (((kk * 4 + lg) ^ (col & 7)) * 16));
      }
#pragma unroll
    for (int i = 0; i < 2; ++i)
#pragma unroll
      for (int j = 0; j < 2; ++j) {
        acc[i][j] = mfma16(ah[i][0], bh[j][0], acc[i][j]);
        acc[i][j] = mfma16(ah[i][1], bh[j][1], acc[i][j]);
      }
    if (three) {
      v8s al[2][2], bl[2][2];
#pragma unroll
      for (int i = 0; i < 2; ++i)
#pragma unroll
        for (int kk = 0; kk < 2; ++kk) {
          int row = wr * 32 + i * 16 + l16;
          al[i][kk] = *(const v8s*)((const char*)AsL + row * 128 + (((kk * 4 + lg) ^ (row & 7)) * 16));
          int col = wc * 32 + i * 16 + l16;
          bl[i][kk] = *(const v8s*)((const char*)BsL + col * 128 + (((kk * 4 + lg) ^ (col & 7)) * 16));
        }
#pragma unroll
      for (int i = 0; i < 2; ++i)
#pragma unroll
        for (int j = 0; j < 2; ++j)
#pragma unroll
          for (int kk = 0; kk < 2; ++kk) {
            acc[i][j] = mfma16(ah[i][kk], bl[j][kk], acc[i][j]);
            acc[i][j] = mfma16(al[i][kk], bh[j][kk], acc[i][j]);
          }
    }
  }
#pragma unroll
  for (int i = 0; i < 2; ++i)
#pragma unroll
    for (int j = 0; j < 2; ++j)
#pragma unroll
      for (int r = 0; r < 4; ++r) {
        int row = bm + wr * 32 + i * 16 + lg * 4 + r;
        int col = wc * 32 + j * 16 + l16;
        P[(size_t)ks * 32768 + (size_t)row * 64 + col] = acc[i][j][r];
      }
}

// ---- reduce split-K + bias + exact-erf GELU -> kch/kcl (hi/lo bf16), vct (bf16 transposed) ----
__global__ __launch_bounds__(256) void creduce_kernel(const float* __restrict__ Pk,
                                                      const float* __restrict__ Pv,
                                                      const float* __restrict__ bc,
                                                      u16* __restrict__ kch, u16* __restrict__ kcl,
                                                      u16* __restrict__ vct) {
  int idx = blockIdx.x * 256 + threadIdx.x;   // 0..65535
  int which = idx >> 15;
  int e = idx & 32767;
  const float* P = which ? Pv : Pk;
  float s = 0.f;
#pragma unroll
  for (int ks = 0; ks < 8; ++ks) s += P[(size_t)ks * 32768 + e];
  s += bc[e & 63];
  float g = 0.5f * s * (1.f + erff(s * 0.70710678118654752f));
  if (!which) {
    u16 hh = f2b(g);
    kch[e] = hh;
    kcl[e] = f2b(g - b2f(hh));
  } else {
    int h2 = e >> 11, j = (e >> 6) & 31, d = e & 63;
    vct[(size_t)h2 * 2048 + d * 32 + j] = f2b(g);
  }
}

// ------- importance (hi/lo MFMA, fp32-accurate) + compressed attn; merged = st1*comp -------
__global__ __launch_bounds__(256) void impcomp_mfma(const u16* __restrict__ qh,
                                                    const u16* __restrict__ ql,
                                                    const u16* __restrict__ kch,
                                                    const u16* __restrict__ kcl,
                                                    const u16* __restrict__ vct,
                                                    const float* __restrict__ strat,
                                                    float* __restrict__ imp,
                                                    u16* __restrict__ merged) {
  __shared__ u16 Pl[4][16 * 32];
  const int tt = blockIdx.x, h = blockIdx.y;
  const int tid = threadIdx.x, w = tid >> 6, lane = tid & 63;
  const int lg = lane >> 4, l16 = lane & 15;
  const size_t qoff = (size_t)(tt * 64 + w * 16 + l16) * kHID + h * 64;
  v8s ah[2], al[2];
  ah[0] = *(const v8s*)(qh + qoff + lg * 8);
  ah[1] = *(const v8s*)(qh + qoff + 32 + lg * 8);
  al[0] = *(const v8s*)(ql + qoff + lg * 8);
  al[1] = *(const v8s*)(ql + qoff + 32 + lg * 8);
  v4f sa[2] = {};
#pragma unroll
  for (int ct = 0; ct < 2; ++ct) {
    int col = ct * 16 + l16;
#pragma unroll
    for (int kk = 0; kk < 2; ++kk) {
      v8s bh = *(const v8s*)(kch + ((size_t)h * 32 + col) * 64 + kk * 32 + lg * 8);
      v8s bl = *(const v8s*)(kcl + ((size_t)h * 32 + col) * 64 + kk * 32 + lg * 8);
      sa[ct] = mfma16(ah[kk], bh, sa[ct]);
      sa[ct] = mfma16(ah[kk], bl, sa[ct]);
      sa[ct] = mfma16(al[kk], bh, sa[ct]);
    }
  }
#pragma unroll
  for (int ct = 0; ct < 2; ++ct)
#pragma unroll
    for (int j = 0; j < 4; ++j) sa[ct][j] *= 0.125f;
#pragma unroll
  for (int j = 0; j < 4; ++j) {
    int t = tt * 64 + w * 16 + lg * 4 + j;
    imp[((size_t)h * kT + t) * kNB + l16] = sa[0][j];
    imp[((size_t)h * kT + t) * kNB + 16 + l16] = sa[1][j];
  }
  float linv[4];
#pragma unroll
  for (int j = 0; j < 4; ++j) {
    float m = fmaxf(sa[0][j], sa[1][j]);
#pragma unroll
    for (int mm = 1; mm < 16; mm <<= 1) m = fmaxf(m, __shfl_xor(m, mm, 64));
    float e0 = __expf(sa[0][j] - m), e1 = __expf(sa[1][j] - m);
    float s = e0 + e1;
#pragma unroll
    for (int mm = 1; mm < 16; mm <<= 1) s += __shfl_xor(s, mm, 64);
    linv[j] = 1.f / s;
    int row = lg * 4 + j;
    Pl[w][row * 32 + l16] = f2b(e0);
    Pl[w][row * 32 + 16 + l16] = f2b(e1);
  }
  v8s pa = *(const v8s*)(&Pl[w][l16 * 32 + lg * 8]);
  v4f o[4] = {};
#pragma unroll
  for (int dt = 0; dt < 4; ++dt) {
    v8s b = *(const v8s*)(vct + ((size_t)h * 64 + dt * 16 + l16) * 32 + lg * 8);
    o[dt] = mfma16(pa, b, o[dt]);
  }
#pragma unroll
  for (int dt = 0; dt < 4; ++dt)
#pragma unroll
    for (int j = 0; j < 4; ++j) {
      int t = tt * 64 + w * 16 + lg * 4 + j;
      int d = dt * 16 + l16;
      size_t mi = (size_t)t * kHID + h * 64 + d;
      float val = o[dt][j] * linv[j];
      merged[mi] = f2b(strat[t * 48 + h * 3 + 1] * val);   // pure write (first pass)
    }
}

// ------- block scores -> softmax/entropy/dynamic_k/top-k mask per (h,qblk) -------
__global__ __launch_bounds__(256) void blocksel_kernel(const float* __restrict__ imp,
                                                       const float* __restrict__ kscale_p,
                                                       const float* __restrict__ kbias_p,
                                                       unsigned* __restrict__ maskb,
                                                       float* __restrict__ krb,
                                                       float* __restrict__ neb,
                                                       int* __restrict__ dkb) {
  const int gw = blockIdx.x * 4 + (threadIdx.x >> 6);
  const int lane = threadIdx.x & 63;
  const int h = gw >> 5, qb = gw & 31;
  const int j = lane & 31, half = lane >> 5;
  float acc = 0.f;
#pragma unroll 4
  for (int s2 = 0; s2 < 32; ++s2) {
    int s = half * 32 + s2;
    acc += imp[((size_t)h * kT + qb * 64 + s) * kNB + j];
  }
  acc += __shfl_xor(acc, 32, 64);
  float bsj = acc * (1.f / 64.f);
  float mx = bsj;
#pragma unroll
  for (int m = 1; m < 32; m <<= 1) mx = fmaxf(mx, __shfl_xor(mx, m, 64));
  float e = expf(bsj - mx);
  float lsum = e;
#pragma unroll
  for (int m = 1; m < 32; m <<= 1) lsum += __shfl_xor(lsum, m, 64);
  float p = e / lsum;
  float ent = p * logf(p + 1e-9f);
#pragma unroll
  for (int m = 1; m < 32; m <<= 1) ent += __shfl_xor(ent, m, 64);
  ent = -ent;
  float ne = ent / (logf(32.f) + 1e-9f);
  float kr = 1.f / (1.f + expf(-(kscale_p[0] * ne + kbias_p[0])));
  int dk = (int)fminf(fmaxf(8.f * kr, 1.f), 8.f);
  unsigned mword = 1u << qb;
  int taken = 0;
  for (int r = 0; r < dk; ++r) {
    float v2 = taken ? -3.4e38f : bsj;
    int idx2 = j;
#pragma unroll
    for (int m = 1; m < 32; m <<= 1) {
      float ov = __shfl_xor(v2, m, 64);
      int oi = __shfl_xor(idx2, m, 64);
      if (ov > v2 || (ov == v2 && oi < idx2)) { v2 = ov; idx2 = oi; }
    }
    mword |= (1u << idx2);
    if (j == idx2) taken = 1;
  }
  if (lane == 0) {
    maskb[h * kNB + qb] = mword;
    krb[h * kNB + qb] = kr;
    neb[h * kNB + qb] = ne;
    dkb[h * kNB + qb] = dk;
  }
}

// ---------------- scalar outputs: avg_k, aux_loss ----------------
__global__ void finalize_kernel(const int* __restrict__ dkb, const float* __restrict__ krb,
                                const float* __restrict__ neb, float* __restrict__ out) {
  __shared__ float s1[512], s2[512], s3[512];
  int t2 = threadIdx.x;
  float fdk = (float)dkb[t2], kr = krb[t2], ne = neb[t2];
  float d = kr - ne;
  s1[t2] = fdk; s2[t2] = d * d; s3[t2] = kr;
  __syncthreads();
  for (int st = 256; st > 0; st >>= 1) {
    if (t2 < st) { s1[t2] += s1[t2 + st]; s2[t2] += s2[t2 + st]; s3[t2] += s3[t2 + st]; }
    __syncthreads();
  }
  if (t2 == 0) {
    out[(size_t)kT * kHID + 0] = s1[0] * (1.f / 512.f);
    out[(size_t)kT * kHID + 1] = 0.01f * (s2[0] * (1.f / 512.f)) + 0.01f * (s3[0] * (1.f / 512.f));
  }
}

// ------- merged fine (block-sparse) + sliding attention; merged += st0*slide + st2*fine -------
__global__ __launch_bounds__(256) void fineslide_mfma(const u16* __restrict__ qh,
                                                      const u16* __restrict__ kb_,
                                                      const u16* __restrict__ vb_,
                                                      const float* __restrict__ strat,
                                                      const unsigned* __restrict__ maskb,
                                                      u16* __restrict__ merged) {
  __shared__ u16 Kb[64 * 64];
  __shared__ u16 Vt[64 * 64];
  __shared__ u16 Pl[4][16 * 64];
  const int qb = blockIdx.x, h = blockIdx.y;
  const unsigned mword = maskb[h * kNB + qb];
  unsigned uni = mword | (1u << qb);
  if (qb > 0) uni |= 1u << (qb - 1);
  const int tid = threadIdx.x, w = tid >> 6, lane = tid & 63;
  const int lg = lane >> 4, l16 = lane & 15;
  v8s aq[2];
  {
    const u16* qrow = qh + (size_t)(qb * 64 + w * 16 + l16) * kHID + h * 64;
    aq[0] = *(const v8s*)(qrow + lg * 8);
    aq[1] = *(const v8s*)(qrow + 32 + lg * 8);
  }
  float mF[4], lF[4], mS[4], lS[4];
  v4f oF[4] = {}, oS[4] = {};
#pragma unroll
  for (int j = 0; j < 4; ++j) { mF[j] = -1e30f; lF[j] = 0.f; mS[j] = -1e30f; lS[j] = 0.f; }

  auto upd = [&](v4f* sa, float* m_run, float* l_run, v4f* o_acc) {
    float corr[4];
#pragma unroll
    for (int j = 0; j < 4; ++j) {
      float t = fmaxf(fmaxf(sa[0][j], sa[1][j]), fmaxf(sa[2][j], sa[3][j]));
#pragma unroll
      for (int mm = 1; mm < 16; mm <<= 1) t = fmaxf(t, __shfl_xor(t, mm, 64));
      float mn = fmaxf(m_run[j], t);
      corr[j] = __expf(m_run[j] - mn);
      m_run[j] = mn;
    }
    float rs[4] = {0.f, 0.f, 0.f, 0.f};
    float pv[4][4];
#pragma unroll
    for (int ct = 0; ct < 4; ++ct)
#pragma unroll
      for (int j = 0; j < 4; ++j) {
        float e = __expf(sa[ct][j] - m_run[j]);
        pv[ct][j] = e;
        rs[j] += e;
      }
#pragma unroll
    for (int j = 0; j < 4; ++j) {
#pragma unroll
      for (int mm = 1; mm < 16; mm <<= 1) rs[j] += __shfl_xor(rs[j], mm, 64);
      l_run[j] = l_run[j] * corr[j] + rs[j];
    }
#pragma unroll
    for (int ct = 0; ct < 4; ++ct)
#pragma unroll
      for (int j = 0; j < 4; ++j) {
        int row = lg * 4 + j;
        int seg = ct * 2 + (l16 >> 3);
        *((u16*)((char*)Pl + w * 2048 + row * 128 + ((seg ^ (row & 7)) * 16)) + (l16 & 7)) = f2b(pv[ct][j]);
      }
#pragma unroll
    for (int dt = 0; dt < 4; ++dt)
#pragma unroll
      for (int j = 0; j < 4; ++j) o_acc[dt][j] *= corr[j];
#pragma unroll
    for (int dt = 0; dt < 4; ++dt) {
      int d = dt * 16 + l16;
#pragma unroll
      for (int kk = 0; kk < 2; ++kk) {
        v8s pa = *(const v8s*)((const char*)Pl + w * 2048 + l16 * 128 + (((kk * 4 + lg) ^ (l16 & 7)) * 16));
        v8s vb2 = *(const v8s*)((const char*)Vt + d * 128 + (((kk * 4 + lg) ^ (d & 7)) * 16));
        o_acc[dt] = mfma16(pa, vb2, o_acc[dt]);
      }
    }
  };

  for (int jb = 0; jb < 32; ++jb) {
    if (!((uni >> jb) & 1u)) continue;
    __syncthreads();
#pragma unroll
    for (int ss = 0; ss < 2; ++ss) {
      int s = tid + ss * 256;
      int key = s >> 3, sf = (s & 7) ^ (key & 7);
      *(uint4*)((char*)Kb + s * 16) =
          *(const uint4*)(kb_ + (size_t)(jb * 64 + key) * kHID + h * 64 + sf * 8);
    }
    {
      int key = tid & 63, d0 = (tid >> 6) * 16;
      const u16* vsrc = vb_ + (size_t)(jb * 64 + key) * kHID + h * 64 + d0;
      union { uint4 u[2]; u16 s[16]; } c;
      c.u[0] = *(const uint4*)(vsrc);
      c.u[1] = *(const uint4*)(vsrc + 8);
#pragma unroll
      for (int i = 0; i < 16; ++i) {
        int d = d0 + i;
        *((u16*)((char*)Vt + d * 128 + (((key >> 3) ^ (d & 7)) * 16)) + (key & 7)) = c.s[i];
      }
    }
    __syncthreads();
    v4f sa[4] = {};
#pragma unroll
    for (int ct = 0; ct < 4; ++ct) {
      int key = ct * 16 + l16;
#pragma unroll
      for (int kk = 0; kk < 2; ++kk) {
        v8s bk = *(const v8s*)((const char*)Kb + key * 128 + (((kk * 4 + lg) ^ (key & 7)) * 16));
        sa[ct] = mfma16(aq[kk], bk, sa[ct]);
      }
    }
#pragma unroll
    for (int ct = 0; ct < 4; ++ct)
#pragma unroll
      for (int j = 0; j < 4; ++j) sa[ct][j] *= 0.125f;
    const bool inF = (mword >> jb) & 1u;
    const bool inS = (jb == qb) || (jb + 1 == qb);
    if (inF) upd(sa, mF, lF, oF);
    if (inS) {
      v4f sb[4];
#pragma unroll
      for (int ct = 0; ct < 4; ++ct) sb[ct] = sa[ct];
      if (jb == qb) {
#pragma unroll
        for (int ct = 0; ct < 4; ++ct) {
          int key = ct * 16 + l16;
#pragma unroll
          for (int j = 0; j < 4; ++j) {
            int qp = w * 16 + lg * 4 + j;
            if (key > qp) sb[ct][j] = -1e30f;
          }
        }
      }
      upd(sb, mS, lS, oS);
    }
  }
#pragma unroll
  for (int dt = 0; dt < 4; ++dt)
#pragma unroll
    for (int j = 0; j < 4; ++j) {
      int row = lg * 4 + j;
      int t = qb * 64 + w * 16 + row;
      int d = dt * 16 + l16;
      size_t idx = (size_t)t * kHID + h * 64 + d;
      float add = strat[t * 48 + h * 3 + 0] * (oS[dt][j] / lS[j]) +
                  strat[t * 48 + h * 3 + 2] * (oF[dt][j] / lF[j]);
      merged[idx] = f2b(b2f(merged[idx]) + add);
    }
}

// ---------------- launch ----------------
extern "C" void kernel_launch(void* const* d_in, const int* in_sizes, int n_in,
                              void* d_out, int out_size, void* d_ws, size_t ws_size,
                              hipStream_t stream) {
  const float* x      = (const float*)d_in[0];
  const float* Wq     = (const float*)d_in[1];
  const float* Wk     = (const float*)d_in[2];
  const float* Wv     = (const float*)d_in[3];
  const float* Wo     = (const float*)d_in[4];
  const float* Wc     = (const float*)d_in[5];
  const float* bc     = (const float*)d_in[6];
  const float* kscale = (const float*)d_in[7];
  const float* kbias  = (const float*)d_in[8];
  const float* Wsp    = (const float*)d_in[9];
  const float* bsp    = (const float*)d_in[10];
  float* out = (float*)d_out;
  char* W = (char*)d_ws;

  // flat layout, ~62 MB (ws is ~268 MB per harness poison traffic)
  u16* qh     = (u16*)(W + 0 * MB);
  u16* ql     = (u16*)(W + 4 * MB);
  u16* kbf    = (u16*)(W + 8 * MB);
  u16* vbf    = (u16*)(W + 12 * MB);
  u16* vbg    = (u16*)(W + 16 * MB);
  u16* Agh    = (u16*)(W + 20 * MB);
  u16* Agl    = (u16*)(W + 24 * MB);
  u16* merged = (u16*)(W + 28 * MB);
  u16* xh     = (u16*)(W + 32 * MB);
  u16* xl     = (u16*)(W + 36 * MB);
  float* imp  = (float*)(W + 40 * MB);
  u16* WqtH   = (u16*)(W + 44 * MB);
  u16* WqtL   = (u16*)(W + 46 * MB);
  u16* WktH   = (u16*)(W + 48 * MB);
  u16* WktL   = (u16*)(W + 50 * MB);
  u16* WvtH   = (u16*)(W + 52 * MB);
  u16* WotH   = (u16*)(W + 54 * MB);
  u16* WctH   = (u16*)(W + 56 * MB);
  u16* WctL   = (u16*)(W + 56 * MB + 512 * 1024);
  u16* Wst    = (u16*)(W + 57 * MB);
  float* strat= (float*)(W + 58 * MB);
  float* Pk   = (float*)(W + 59 * MB);
  float* Pv   = (float*)(W + 60 * MB);
  u16* kchb   = (u16*)(W + 61 * MB);
  u16* kclb   = (u16*)(W + 61 * MB + 64 * 1024);
  u16* vctb   = (u16*)(W + 61 * MB + 128 * 1024);
  unsigned* maskb = (unsigned*)(W + 61 * MB + 192 * 1024);
  float* krb  = (float*)(W + 61 * MB + 196 * 1024);
  float* neb  = (float*)(W + 61 * MB + 200 * 1024);
  int*   dkb  = (int*)(W + 61 * MB + 204 * 1024);

  dim3 b256(256);
  split_kernel<<<8192, b256, 0, stream>>>(x, xh, xl, kT * kHID);
  dim3 tg(32, 32);
  tsplit_kernel<<<tg, b256, 0, stream>>>(Wq, WqtH, WqtL, kHID, kHID);
  tsplit_kernel<<<tg, b256, 0, stream>>>(Wk, WktH, WktL, kHID, kHID);
  tsplit_kernel<<<tg, b256, 0, stream>>>(Wv, WvtH, nullptr, kHID, kHID);
  tsplit_kernel<<<tg, b256, 0, stream>>>(Wo, WotH, nullptr, kHID, kHID);
  wst_kernel<<<256, b256, 0, stream>>>(Wsp, Wst);
  tsplit_kernel<<<dim3(2, 128), b256, 0, stream>>>(Wc, WctH, WctL, 4096, 64);

  // projections (Q+K fused via grid.z; 128x64 tiles)
  qkproj_gemm<<<dim3(16, 16, 2), b256, 0, stream>>>(xh, xl, WktH, WktL, WqtH, WqtL,
                                                    kbf, Agh, Agl, qh, ql);
  gemm1_128<<<dim3(16, 16), b256, 0, stream>>>(xh, WvtH, nullptr, vbf, vbg);
  strat_gemm<<<32, b256, 0, stream>>>(xh, Wst, bsp, strat);

  // compress path
  cgemm_splitk<<<dim3(1, 8, 8), b256, 0, stream>>>(Agh, Agl, WctH, WctL, Pk, 1);
  cgemm_splitk<<<dim3(1, 8, 8), b256, 0, stream>>>(vbg, nullptr, WctH, nullptr, Pv, 0);
  creduce_kernel<<<256, b256, 0, stream>>>(Pk, Pv, bc, kchb, kclb, vctb);

  // attention: comp (writes merged) -> selection -> fine+slide (RMW merged)
  impcomp_mfma<<<dim3(32, kH), b256, 0, stream>>>(qh, ql, kchb, kclb, vctb, strat, imp, merged);
  blocksel_kernel<<<128, b256, 0, stream>>>(imp, kscale, kbias, maskb, krb, neb, dkb);
  finalize_kernel<<<1, 512, 0, stream>>>(dkb, krb, neb, out);
  fineslide_mfma<<<dim3(kNB, kH), b256, 0, stream>>>(qh, kbf, vbf, strat, maskb, merged);

  // output projection
  gemm1_128<<<dim3(16, 16), b256, 0, stream>>>(merged, WotH, out, nullptr, nullptr);
}

// Round 6
// 127.024 us; speedup vs baseline: 8.1000x; 1.2937x over previous
//
#include <hip/hip_runtime.h>
#include <math.h>
#include <stdint.h>

typedef unsigned short u16;
typedef short v8s __attribute__((ext_vector_type(8)));
typedef float v4f __attribute__((ext_vector_type(4)));

constexpr int kT   = 2048;
constexpr int kHID = 1024;
constexpr int kH   = 16;
constexpr int kNB  = 32;
constexpr size_t MB = 1ull << 20;

__device__ __forceinline__ float b2f(u16 u) { unsigned x = ((unsigned)u) << 16; return __uint_as_float(x); }
__device__ __forceinline__ u16 f2b(float f) {
  unsigned x = __float_as_uint(f);
  x += 0x7FFFu + ((x >> 16) & 1u);
  return (u16)(x >> 16);
}
__device__ __forceinline__ v4f mfma16(v8s a, v8s b, v4f c) {
  return __builtin_amdgcn_mfma_f32_16x16x32_bf16(a, b, c, 0, 0, 0);
}
__device__ __forceinline__ void gl_lds16(const void* g, void* l) {
  __builtin_amdgcn_global_load_lds((const __attribute__((address_space(1))) uint32_t*)g,
                                   (__attribute__((address_space(3))) uint32_t*)l, 16, 0, 0);
}

// ==== fused prep: x hi/lo split, Wq/Wk/Wv/Wo/Wc transposes+splits, Ws pad ====
__global__ __launch_bounds__(256) void prep_kernel(
    const float* __restrict__ x, const float* __restrict__ Wq, const float* __restrict__ Wk,
    const float* __restrict__ Wv, const float* __restrict__ Wo, const float* __restrict__ Wc,
    const float* __restrict__ Wsp,
    u16* __restrict__ xh, u16* __restrict__ xl,
    u16* __restrict__ WqtH, u16* __restrict__ WqtL, u16* __restrict__ WktH, u16* __restrict__ WktL,
    u16* __restrict__ WvtH, u16* __restrict__ WotH, u16* __restrict__ WctH, u16* __restrict__ WctL,
    u16* __restrict__ Wst) {
  __shared__ float tbuf[32][33];
  int bid = blockIdx.x;
  const int tid = threadIdx.x;
  if (bid < 1024) {                        // split x: 8 elems/thread
    int i = bid * 2048 + tid * 8;
    float4 a = *(const float4*)(x + i), b = *(const float4*)(x + i + 4);
    float tv[8] = {a.x, a.y, a.z, a.w, b.x, b.y, b.z, b.w};
    union { u16 s[8]; uint4 u; } hs, ls;
#pragma unroll
    for (int e = 0; e < 8; ++e) {
      u16 h = f2b(tv[e]);
      hs.s[e] = h;
      ls.s[e] = f2b(tv[e] - b2f(h));
    }
    *(uint4*)(xh + i) = hs.u;
    *(uint4*)(xl + i) = ls.u;
    return;
  }
  bid -= 1024;
  const float* W; u16* Hh; u16* Ll; int Kd, Nd, bx, by;
  if (bid < 4096) {                        // 1024x1024 weight transposes
    int wsel = bid >> 10, sub = bid & 1023;
    W  = wsel == 0 ? Wq : wsel == 1 ? Wk : wsel == 2 ? Wv : Wo;
    Hh = wsel == 0 ? WqtH : wsel == 1 ? WktH : wsel == 2 ? WvtH : WotH;
    Ll = wsel == 0 ? WqtL : wsel == 1 ? WktL : nullptr;
    Kd = 1024; Nd = 1024;
    bx = (sub & 31) * 32; by = (sub >> 5) * 32;
  } else if (bid < 4096 + 256) {           // Wc (4096x64)
    int sub = bid - 4096;
    W = Wc; Hh = WctH; Ll = WctL;
    Kd = 4096; Nd = 64;
    bx = (sub & 1) * 32; by = (sub >> 1) * 32;
  } else {                                 // Wst pad: 64x1024
    int i = (bid - 4096 - 256) * 256 + tid;
    int n = i >> 10, k2 = i & 1023;
    float v = (n < 48) ? Wsp[(size_t)k2 * 48 + n] : 0.f;
    Wst[(size_t)n * 1024 + k2] = f2b(v);
    return;
  }
  const int lx = tid & 31, ly = tid >> 5;
  for (int i2 = ly; i2 < 32; i2 += 8) tbuf[i2][lx] = W[(size_t)(by + i2) * Nd + bx + lx];
  __syncthreads();
  for (int i2 = ly; i2 < 32; i2 += 8) {
    float xv = tbuf[lx][i2];
    size_t idx = (size_t)(bx + i2) * Kd + by + lx;
    u16 h = f2b(xv);
    Hh[idx] = h;
    if (Ll) Ll[idx] = f2b(xv - b2f(h));
  }
}

// ==== unified projection GEMM, BM=128 BN=64 BK=64
// z=0: K 3-combo -> kbf(hi) + klbf(lo) row-major
// z=1: Q 3-combo -> qh + ql
// z=2: V single  -> vbf
// z=3: strat single (bx==0 only) -> sigmoid epilogue
__global__ __launch_bounds__(256) void proj_gemm(const u16* __restrict__ xh, const u16* __restrict__ xl,
                                                 const u16* __restrict__ WkH, const u16* __restrict__ WkL,
                                                 const u16* __restrict__ WqH, const u16* __restrict__ WqL,
                                                 const u16* __restrict__ WvH, const u16* __restrict__ Wst,
                                                 const float* __restrict__ bsp,
                                                 u16* __restrict__ kbf, u16* __restrict__ klbf,
                                                 u16* __restrict__ qh, u16* __restrict__ ql,
                                                 u16* __restrict__ vbf, float* __restrict__ strat) {
  __shared__ u16 AsH[128 * 64], AsL[128 * 64], BsH[64 * 64], BsL[64 * 64];
  const int z = blockIdx.z;
  if (z == 3 && blockIdx.x) return;
  const int bm = blockIdx.y * 128, bn = blockIdx.x * 64;
  const int three = (z < 2);
  const u16* Bh = (z == 0) ? WkH : (z == 1) ? WqH : (z == 2) ? WvH : Wst;
  const u16* Bl = (z == 0) ? WkL : WqL;
  const int tid = threadIdx.x, w = tid >> 6, lane = tid & 63;
  const int lg = lane >> 4, l16 = lane & 15;
  const int K = kHID;
  v4f acc[2][4] = {};
  for (int k0 = 0; k0 < K; k0 += 64) {
    __syncthreads();
#pragma unroll
    for (int p = 0; p < 4; ++p) {
      int s = tid + p * 256, row = s >> 3, sf = (s & 7) ^ (row & 7);
      gl_lds16(xh + (size_t)(bm + row) * K + k0 + sf * 8, (char*)AsH + s * 16);
      if (three) gl_lds16(xl + (size_t)(bm + row) * K + k0 + sf * 8, (char*)AsL + s * 16);
    }
#pragma unroll
    for (int p = 0; p < 2; ++p) {
      int s = tid + p * 256, row = s >> 3, sf = (s & 7) ^ (row & 7);
      gl_lds16(Bh + (size_t)(bn + row) * K + k0 + sf * 8, (char*)BsH + s * 16);
      if (three) gl_lds16(Bl + (size_t)(bn + row) * K + k0 + sf * 8, (char*)BsL + s * 16);
    }
    __syncthreads();
    v8s ah[2][2], al[2][2], bh[4][2], bl[4][2];
#pragma unroll
    for (int i = 0; i < 2; ++i)
#pragma unroll
      for (int kk = 0; kk < 2; ++kk) {
        int row = w * 32 + i * 16 + l16;
        int ao = row * 128 + (((kk * 4 + lg) ^ (row & 7)) * 16);
        ah[i][kk] = *(const v8s*)((const char*)AsH + ao);
        if (three) al[i][kk] = *(const v8s*)((const char*)AsL + ao);
      }
#pragma unroll
    for (int j = 0; j < 4; ++j)
#pragma unroll
      for (int kk = 0; kk < 2; ++kk) {
        int col = j * 16 + l16;
        int bo = col * 128 + (((kk * 4 + lg) ^ (col & 7)) * 16);
        bh[j][kk] = *(const v8s*)((const char*)BsH + bo);
        if (three) bl[j][kk] = *(const v8s*)((const char*)BsL + bo);
      }
#pragma unroll
    for (int i = 0; i < 2; ++i)
#pragma unroll
      for (int j = 0; j < 4; ++j)
#pragma unroll
        for (int kk = 0; kk < 2; ++kk) {
          acc[i][j] = mfma16(ah[i][kk], bh[j][kk], acc[i][j]);
          if (three) {
            acc[i][j] = mfma16(ah[i][kk], bl[j][kk], acc[i][j]);
            acc[i][j] = mfma16(al[i][kk], bh[j][kk], acc[i][j]);
          }
        }
  }
#pragma unroll
  for (int i = 0; i < 2; ++i)
#pragma unroll
    for (int j = 0; j < 4; ++j)
#pragma unroll
      for (int r = 0; r < 4; ++r) {
        int row = bm + w * 32 + i * 16 + lg * 4 + r;
        int col = bn + j * 16 + l16;
        float val = acc[i][j][r];
        if (z == 3) {
          if (col < 48) strat[(size_t)row * 48 + col] = 1.f / (1.f + expf(-(val + bsp[col])));
        } else {
          u16 hh = f2b(val);
          size_t idx = (size_t)row * kHID + col;
          if (z == 0) { kbf[idx] = hh; klbf[idx] = f2b(val - b2f(hh)); }
          else if (z == 1) { qh[idx] = hh; ql[idx] = f2b(val - b2f(hh)); }
          else vbf[idx] = hh;
        }
      }
}

// ==== compress GEMM (k 3-combo + v single fused), split-K partials, A read from row-major k/v ====
// z<8: K path, ks=z; z>=8: V path, ks=z-8
__global__ __launch_bounds__(256) void cgemm_fused(const u16* __restrict__ kbf, const u16* __restrict__ klbf,
                                                   const u16* __restrict__ vbf,
                                                   const u16* __restrict__ WcH, const u16* __restrict__ WcL,
                                                   float* __restrict__ Pk, float* __restrict__ Pv) {
  __shared__ u16 AsH[64 * 64], BsH[64 * 64], AsL[64 * 64], BsL[64 * 64];
  const int bm = blockIdx.y * 64;
  const int isK = (blockIdx.z < 8);
  const int ks = isK ? blockIdx.z : blockIdx.z - 8;
  const u16* Asrc = isK ? kbf : vbf;
  float* P = isK ? Pk : Pv;
  const int tid = threadIdx.x;
  const int w = tid >> 6, lane = tid & 63;
  const int lg = lane >> 4, l16 = lane & 15;
  const int wr = w >> 1, wc = w & 1;
  v4f acc[2][2] = {};
  for (int k0 = ks * 512; k0 < ks * 512 + 512; k0 += 64) {
    __syncthreads();
#pragma unroll
    for (int ss = 0; ss < 2; ++ss) {
      int s = tid + ss * 256, row = s >> 3, sf = (s & 7) ^ (row & 7);
      int r = bm + row;                              // (h*32+nb)
      size_t abase = ((size_t)((r & 31) * 64 + (k0 >> 6))) * kHID + (r >> 5) * 64 + sf * 8;
      gl_lds16(Asrc + abase, (char*)AsH + s * 16);
      gl_lds16(WcH + (size_t)row * 4096 + k0 + sf * 8, (char*)BsH + s * 16);
      if (isK) {
        gl_lds16(klbf + abase, (char*)AsL + s * 16);
        gl_lds16(WcL + (size_t)row * 4096 + k0 + sf * 8, (char*)BsL + s * 16);
      }
    }
    __syncthreads();
    v8s ah[2][2], bh[2][2];
#pragma unroll
    for (int i = 0; i < 2; ++i)
#pragma unroll
      for (int kk = 0; kk < 2; ++kk) {
        int row = wr * 32 + i * 16 + l16;
        ah[i][kk] = *(const v8s*)((const char*)AsH + row * 128 + (((kk * 4 + lg) ^ (row & 7)) * 16));
        int col = wc * 32 + i * 16 + l16;
        bh[i][kk] = *(const v8s*)((const char*)BsH + col * 128 + (((kk * 4 + lg) ^ (col & 7)) * 16));
      }
#pragma unroll
    for (int i = 0; i < 2; ++i)
#pragma unroll
      for (int j = 0; j < 2; ++j) {
        acc[i][j] = mfma16(ah[i][0], bh[j][0], acc[i][j]);
        acc[i][j] = mfma16(ah[i][1], bh[j][1], acc[i][j]);
      }
    if (isK) {
      v8s al[2][2], bl[2][2];
#pragma unroll
      for (int i = 0; i < 2; ++i)
#pragma unroll
        for (int kk = 0; kk < 2; ++kk) {
          int row = wr * 32 + i * 16 + l16;
          al[i][kk] = *(const v8s*)((const char*)AsL + row * 128 + (((kk * 4 + lg) ^ (row & 7)) * 16));
          int col = wc * 32 + i * 16 + l16;
          bl[i][kk] = *(const v8s*)((const char*)BsL + col * 128 + (((kk * 4 + lg) ^ (col & 7)) * 16));
        }
#pragma unroll
      for (int i = 0; i < 2; ++i)
#pragma unroll
        for (int j = 0; j < 2; ++j)
#pragma unroll
          for (int kk = 0; kk < 2; ++kk) {
            acc[i][j] = mfma16(ah[i][kk], bl[j][kk], acc[i][j]);
            acc[i][j] = mfma16(al[i][kk], bh[j][kk], acc[i][j]);
          }
    }
  }
#pragma unroll
  for (int i = 0; i < 2; ++i)
#pragma unroll
    for (int j = 0; j < 2; ++j)
#pragma unroll
      for (int r = 0; r < 4; ++r) {
        int row = bm + wr * 32 + i * 16 + lg * 4 + r;
        int col = wc * 32 + j * 16 + l16;
        P[(size_t)ks * 32768 + (size_t)row * 64 + col] = acc[i][j][r];
      }
}

// ---- reduce split-K + bias + exact-erf GELU -> kch/kcl (hi/lo), vct (transposed) ----
__global__ __launch_bounds__(256) void creduce_kernel(const float* __restrict__ Pk,
                                                      const float* __restrict__ Pv,
                                                      const float* __restrict__ bc,
                                                      u16* __restrict__ kch, u16* __restrict__ kcl,
                                                      u16* __restrict__ vct) {
  int idx = blockIdx.x * 256 + threadIdx.x;   // 0..65535
  int which = idx >> 15;
  int e = idx & 32767;
  const float* P = which ? Pv : Pk;
  float s = 0.f;
#pragma unroll
  for (int ks = 0; ks < 8; ++ks) s += P[(size_t)ks * 32768 + e];
  s += bc[e & 63];
  float g = 0.5f * s * (1.f + erff(s * 0.70710678118654752f));
  if (!which) {
    u16 hh = f2b(g);
    kch[e] = hh;
    kcl[e] = f2b(g - b2f(hh));
  } else {
    int h2 = e >> 11, j = (e >> 6) & 31, d = e & 63;
    vct[(size_t)h2 * 2048 + d * 32 + j] = f2b(g);
  }
}

// ==== importance + comp attention + block selection, fused; merged = st1*comp ====
__global__ __launch_bounds__(256) void impsel_mfma(const u16* __restrict__ qh,
                                                   const u16* __restrict__ ql,
                                                   const u16* __restrict__ kch,
                                                   const u16* __restrict__ kcl,
                                                   const u16* __restrict__ vct,
                                                   const float* __restrict__ strat,
                                                   const float* __restrict__ kscale_p,
                                                   const float* __restrict__ kbias_p,
                                                   unsigned* __restrict__ maskb,
                                                   float* __restrict__ krb,
                                                   float* __restrict__ neb,
                                                   int* __restrict__ dkb,
                                                   u16* __restrict__ merged) {
  __shared__ u16 Pl[4][16 * 32];
  __shared__ float red[4][32];
  const int tt = blockIdx.x, h = blockIdx.y;
  const int tid = threadIdx.x, w = tid >> 6, lane = tid & 63;
  const int lg = lane >> 4, l16 = lane & 15;
  const size_t qoff = (size_t)(tt * 64 + w * 16 + l16) * kHID + h * 64;
  v8s ah[2], al[2];
  ah[0] = *(const v8s*)(qh + qoff + lg * 8);
  ah[1] = *(const v8s*)(qh + qoff + 32 + lg * 8);
  al[0] = *(const v8s*)(ql + qoff + lg * 8);
  al[1] = *(const v8s*)(ql + qoff + 32 + lg * 8);
  v4f sa[2] = {};
#pragma unroll
  for (int ct = 0; ct < 2; ++ct) {
    int col = ct * 16 + l16;
#pragma unroll
    for (int kk = 0; kk < 2; ++kk) {
      v8s bh = *(const v8s*)(kch + ((size_t)h * 32 + col) * 64 + kk * 32 + lg * 8);
      v8s bl = *(const v8s*)(kcl + ((size_t)h * 32 + col) * 64 + kk * 32 + lg * 8);
      sa[ct] = mfma16(ah[kk], bh, sa[ct]);
      sa[ct] = mfma16(ah[kk], bl, sa[ct]);
      sa[ct] = mfma16(al[kk], bh, sa[ct]);
    }
  }
#pragma unroll
  for (int ct = 0; ct < 2; ++ct)
#pragma unroll
    for (int j = 0; j < 4; ++j) sa[ct][j] *= 0.125f;
  // block-score partial: sum over this thread's 4 rows, then over lg (row quarters)
#pragma unroll
  for (int ct = 0; ct < 2; ++ct) {
    float v = sa[ct][0] + sa[ct][1] + sa[ct][2] + sa[ct][3];
    v += __shfl_xor(v, 16, 64);
    v += __shfl_xor(v, 32, 64);
    if (lg == 0) red[w][ct * 16 + l16] = v;
  }
  // comp-attention softmax (per-wave, register/LDS-private)
  float linv[4];
#pragma unroll
  for (int j = 0; j < 4; ++j) {
    float m = fmaxf(sa[0][j], sa[1][j]);
#pragma unroll
    for (int mm = 1; mm < 16; mm <<= 1) m = fmaxf(m, __shfl_xor(m, mm, 64));
    float e0 = __expf(sa[0][j] - m), e1 = __expf(sa[1][j] - m);
    float s = e0 + e1;
#pragma unroll
    for (int mm = 1; mm < 16; mm <<= 1) s += __shfl_xor(s, mm, 64);
    linv[j] = 1.f / s;
    int row = lg * 4 + j;
    Pl[w][row * 32 + l16] = f2b(e0);
    Pl[w][row * 32 + 16 + l16] = f2b(e1);
  }
  v8s pa = *(const v8s*)(&Pl[w][l16 * 32 + lg * 8]);
  v4f o[4] = {};
#pragma unroll
  for (int dt = 0; dt < 4; ++dt) {
    v8s b = *(const v8s*)(vct + ((size_t)h * 64 + dt * 16 + l16) * 32 + lg * 8);
    o[dt] = mfma16(pa, b, o[dt]);
  }
#pragma unroll
  for (int dt = 0; dt < 4; ++dt)
#pragma unroll
    for (int j = 0; j < 4; ++j) {
      int t = tt * 64 + w * 16 + lg * 4 + j;
      int d = dt * 16 + l16;
      size_t mi = (size_t)t * kHID + h * 64 + d;
      merged[mi] = f2b(strat[t * 48 + h * 3 + 1] * (o[dt][j] * linv[j]));
    }
  __syncthreads();
  // block selection by wave 0 (both 32-halves replicated)
  if (w == 0) {
    const int j = lane & 31;
    float bsj = (red[0][j] + red[1][j] + red[2][j] + red[3][j]) * (1.f / 64.f);
    float mx = bsj;
#pragma unroll
    for (int m = 1; m < 32; m <<= 1) mx = fmaxf(mx, __shfl_xor(mx, m, 64));
    float e = expf(bsj - mx);
    float lsum = e;
#pragma unroll
    for (int m = 1; m < 32; m <<= 1) lsum += __shfl_xor(lsum, m, 64);
    float p = e / lsum;
    float ent = p * logf(p + 1e-9f);
#pragma unroll
    for (int m = 1; m < 32; m <<= 1) ent += __shfl_xor(ent, m, 64);
    ent = -ent;
    float ne = ent / (logf(32.f) + 1e-9f);
    float kr = 1.f / (1.f + expf(-(kscale_p[0] * ne + kbias_p[0])));
    int dk = (int)fminf(fmaxf(8.f * kr, 1.f), 8.f);
    unsigned mword = 1u << tt;
    int taken = 0;
    for (int r = 0; r < dk; ++r) {
      float v2 = taken ? -3.4e38f : bsj;
      int idx2 = j;
#pragma unroll
      for (int m = 1; m < 32; m <<= 1) {
        float ov = __shfl_xor(v2, m, 64);
        int oi = __shfl_xor(idx2, m, 64);
        if (ov > v2 || (ov == v2 && oi < idx2)) { v2 = ov; idx2 = oi; }
      }
      mword |= (1u << idx2);
      if (j == idx2) taken = 1;
    }
    if (lane == 0) {
      maskb[h * kNB + tt] = mword;
      krb[h * kNB + tt] = kr;
      neb[h * kNB + tt] = ne;
      dkb[h * kNB + tt] = dk;
    }
  }
}

// ---------------- scalar outputs: avg_k, aux_loss ----------------
__global__ void finalize_kernel(const int* __restrict__ dkb, const float* __restrict__ krb,
                                const float* __restrict__ neb, float* __restrict__ out) {
  __shared__ float s1[512], s2[512], s3[512];
  int t2 = threadIdx.x;
  float fdk = (float)dkb[t2], kr = krb[t2], ne = neb[t2];
  float d = kr - ne;
  s1[t2] = fdk; s2[t2] = d * d; s3[t2] = kr;
  __syncthreads();
  for (int st = 256; st > 0; st >>= 1) {
    if (t2 < st) { s1[t2] += s1[t2 + st]; s2[t2] += s2[t2 + st]; s3[t2] += s3[t2 + st]; }
    __syncthreads();
  }
  if (t2 == 0) {
    out[(size_t)kT * kHID + 0] = s1[0] * (1.f / 512.f);
    out[(size_t)kT * kHID + 1] = 0.01f * (s2[0] * (1.f / 512.f)) + 0.01f * (s3[0] * (1.f / 512.f));
  }
}

// ------- merged fine (block-sparse) + sliding attention; merged += st0*slide + st2*fine -------
__global__ __launch_bounds__(256) void fineslide_mfma(const u16* __restrict__ qh,
                                                      const u16* __restrict__ kb_,
                                                      const u16* __restrict__ vb_,
                                                      const float* __restrict__ strat,
                                                      const unsigned* __restrict__ maskb,
                                                      u16* __restrict__ merged) {
  __shared__ u16 Kb[64 * 64];
  __shared__ u16 Vt[64 * 64];
  __shared__ u16 Pl[4][16 * 64];
  const int qb = blockIdx.x, h = blockIdx.y;
  const unsigned mword = maskb[h * kNB + qb];
  unsigned uni = mword | (1u << qb);
  if (qb > 0) uni |= 1u << (qb - 1);
  const int tid = threadIdx.x, w = tid >> 6, lane = tid & 63;
  const int lg = lane >> 4, l16 = lane & 15;
  v8s aq[2];
  {
    const u16* qrow = qh + (size_t)(qb * 64 + w * 16 + l16) * kHID + h * 64;
    aq[0] = *(const v8s*)(qrow + lg * 8);
    aq[1] = *(const v8s*)(qrow + 32 + lg * 8);
  }
  float mF[4], lF[4], mS[4], lS[4];
  v4f oF[4] = {}, oS[4] = {};
#pragma unroll
  for (int j = 0; j < 4; ++j) { mF[j] = -1e30f; lF[j] = 0.f; mS[j] = -1e30f; lS[j] = 0.f; }

  auto upd = [&](v4f* sa, float* m_run, float* l_run, v4f* o_acc) {
    float corr[4];
#pragma unroll
    for (int j = 0; j < 4; ++j) {
      float t = fmaxf(fmaxf(sa[0][j], sa[1][j]), fmaxf(sa[2][j], sa[3][j]));
#pragma unroll
      for (int mm = 1; mm < 16; mm <<= 1) t = fmaxf(t, __shfl_xor(t, mm, 64));
      float mn = fmaxf(m_run[j], t);
      corr[j] = __expf(m_run[j] - mn);
      m_run[j] = mn;
    }
    float rs[4] = {0.f, 0.f, 0.f, 0.f};
    float pv[4][4];
#pragma unroll
    for (int ct = 0; ct < 4; ++ct)
#pragma unroll
      for (int j = 0; j < 4; ++j) {
        float e = __expf(sa[ct][j] - m_run[j]);
        pv[ct][j] = e;
        rs[j] += e;
      }
#pragma unroll
    for (int j = 0; j < 4; ++j) {
#pragma unroll
      for (int mm = 1; mm < 16; mm <<= 1) rs[j] += __shfl_xor(rs[j], mm, 64);
      l_run[j] = l_run[j] * corr[j] + rs[j];
    }
#pragma unroll
    for (int ct = 0; ct < 4; ++ct)
#pragma unroll
      for (int j = 0; j < 4; ++j) {
        int row = lg * 4 + j;
        int seg = ct * 2 + (l16 >> 3);
        *((u16*)((char*)Pl + w * 2048 + row * 128 + ((seg ^ (row & 7)) * 16)) + (l16 & 7)) = f2b(pv[ct][j]);
      }
#pragma unroll
    for (int dt = 0; dt < 4; ++dt)
#pragma unroll
      for (int j = 0; j < 4; ++j) o_acc[dt][j] *= corr[j];
#pragma unroll
    for (int dt = 0; dt < 4; ++dt) {
      int d = dt * 16 + l16;
#pragma unroll
      for (int kk = 0; kk < 2; ++kk) {
        v8s pa = *(const v8s*)((const char*)Pl + w * 2048 + l16 * 128 + (((kk * 4 + lg) ^ (l16 & 7)) * 16));
        v8s vb2 = *(const v8s*)((const char*)Vt + d * 128 + (((kk * 4 + lg) ^ (d & 7)) * 16));
        o_acc[dt] = mfma16(pa, vb2, o_acc[dt]);
      }
    }
  };

  for (int jb = 0; jb < 32; ++jb) {
    if (!((uni >> jb) & 1u)) continue;
    __syncthreads();
#pragma unroll
    for (int ss = 0; ss < 2; ++ss) {
      int s = tid + ss * 256;
      int key = s >> 3, sf = (s & 7) ^ (key & 7);
      gl_lds16(kb_ + (size_t)(jb * 64 + key) * kHID + h * 64 + sf * 8, (char*)Kb + s * 16);
    }
    {
      int key = tid & 63, d0 = (tid >> 6) * 16;
      const u16* vsrc = vb_ + (size_t)(jb * 64 + key) * kHID + h * 64 + d0;
      union { uint4 u[2]; u16 s[16]; } c;
      c.u[0] = *(const uint4*)(vsrc);
      c.u[1] = *(const uint4*)(vsrc + 8);
#pragma unroll
      for (int i = 0; i < 16; ++i) {
        int d = d0 + i;
        *((u16*)((char*)Vt + d * 128 + (((key >> 3) ^ (d & 7)) * 16)) + (key & 7)) = c.s[i];
      }
    }
    __syncthreads();
    v4f sa[4] = {};
#pragma unroll
    for (int ct = 0; ct < 4; ++ct) {
      int key = ct * 16 + l16;
#pragma unroll
      for (int kk = 0; kk < 2; ++kk) {
        v8s bk = *(const v8s*)((const char*)Kb + key * 128 + (((kk * 4 + lg) ^ (key & 7)) * 16));
        sa[ct] = mfma16(aq[kk], bk, sa[ct]);
      }
    }
#pragma unroll
    for (int ct = 0; ct < 4; ++ct)
#pragma unroll
      for (int j = 0; j < 4; ++j) sa[ct][j] *= 0.125f;
    const bool inF = (mword >> jb) & 1u;
    const bool inS = (jb == qb) || (jb + 1 == qb);
    if (inF) upd(sa, mF, lF, oF);
    if (inS) {
      v4f sb[4];
#pragma unroll
      for (int ct = 0; ct < 4; ++ct) sb[ct] = sa[ct];
      if (jb == qb) {
#pragma unroll
        for (int ct = 0; ct < 4; ++ct) {
          int key = ct * 16 + l16;
#pragma unroll
          for (int j = 0; j < 4; ++j) {
            int qp = w * 16 + lg * 4 + j;
            if (key > qp) sb[ct][j] = -1e30f;
          }
        }
      }
      upd(sb, mS, lS, oS);
    }
  }
#pragma unroll
  for (int dt = 0; dt < 4; ++dt)
#pragma unroll
    for (int j = 0; j < 4; ++j) {
      int row = lg * 4 + j;
      int t = qb * 64 + w * 16 + row;
      int d = dt * 16 + l16;
      size_t idx = (size_t)t * kHID + h * 64 + d;
      float add = strat[t * 48 + h * 3 + 0] * (oS[dt][j] / lS[j]) +
                  strat[t * 48 + h * 3 + 2] * (oF[dt][j] / lF[j]);
      merged[idx] = f2b(b2f(merged[idx]) + add);
    }
}

// ==== output projection: out(T,HID) fp32 = merged(bf16) @ WotH^T ====
__global__ __launch_bounds__(256) void gemm_out(const u16* __restrict__ A, const u16* __restrict__ Bt,
                                                float* __restrict__ Cf) {
  __shared__ u16 As[128 * 64], Bs[64 * 64];
  const int bm = blockIdx.y * 128, bn = blockIdx.x * 64;
  const int tid = threadIdx.x, w = tid >> 6, lane = tid & 63;
  const int lg = lane >> 4, l16 = lane & 15;
  const int K = kHID;
  v4f acc[2][4] = {};
  for (int k0 = 0; k0 < K; k0 += 64) {
    __syncthreads();
#pragma unroll
    for (int p = 0; p < 4; ++p) {
      int s = tid + p * 256, row = s >> 3, sf = (s & 7) ^ (row & 7);
      gl_lds16(A + (size_t)(bm + row) * K + k0 + sf * 8, (char*)As + s * 16);
    }
#pragma unroll
    for (int p = 0; p < 2; ++p) {
      int s = tid + p * 256, row = s >> 3, sf = (s & 7) ^ (row & 7);
      gl_lds16(Bt + (size_t)(bn + row) * K + k0 + sf * 8, (char*)Bs + s * 16);
    }
    __syncthreads();
    v8s a[2][2], b[4][2];
#pragma unroll
    for (int i = 0; i < 2; ++i)
#pragma unroll
      for (int kk = 0; kk < 2; ++kk) {
        int row = w * 32 + i * 16 + l16;
        a[i][kk] = *(const v8s*)((const char*)As + row * 128 + (((kk * 4 + lg) ^ (row & 7)) * 16));
      }
#pragma unroll
    for (int j = 0; j < 4; ++j)
#pragma unroll
      for (int kk = 0; kk < 2; ++kk) {
        int col = j * 16 + l16;
        b[j][kk] = *(const v8s*)((const char*)Bs + col * 128 + (((kk * 4 + lg) ^ (col & 7)) * 16));
      }
#pragma unroll
    for (int i = 0; i < 2; ++i)
#pragma unroll
      for (int j = 0; j < 4; ++j) {
        acc[i][j] = mfma16(a[i][0], b[j][0], acc[i][j]);
        acc[i][j] = mfma16(a[i][1], b[j][1], acc[i][j]);
      }
  }
#pragma unroll
  for (int i = 0; i < 2; ++i)
#pragma unroll
    for (int j = 0; j < 4; ++j)
#pragma unroll
      for (int r = 0; r < 4; ++r) {
        int row = bm + w * 32 + i * 16 + lg * 4 + r;
        int col = bn + j * 16 + l16;
        Cf[(size_t)row * kHID + col] = acc[i][j][r];
      }
}

// ---------------- launch ----------------
extern "C" void kernel_launch(void* const* d_in, const int* in_sizes, int n_in,
                              void* d_out, int out_size, void* d_ws, size_t ws_size,
                              hipStream_t stream) {
  const float* x      = (const float*)d_in[0];
  const float* Wq     = (const float*)d_in[1];
  const float* Wk     = (const float*)d_in[2];
  const float* Wv     = (const float*)d_in[3];
  const float* Wo     = (const float*)d_in[4];
  const float* Wc     = (const float*)d_in[5];
  const float* bc     = (const float*)d_in[6];
  const float* kscale = (const float*)d_in[7];
  const float* kbias  = (const float*)d_in[8];
  const float* Wsp    = (const float*)d_in[9];
  const float* bsp    = (const float*)d_in[10];
  float* out = (float*)d_out;
  char* W = (char*)d_ws;

  u16* qh     = (u16*)(W + 0 * MB);
  u16* ql     = (u16*)(W + 4 * MB);
  u16* kbf    = (u16*)(W + 8 * MB);
  u16* klbf   = (u16*)(W + 12 * MB);
  u16* vbf    = (u16*)(W + 16 * MB);
  u16* merged = (u16*)(W + 20 * MB);
  u16* xh     = (u16*)(W + 24 * MB);
  u16* xl     = (u16*)(W + 28 * MB);
  u16* WqtH   = (u16*)(W + 32 * MB);
  u16* WqtL   = (u16*)(W + 34 * MB);
  u16* WktH   = (u16*)(W + 36 * MB);
  u16* WktL   = (u16*)(W + 38 * MB);
  u16* WvtH   = (u16*)(W + 40 * MB);
  u16* WotH   = (u16*)(W + 42 * MB);
  u16* WctH   = (u16*)(W + 44 * MB);
  u16* WctL   = (u16*)(W + 44 * MB + 512 * 1024);
  u16* Wst    = (u16*)(W + 45 * MB);
  float* strat= (float*)(W + 46 * MB);
  float* Pk   = (float*)(W + 47 * MB);
  float* Pv   = (float*)(W + 48 * MB);
  u16* kchb   = (u16*)(W + 49 * MB);
  u16* kclb   = (u16*)(W + 49 * MB + 64 * 1024);
  u16* vctb   = (u16*)(W + 49 * MB + 128 * 1024);
  unsigned* maskb = (unsigned*)(W + 49 * MB + 192 * 1024);
  float* krb  = (float*)(W + 49 * MB + 196 * 1024);
  float* neb  = (float*)(W + 49 * MB + 200 * 1024);
  int*   dkb  = (int*)(W + 49 * MB + 204 * 1024);

  dim3 b256(256);
  // 1: all input prep in one dispatch
  prep_kernel<<<5632, b256, 0, stream>>>(x, Wq, Wk, Wv, Wo, Wc, Wsp,
                                         xh, xl, WqtH, WqtL, WktH, WktL,
                                         WvtH, WotH, WctH, WctL, Wst);
  // 2: Q,K,V,strat projections in one dispatch
  proj_gemm<<<dim3(16, 16, 4), b256, 0, stream>>>(xh, xl, WktH, WktL, WqtH, WqtL, WvtH, Wst,
                                                  bsp, kbf, klbf, qh, ql, vbf, strat);
  // 3-4: compress MLP (k 3-combo + v fused), reduce+GELU
  cgemm_fused<<<dim3(1, 8, 16), b256, 0, stream>>>(kbf, klbf, vbf, WctH, WctL, Pk, Pv);
  creduce_kernel<<<256, b256, 0, stream>>>(Pk, Pv, bc, kchb, kclb, vctb);
  // 5: importance + comp attention + block selection
  impsel_mfma<<<dim3(32, kH), b256, 0, stream>>>(qh, ql, kchb, kclb, vctb, strat,
                                                 kscale, kbias, maskb, krb, neb, dkb, merged);
  // 6: scalar outputs
  finalize_kernel<<<1, 512, 0, stream>>>(dkb, krb, neb, out);
  // 7: fine + sliding attention (RMW merged)
  fineslide_mfma<<<dim3(kNB, kH), b256, 0, stream>>>(qh, kbf, vbf, strat, maskb, merged);
  // 8: output projection
  gemm_out<<<dim3(16, 16), b256, 0, stream>>>(merged, WotH, out);
}

// Round 7
// 118.692 us; speedup vs baseline: 8.6686x; 1.0702x over previous
//
#include <hip/hip_runtime.h>
#include <math.h>
#include <stdint.h>

typedef unsigned short u16;
typedef short v8s __attribute__((ext_vector_type(8)));
typedef float v4f __attribute__((ext_vector_type(4)));

constexpr int kT   = 2048;
constexpr int kHID = 1024;
constexpr int kH   = 16;
constexpr int kNB  = 32;
constexpr size_t MB = 1ull << 20;

__device__ __forceinline__ float b2f(u16 u) { unsigned x = ((unsigned)u) << 16; return __uint_as_float(x); }
__device__ __forceinline__ u16 f2b(float f) {
  unsigned x = __float_as_uint(f);
  x += 0x7FFFu + ((x >> 16) & 1u);
  return (u16)(x >> 16);
}
__device__ __forceinline__ v4f mfma16(v8s a, v8s b, v4f c) {
  return __builtin_amdgcn_mfma_f32_16x16x32_bf16(a, b, c, 0, 0, 0);
}
__device__ __forceinline__ void gl_lds16(const void* g, void* l) {
  __builtin_amdgcn_global_load_lds((const __attribute__((address_space(1))) uint32_t*)g,
                                   (__attribute__((address_space(3))) uint32_t*)l, 16, 0, 0);
}

// ==== fused prep: x hi/lo split, Wq/Wk/Wv/Wo/Wc transposes (+lo only for Wk/Wc), Ws pad(128) ====
__global__ __launch_bounds__(256) void prep_kernel(
    const float* __restrict__ x, const float* __restrict__ Wq, const float* __restrict__ Wk,
    const float* __restrict__ Wv, const float* __restrict__ Wo, const float* __restrict__ Wc,
    const float* __restrict__ Wsp,
    u16* __restrict__ xh, u16* __restrict__ xl,
    u16* __restrict__ WqtH, u16* __restrict__ WktH, u16* __restrict__ WktL,
    u16* __restrict__ WvtH, u16* __restrict__ WotH, u16* __restrict__ WctH, u16* __restrict__ WctL,
    u16* __restrict__ Wst) {
  __shared__ float tbuf[32][33];
  int bid = blockIdx.x;
  const int tid = threadIdx.x;
  if (bid < 1024) {                        // split x: 8 elems/thread
    int i = bid * 2048 + tid * 8;
    float4 a = *(const float4*)(x + i), b = *(const float4*)(x + i + 4);
    float tv[8] = {a.x, a.y, a.z, a.w, b.x, b.y, b.z, b.w};
    union { u16 s[8]; uint4 u; } hs, ls;
#pragma unroll
    for (int e = 0; e < 8; ++e) {
      u16 h = f2b(tv[e]);
      hs.s[e] = h;
      ls.s[e] = f2b(tv[e] - b2f(h));
    }
    *(uint4*)(xh + i) = hs.u;
    *(uint4*)(xl + i) = ls.u;
    return;
  }
  bid -= 1024;
  const float* W; u16* Hh; u16* Ll; int Kd, Nd, bx, by;
  if (bid < 4096) {                        // 1024x1024 weight transposes
    int wsel = bid >> 10, sub = bid & 1023;
    W  = wsel == 0 ? Wq : wsel == 1 ? Wk : wsel == 2 ? Wv : Wo;
    Hh = wsel == 0 ? WqtH : wsel == 1 ? WktH : wsel == 2 ? WvtH : WotH;
    Ll = wsel == 1 ? WktL : nullptr;
    Kd = 1024; Nd = 1024;
    bx = (sub & 31) * 32; by = (sub >> 5) * 32;
  } else if (bid < 4096 + 256) {           // Wc (4096x64)
    int sub = bid - 4096;
    W = Wc; Hh = WctH; Ll = WctL;
    Kd = 4096; Nd = 64;
    bx = (sub & 1) * 32; by = (sub >> 1) * 32;
  } else {                                 // Wst pad: 128x1024
    int i = (bid - 4096 - 256) * 256 + tid;
    int n = i >> 10, k2 = i & 1023;
    float v = (n < 48) ? Wsp[(size_t)k2 * 48 + n] : 0.f;
    Wst[(size_t)n * 1024 + k2] = f2b(v);
    return;
  }
  const int lx = tid & 31, ly = tid >> 5;
  for (int i2 = ly; i2 < 32; i2 += 8) tbuf[i2][lx] = W[(size_t)(by + i2) * Nd + bx + lx];
  __syncthreads();
  for (int i2 = ly; i2 < 32; i2 += 8) {
    float xv = tbuf[lx][i2];
    size_t idx = (size_t)(bx + i2) * Kd + by + lx;
    u16 h = f2b(xv);
    Hh[idx] = h;
    if (Ll) Ll[idx] = f2b(xv - b2f(h));
  }
}

// ==== unified projection GEMM, BM=128 BN=128 BK=64, XCD-swizzled by bm (A-slab) ====
// z=0: K 3-combo -> kbf(hi) + klbf(lo)
// z=1: Q single  -> qh
// z=2: V single  -> vbf
// z=3: strat single (bn=0 only, Wst padded 128) -> sigmoid epilogue
__global__ __launch_bounds__(256) void proj_gemm(const u16* __restrict__ xh, const u16* __restrict__ xl,
                                                 const u16* __restrict__ WkH, const u16* __restrict__ WkL,
                                                 const u16* __restrict__ WqH, const u16* __restrict__ WvH,
                                                 const u16* __restrict__ Wst, const float* __restrict__ bsp,
                                                 u16* __restrict__ kbf, u16* __restrict__ klbf,
                                                 u16* __restrict__ qh, u16* __restrict__ vbf,
                                                 float* __restrict__ strat) {
  __shared__ u16 AsH[128 * 64], AsL[128 * 64], BsH[128 * 64], BsL[128 * 64];  // 64 KB
  // bijective decode: 400 blocks = 8 xcd x (2 bm-halves x 25 roles)
  const int b = blockIdx.x;
  const int xcd = b & 7, slot = b >> 3;          // slot in [0,50)
  const int bmi = xcd + 8 * (slot / 25);         // bm index 0..15 (A-slab colocated per XCD)
  const int wsel = slot % 25;
  int z, bni;
  if (wsel < 8)       { z = 0; bni = wsel; }
  else if (wsel < 16) { z = 1; bni = wsel - 8; }
  else if (wsel < 24) { z = 2; bni = wsel - 16; }
  else                { z = 3; bni = 0; }
  const int bm = bmi * 128, bn = bni * 128;
  const int three = (z == 0);
  const u16* Bh = (z == 0) ? WkH : (z == 1) ? WqH : (z == 2) ? WvH : Wst;
  const int tid = threadIdx.x, w = tid >> 6, lane = tid & 63;
  const int lg = lane >> 4, l16 = lane & 15;
  const int wr = w >> 1, wc = w & 1;
  v4f acc[4][4] = {};
  for (int k0 = 0; k0 < kHID; k0 += 64) {
    __syncthreads();
#pragma unroll
    for (int p = 0; p < 4; ++p) {
      int s = tid + p * 256, row = s >> 3, sf = (s & 7) ^ (row & 7);
      gl_lds16(xh + (size_t)(bm + row) * kHID + k0 + sf * 8, (char*)AsH + s * 16);
      gl_lds16(Bh + (size_t)(bn + row) * kHID + k0 + sf * 8, (char*)BsH + s * 16);
      if (three) {
        gl_lds16(xl + (size_t)(bm + row) * kHID + k0 + sf * 8, (char*)AsL + s * 16);
        gl_lds16(WkL + (size_t)(bn + row) * kHID + k0 + sf * 8, (char*)BsL + s * 16);
      }
    }
    __syncthreads();
#pragma unroll
    for (int kk = 0; kk < 2; ++kk) {
      v8s bh4[4], bl4[4];
#pragma unroll
      for (int j = 0; j < 4; ++j) {
        int col = wc * 64 + j * 16 + l16;
        int bo = col * 128 + (((kk * 4 + lg) ^ (col & 7)) * 16);
        bh4[j] = *(const v8s*)((const char*)BsH + bo);
        if (three) bl4[j] = *(const v8s*)((const char*)BsL + bo);
      }
#pragma unroll
      for (int i = 0; i < 4; ++i) {
        int row = wr * 64 + i * 16 + l16;
        int ao = row * 128 + (((kk * 4 + lg) ^ (row & 7)) * 16);
        v8s ah = *(const v8s*)((const char*)AsH + ao);
        v8s al = three ? *(const v8s*)((const char*)AsL + ao) : ah;
#pragma unroll
        for (int j = 0; j < 4; ++j) {
          acc[i][j] = mfma16(ah, bh4[j], acc[i][j]);
          if (three) {
            acc[i][j] = mfma16(ah, bl4[j], acc[i][j]);
            acc[i][j] = mfma16(al, bh4[j], acc[i][j]);
          }
        }
      }
    }
  }
#pragma unroll
  for (int i = 0; i < 4; ++i)
#pragma unroll
    for (int j = 0; j < 4; ++j)
#pragma unroll
      for (int r = 0; r < 4; ++r) {
        int row = bm + wr * 64 + i * 16 + lg * 4 + r;
        int col = bn + wc * 64 + j * 16 + l16;
        float val = acc[i][j][r];
        if (z == 3) {
          if (col < 48) strat[(size_t)row * 48 + col] = 1.f / (1.f + expf(-(val + bsp[col])));
        } else {
          u16 hh = f2b(val);
          size_t idx = (size_t)row * kHID + col;
          if (z == 0) { kbf[idx] = hh; klbf[idx] = f2b(val - b2f(hh)); }
          else if (z == 1) qh[idx] = hh;
          else vbf[idx] = hh;
        }
      }
}

// ==== compress GEMM (k 3-combo + v single fused), split-K partials, A read from row-major k/v ====
__global__ __launch_bounds__(256) void cgemm_fused(const u16* __restrict__ kbf, const u16* __restrict__ klbf,
                                                   const u16* __restrict__ vbf,
                                                   const u16* __restrict__ WcH, const u16* __restrict__ WcL,
                                                   float* __restrict__ Pk, float* __restrict__ Pv) {
  __shared__ u16 AsH[64 * 64], BsH[64 * 64], AsL[64 * 64], BsL[64 * 64];
  const int bm = blockIdx.y * 64;
  const int isK = (blockIdx.z < 8);
  const int ks = isK ? blockIdx.z : blockIdx.z - 8;
  const u16* Asrc = isK ? kbf : vbf;
  float* P = isK ? Pk : Pv;
  const int tid = threadIdx.x;
  const int w = tid >> 6, lane = tid & 63;
  const int lg = lane >> 4, l16 = lane & 15;
  const int wr = w >> 1, wc = w & 1;
  v4f acc[2][2] = {};
  for (int k0 = ks * 512; k0 < ks * 512 + 512; k0 += 64) {
    __syncthreads();
#pragma unroll
    for (int ss = 0; ss < 2; ++ss) {
      int s = tid + ss * 256, row = s >> 3, sf = (s & 7) ^ (row & 7);
      int r = bm + row;                              // (h*32+nb)
      size_t abase = ((size_t)((r & 31) * 64 + (k0 >> 6))) * kHID + (r >> 5) * 64 + sf * 8;
      gl_lds16(Asrc + abase, (char*)AsH + s * 16);
      gl_lds16(WcH + (size_t)row * 4096 + k0 + sf * 8, (char*)BsH + s * 16);
      if (isK) {
        gl_lds16(klbf + abase, (char*)AsL + s * 16);
        gl_lds16(WcL + (size_t)row * 4096 + k0 + sf * 8, (char*)BsL + s * 16);
      }
    }
    __syncthreads();
    v8s ah[2][2], bh[2][2];
#pragma unroll
    for (int i = 0; i < 2; ++i)
#pragma unroll
      for (int kk = 0; kk < 2; ++kk) {
        int row = wr * 32 + i * 16 + l16;
        ah[i][kk] = *(const v8s*)((const char*)AsH + row * 128 + (((kk * 4 + lg) ^ (row & 7)) * 16));
        int col = wc * 32 + i * 16 + l16;
        bh[i][kk] = *(const v8s*)((const char*)BsH + col * 128 + (((kk * 4 + lg) ^ (col & 7)) * 16));
      }
#pragma unroll
    for (int i = 0; i < 2; ++i)
#pragma unroll
      for (int j = 0; j < 2; ++j) {
        acc[i][j] = mfma16(ah[i][0], bh[j][0], acc[i][j]);
        acc[i][j] = mfma16(ah[i][1], bh[j][1], acc[i][j]);
      }
    if (isK) {
      v8s al[2][2], bl[2][2];
#pragma unroll
      for (int i = 0; i < 2; ++i)
#pragma unroll
        for (int kk = 0; kk < 2; ++kk) {
          int row = wr * 32 + i * 16 + l16;
          al[i][kk] = *(const v8s*)((const char*)AsL + row * 128 + (((kk * 4 + lg) ^ (row & 7)) * 16));
          int col = wc * 32 + i * 16 + l16;
          bl[i][kk] = *(const v8s*)((const char*)BsL + col * 128 + (((kk * 4 + lg) ^ (col & 7)) * 16));
        }
#pragma unroll
      for (int i = 0; i < 2; ++i)
#pragma unroll
        for (int j = 0; j < 2; ++j)
#pragma unroll
          for (int kk = 0; kk < 2; ++kk) {
            acc[i][j] = mfma16(ah[i][kk], bl[j][kk], acc[i][j]);
            acc[i][j] = mfma16(al[i][kk], bh[j][kk], acc[i][j]);
          }
    }
  }
#pragma unroll
  for (int i = 0; i < 2; ++i)
#pragma unroll
    for (int j = 0; j < 2; ++j)
#pragma unroll
      for (int r = 0; r < 4; ++r) {
        int row = bm + wr * 32 + i * 16 + lg * 4 + r;
        int col = wc * 32 + j * 16 + l16;
        P[(size_t)ks * 32768 + (size_t)row * 64 + col] = acc[i][j][r];
      }
}

// ---- reduce split-K + bias + exact-erf GELU -> kch/kcl (hi/lo), vct (transposed) ----
__global__ __launch_bounds__(256) void creduce_kernel(const float* __restrict__ Pk,
                                                      const float* __restrict__ Pv,
                                                      const float* __restrict__ bc,
                                                      u16* __restrict__ kch, u16* __restrict__ kcl,
                                                      u16* __restrict__ vct) {
  int idx = blockIdx.x * 256 + threadIdx.x;   // 0..65535
  int which = idx >> 15;
  int e = idx & 32767;
  const float* P = which ? Pv : Pk;
  float s = 0.f;
#pragma unroll
  for (int ks = 0; ks < 8; ++ks) s += P[(size_t)ks * 32768 + e];
  s += bc[e & 63];
  float g = 0.5f * s * (1.f + erff(s * 0.70710678118654752f));
  if (!which) {
    u16 hh = f2b(g);
    kch[e] = hh;
    kcl[e] = f2b(g - b2f(hh));
  } else {
    int h2 = e >> 11, j = (e >> 6) & 31, d = e & 63;
    vct[(size_t)h2 * 2048 + d * 32 + j] = f2b(g);
  }
}

// ==== importance + comp attention + block selection, fused; merged = st1*comp ====
__global__ __launch_bounds__(256) void impsel_mfma(const u16* __restrict__ qh,
                                                   const u16* __restrict__ kch,
                                                   const u16* __restrict__ kcl,
                                                   const u16* __restrict__ vct,
                                                   const float* __restrict__ strat,
                                                   const float* __restrict__ kscale_p,
                                                   const float* __restrict__ kbias_p,
                                                   unsigned* __restrict__ maskb,
                                                   float* __restrict__ krb,
                                                   float* __restrict__ neb,
                                                   int* __restrict__ dkb,
                                                   u16* __restrict__ merged) {
  __shared__ u16 Pl[4][16 * 32];
  __shared__ float red[4][32];
  const int tt = blockIdx.x, h = blockIdx.y;
  const int tid = threadIdx.x, w = tid >> 6, lane = tid & 63;
  const int lg = lane >> 4, l16 = lane & 15;
  const size_t qoff = (size_t)(tt * 64 + w * 16 + l16) * kHID + h * 64;
  v8s ah[2];
  ah[0] = *(const v8s*)(qh + qoff + lg * 8);
  ah[1] = *(const v8s*)(qh + qoff + 32 + lg * 8);
  v4f sa[2] = {};
#pragma unroll
  for (int ct = 0; ct < 2; ++ct) {
    int col = ct * 16 + l16;
#pragma unroll
    for (int kk = 0; kk < 2; ++kk) {
      v8s bh = *(const v8s*)(kch + ((size_t)h * 32 + col) * 64 + kk * 32 + lg * 8);
      v8s bl = *(const v8s*)(kcl + ((size_t)h * 32 + col) * 64 + kk * 32 + lg * 8);
      sa[ct] = mfma16(ah[kk], bh, sa[ct]);
      sa[ct] = mfma16(ah[kk], bl, sa[ct]);
    }
  }
#pragma unroll
  for (int ct = 0; ct < 2; ++ct)
#pragma unroll
    for (int j = 0; j < 4; ++j) sa[ct][j] *= 0.125f;
  // block-score partial: sum over this thread's 4 rows, then over lg (row quarters)
#pragma unroll
  for (int ct = 0; ct < 2; ++ct) {
    float v = sa[ct][0] + sa[ct][1] + sa[ct][2] + sa[ct][3];
    v += __shfl_xor(v, 16, 64);
    v += __shfl_xor(v, 32, 64);
    if (lg == 0) red[w][ct * 16 + l16] = v;
  }
  // comp-attention softmax (per-wave)
  float linv[4];
#pragma unroll
  for (int j = 0; j < 4; ++j) {
    float m = fmaxf(sa[0][j], sa[1][j]);
#pragma unroll
    for (int mm = 1; mm < 16; mm <<= 1) m = fmaxf(m, __shfl_xor(m, mm, 64));
    float e0 = __expf(sa[0][j] - m), e1 = __expf(sa[1][j] - m);
    float s = e0 + e1;
#pragma unroll
    for (int mm = 1; mm < 16; mm <<= 1) s += __shfl_xor(s, mm, 64);
    linv[j] = 1.f / s;
    int row = lg * 4 + j;
    Pl[w][row * 32 + l16] = f2b(e0);
    Pl[w][row * 32 + 16 + l16] = f2b(e1);
  }
  v8s pa = *(const v8s*)(&Pl[w][l16 * 32 + lg * 8]);
  v4f o[4] = {};
#pragma unroll
  for (int dt = 0; dt < 4; ++dt) {
    v8s b = *(const v8s*)(vct + ((size_t)h * 64 + dt * 16 + l16) * 32 + lg * 8);
    o[dt] = mfma16(pa, b, o[dt]);
  }
#pragma unroll
  for (int dt = 0; dt < 4; ++dt)
#pragma unroll
    for (int j = 0; j < 4; ++j) {
      int t = tt * 64 + w * 16 + lg * 4 + j;
      int d = dt * 16 + l16;
      size_t mi = (size_t)t * kHID + h * 64 + d;
      merged[mi] = f2b(strat[t * 48 + h * 3 + 1] * (o[dt][j] * linv[j]));
    }
  __syncthreads();
  // block selection by wave 0
  if (w == 0) {
    const int j = lane & 31;
    float bsj = (red[0][j] + red[1][j] + red[2][j] + red[3][j]) * (1.f / 64.f);
    float mx = bsj;
#pragma unroll
    for (int m = 1; m < 32; m <<= 1) mx = fmaxf(mx, __shfl_xor(mx, m, 64));
    float e = expf(bsj - mx);
    float lsum = e;
#pragma unroll
    for (int m = 1; m < 32; m <<= 1) lsum += __shfl_xor(lsum, m, 64);
    float p = e / lsum;
    float ent = p * logf(p + 1e-9f);
#pragma unroll
    for (int m = 1; m < 32; m <<= 1) ent += __shfl_xor(ent, m, 64);
    ent = -ent;
    float ne = ent / (logf(32.f) + 1e-9f);
    float kr = 1.f / (1.f + expf(-(kscale_p[0] * ne + kbias_p[0])));
    int dk = (int)fminf(fmaxf(8.f * kr, 1.f), 8.f);
    unsigned mword = 1u << tt;
    int taken = 0;
    for (int r = 0; r < dk; ++r) {
      float v2 = taken ? -3.4e38f : bsj;
      int idx2 = j;
#pragma unroll
      for (int m = 1; m < 32; m <<= 1) {
        float ov = __shfl_xor(v2, m, 64);
        int oi = __shfl_xor(idx2, m, 64);
        if (ov > v2 || (ov == v2 && oi < idx2)) { v2 = ov; idx2 = oi; }
      }
      mword |= (1u << idx2);
      if (j == idx2) taken = 1;
    }
    if (lane == 0) {
      maskb[h * kNB + tt] = mword;
      krb[h * kNB + tt] = kr;
      neb[h * kNB + tt] = ne;
      dkb[h * kNB + tt] = dk;
    }
  }
}

// ---------------- scalar outputs: avg_k, aux_loss ----------------
__global__ void finalize_kernel(const int* __restrict__ dkb, const float* __restrict__ krb,
                                const float* __restrict__ neb, float* __restrict__ out) {
  __shared__ float s1[512], s2[512], s3[512];
  int t2 = threadIdx.x;
  float fdk = (float)dkb[t2], kr = krb[t2], ne = neb[t2];
  float d = kr - ne;
  s1[t2] = fdk; s2[t2] = d * d; s3[t2] = kr;
  __syncthreads();
  for (int st = 256; st > 0; st >>= 1) {
    if (t2 < st) { s1[t2] += s1[t2 + st]; s2[t2] += s2[t2 + st]; s3[t2] += s3[t2 + st]; }
    __syncthreads();
  }
  if (t2 == 0) {
    out[(size_t)kT * kHID + 0] = s1[0] * (1.f / 512.f);
    out[(size_t)kT * kHID + 1] = 0.01f * (s2[0] * (1.f / 512.f)) + 0.01f * (s3[0] * (1.f / 512.f));
  }
}

// ------- merged fine (block-sparse) + sliding attention, XCD-swizzled by head -------
__global__ __launch_bounds__(256) void fineslide_mfma(const u16* __restrict__ qh,
                                                      const u16* __restrict__ kb_,
                                                      const u16* __restrict__ vb_,
                                                      const float* __restrict__ strat,
                                                      const unsigned* __restrict__ maskb,
                                                      u16* __restrict__ merged) {
  __shared__ u16 Kb[64 * 64];
  __shared__ u16 Vt[64 * 64];
  __shared__ u16 Pl[4][16 * 64];
  // bijective decode: 512 blocks = 8 xcd x (2 h-halves x 32 qb); same-head blocks colocated
  const int b = blockIdx.x;
  const int xcd = b & 7, slot = b >> 3;
  const int h = xcd + 8 * (slot >> 5);
  const int qb = slot & 31;
  const unsigned mword = maskb[h * kNB + qb];
  unsigned uni = mword | (1u << qb);
  if (qb > 0) uni |= 1u << (qb - 1);
  const int tid = threadIdx.x, w = tid >> 6, lane = tid & 63;
  const int lg = lane >> 4, l16 = lane & 15;
  v8s aq[2];
  {
    const u16* qrow = qh + (size_t)(qb * 64 + w * 16 + l16) * kHID + h * 64;
    aq[0] = *(const v8s*)(qrow + lg * 8);
    aq[1] = *(const v8s*)(qrow + 32 + lg * 8);
  }
  float mF[4], lF[4], mS[4], lS[4];
  v4f oF[4] = {}, oS[4] = {};
#pragma unroll
  for (int j = 0; j < 4; ++j) { mF[j] = -1e30f; lF[j] = 0.f; mS[j] = -1e30f; lS[j] = 0.f; }

  auto upd = [&](v4f* sa, float* m_run, float* l_run, v4f* o_acc) {
    float corr[4];
#pragma unroll
    for (int j = 0; j < 4; ++j) {
      float t = fmaxf(fmaxf(sa[0][j], sa[1][j]), fmaxf(sa[2][j], sa[3][j]));
#pragma unroll
      for (int mm = 1; mm < 16; mm <<= 1) t = fmaxf(t, __shfl_xor(t, mm, 64));
      float mn = fmaxf(m_run[j], t);
      corr[j] = __expf(m_run[j] - mn);
      m_run[j] = mn;
    }
    float rs[4] = {0.f, 0.f, 0.f, 0.f};
    float pv[4][4];
#pragma unroll
    for (int ct = 0; ct < 4; ++ct)
#pragma unroll
      for (int j = 0; j < 4; ++j) {
        float e = __expf(sa[ct][j] - m_run[j]);
        pv[ct][j] = e;
        rs[j] += e;
      }
#pragma unroll
    for (int j = 0; j < 4; ++j) {
#pragma unroll
      for (int mm = 1; mm < 16; mm <<= 1) rs[j] += __shfl_xor(rs[j], mm, 64);
      l_run[j] = l_run[j] * corr[j] + rs[j];
    }
#pragma unroll
    for (int ct = 0; ct < 4; ++ct)
#pragma unroll
      for (int j = 0; j < 4; ++j) {
        int row = lg * 4 + j;
        int seg = ct * 2 + (l16 >> 3);
        *((u16*)((char*)Pl + w * 2048 + row * 128 + ((seg ^ (row & 7)) * 16)) + (l16 & 7)) = f2b(pv[ct][j]);
      }
#pragma unroll
    for (int dt = 0; dt < 4; ++dt)
#pragma unroll
      for (int j = 0; j < 4; ++j) o_acc[dt][j] *= corr[j];
#pragma unroll
    for (int dt = 0; dt < 4; ++dt) {
      int d = dt * 16 + l16;
#pragma unroll
      for (int kk = 0; kk < 2; ++kk) {
        v8s pa = *(const v8s*)((const char*)Pl + w * 2048 + l16 * 128 + (((kk * 4 + lg) ^ (l16 & 7)) * 16));
        v8s vb2 = *(const v8s*)((const char*)Vt + d * 128 + (((kk * 4 + lg) ^ (d & 7)) * 16));
        o_acc[dt] = mfma16(pa, vb2, o_acc[dt]);
      }
    }
  };

  for (int jb = 0; jb < 32; ++jb) {
    if (!((uni >> jb) & 1u)) continue;
    __syncthreads();
#pragma unroll
    for (int ss = 0; ss < 2; ++ss) {
      int s = tid + ss * 256;
      int key = s >> 3, sf = (s & 7) ^ (key & 7);
      gl_lds16(kb_ + (size_t)(jb * 64 + key) * kHID + h * 64 + sf * 8, (char*)Kb + s * 16);
    }
    {
      int key = tid & 63, d0 = (tid >> 6) * 16;
      const u16* vsrc = vb_ + (size_t)(jb * 64 + key) * kHID + h * 64 + d0;
      union { uint4 u[2]; u16 s[16]; } c;
      c.u[0] = *(const uint4*)(vsrc);
      c.u[1] = *(const uint4*)(vsrc + 8);
#pragma unroll
      for (int i = 0; i < 16; ++i) {
        int d = d0 + i;
        *((u16*)((char*)Vt + d * 128 + (((key >> 3) ^ (d & 7)) * 16)) + (key & 7)) = c.s[i];
      }
    }
    __syncthreads();
    v4f sa[4] = {};
#pragma unroll
    for (int ct = 0; ct < 4; ++ct) {
      int key = ct * 16 + l16;
#pragma unroll
      for (int kk = 0; kk < 2; ++kk) {
        v8s bk = *(const v8s*)((const char*)Kb + key * 128 + (((kk * 4 + lg) ^ (key & 7)) * 16));
        sa[ct] = mfma16(aq[kk], bk, sa[ct]);
      }
    }
#pragma unroll
    for (int ct = 0; ct < 4; ++ct)
#pragma unroll
      for (int j = 0; j < 4; ++j) sa[ct][j] *= 0.125f;
    const bool inF = (mword >> jb) & 1u;
    const bool inS = (jb == qb) || (jb + 1 == qb);
    if (inF) upd(sa, mF, lF, oF);
    if (inS) {
      v4f sb[4];
#pragma unroll
      for (int ct = 0; ct < 4; ++ct) sb[ct] = sa[ct];
      if (jb == qb) {
#pragma unroll
        for (int ct = 0; ct < 4; ++ct) {
          int key = ct * 16 + l16;
#pragma unroll
          for (int j = 0; j < 4; ++j) {
            int qp = w * 16 + lg * 4 + j;
            if (key > qp) sb[ct][j] = -1e30f;
          }
        }
      }
      upd(sb, mS, lS, oS);
    }
  }
#pragma unroll
  for (int dt = 0; dt < 4; ++dt)
#pragma unroll
    for (int j = 0; j < 4; ++j) {
      int row = lg * 4 + j;
      int t = qb * 64 + w * 16 + row;
      int d = dt * 16 + l16;
      size_t idx = (size_t)t * kHID + h * 64 + d;
      float add = strat[t * 48 + h * 3 + 0] * (oS[dt][j] / lS[j]) +
                  strat[t * 48 + h * 3 + 2] * (oF[dt][j] / lF[j]);
      merged[idx] = f2b(b2f(merged[idx]) + add);
    }
}

// ==== output projection: out(T,HID) fp32 = merged(bf16) @ WotH^T, XCD-swizzled by bm ====
__global__ __launch_bounds__(256) void gemm_out(const u16* __restrict__ A, const u16* __restrict__ Bt,
                                                float* __restrict__ Cf) {
  __shared__ u16 As[128 * 64], Bs[64 * 64];
  // 256 blocks = 8 xcd x (2 bm-halves x 16 bn)
  const int b = blockIdx.x;
  const int xcd = b & 7, slot = b >> 3;
  const int bm = (xcd + 8 * (slot >> 4)) * 128;
  const int bn = (slot & 15) * 64;
  const int tid = threadIdx.x, w = tid >> 6, lane = tid & 63;
  const int lg = lane >> 4, l16 = lane & 15;
  const int K = kHID;
  v4f acc[2][4] = {};
  for (int k0 = 0; k0 < K; k0 += 64) {
    __syncthreads();
#pragma unroll
    for (int p = 0; p < 4; ++p) {
      int s = tid + p * 256, row = s >> 3, sf = (s & 7) ^ (row & 7);
      gl_lds16(A + (size_t)(bm + row) * K + k0 + sf * 8, (char*)As + s * 16);
    }
#pragma unroll
    for (int p = 0; p < 2; ++p) {
      int s = tid + p * 256, row = s >> 3, sf = (s & 7) ^ (row & 7);
      gl_lds16(Bt + (size_t)(bn + row) * K + k0 + sf * 8, (char*)Bs + s * 16);
    }
    __syncthreads();
    v8s a[2][2], bfr[4][2];
#pragma unroll
    for (int i = 0; i < 2; ++i)
#pragma unroll
      for (int kk = 0; kk < 2; ++kk) {
        int row = w * 32 + i * 16 + l16;
        a[i][kk] = *(const v8s*)((const char*)As + row * 128 + (((kk * 4 + lg) ^ (row & 7)) * 16));
      }
#pragma unroll
    for (int j = 0; j < 4; ++j)
#pragma unroll
      for (int kk = 0; kk < 2; ++kk) {
        int col = j * 16 + l16;
        bfr[j][kk] = *(const v8s*)((const char*)Bs + col * 128 + (((kk * 4 + lg) ^ (col & 7)) * 16));
      }
#pragma unroll
    for (int i = 0; i < 2; ++i)
#pragma unroll
      for (int j = 0; j < 4; ++j) {
        acc[i][j] = mfma16(a[i][0], bfr[j][0], acc[i][j]);
        acc[i][j] = mfma16(a[i][1], bfr[j][1], acc[i][j]);
      }
  }
#pragma unroll
  for (int i = 0; i < 2; ++i)
#pragma unroll
    for (int j = 0; j < 4; ++j)
#pragma unroll
      for (int r = 0; r < 4; ++r) {
        int row = bm + w * 32 + i * 16 + lg * 4 + r;
        int col = bn + j * 16 + l16;
        Cf[(size_t)row * kHID + col] = acc[i][j][r];
      }
}

// ---------------- launch ----------------
extern "C" void kernel_launch(void* const* d_in, const int* in_sizes, int n_in,
                              void* d_out, int out_size, void* d_ws, size_t ws_size,
                              hipStream_t stream) {
  const float* x      = (const float*)d_in[0];
  const float* Wq     = (const float*)d_in[1];
  const float* Wk     = (const float*)d_in[2];
  const float* Wv     = (const float*)d_in[3];
  const float* Wo     = (const float*)d_in[4];
  const float* Wc     = (const float*)d_in[5];
  const float* bc     = (const float*)d_in[6];
  const float* kscale = (const float*)d_in[7];
  const float* kbias  = (const float*)d_in[8];
  const float* Wsp    = (const float*)d_in[9];
  const float* bsp    = (const float*)d_in[10];
  float* out = (float*)d_out;
  char* W = (char*)d_ws;

  u16* qh     = (u16*)(W + 0 * MB);
  u16* kbf    = (u16*)(W + 8 * MB);
  u16* klbf   = (u16*)(W + 12 * MB);
  u16* vbf    = (u16*)(W + 16 * MB);
  u16* merged = (u16*)(W + 20 * MB);
  u16* xh     = (u16*)(W + 24 * MB);
  u16* xl     = (u16*)(W + 28 * MB);
  u16* WqtH   = (u16*)(W + 32 * MB);
  u16* WktH   = (u16*)(W + 36 * MB);
  u16* WktL   = (u16*)(W + 38 * MB);
  u16* WvtH   = (u16*)(W + 40 * MB);
  u16* WotH   = (u16*)(W + 42 * MB);
  u16* WctH   = (u16*)(W + 44 * MB);
  u16* WctL   = (u16*)(W + 44 * MB + 512 * 1024);
  u16* Wst    = (u16*)(W + 45 * MB);          // 256 KB (padded 128x1024)
  float* strat= (float*)(W + 46 * MB);
  float* Pk   = (float*)(W + 47 * MB);
  float* Pv   = (float*)(W + 48 * MB);
  u16* kchb   = (u16*)(W + 49 * MB);
  u16* kclb   = (u16*)(W + 49 * MB + 64 * 1024);
  u16* vctb   = (u16*)(W + 49 * MB + 128 * 1024);
  unsigned* maskb = (unsigned*)(W + 49 * MB + 192 * 1024);
  float* krb  = (float*)(W + 49 * MB + 196 * 1024);
  float* neb  = (float*)(W + 49 * MB + 200 * 1024);
  int*   dkb  = (int*)(W + 49 * MB + 204 * 1024);

  dim3 b256(256);
  // 1: all input prep
  prep_kernel<<<5888, b256, 0, stream>>>(x, Wq, Wk, Wv, Wo, Wc, Wsp,
                                         xh, xl, WqtH, WktH, WktL,
                                         WvtH, WotH, WctH, WctL, Wst);
  // 2: Q,K,V,strat projections (BM=128 BN=128, XCD-swizzled)
  proj_gemm<<<400, b256, 0, stream>>>(xh, xl, WktH, WktL, WqtH, WvtH, Wst,
                                      bsp, kbf, klbf, qh, vbf, strat);
  // 3-4: compress MLP + reduce+GELU
  cgemm_fused<<<dim3(1, 8, 16), b256, 0, stream>>>(kbf, klbf, vbf, WctH, WctL, Pk, Pv);
  creduce_kernel<<<256, b256, 0, stream>>>(Pk, Pv, bc, kchb, kclb, vctb);
  // 5: importance + comp attention + block selection
  impsel_mfma<<<dim3(32, kH), b256, 0, stream>>>(qh, kchb, kclb, vctb, strat,
                                                 kscale, kbias, maskb, krb, neb, dkb, merged);
  // 6: scalar outputs
  finalize_kernel<<<1, 512, 0, stream>>>(dkb, krb, neb, out);
  // 7: fine + sliding attention (RMW merged)
  fineslide_mfma<<<512, b256, 0, stream>>>(qh, kbf, vbf, strat, maskb, merged);
  // 8: output projection
  gemm_out<<<256, b256, 0, stream>>>(merged, WotH, out);
}

// Round 8
// 104.370 us; speedup vs baseline: 9.8581x; 1.1372x over previous
//
#include <hip/hip_runtime.h>
#include <math.h>
#include <stdint.h>

typedef unsigned short u16;
typedef short v8s __attribute__((ext_vector_type(8)));
typedef float v4f __attribute__((ext_vector_type(4)));

constexpr int kT   = 2048;
constexpr int kHID = 1024;
constexpr int kH   = 16;
constexpr int kNB  = 32;
constexpr size_t MB = 1ull << 20;

__device__ __forceinline__ float b2f(u16 u) { unsigned x = ((unsigned)u) << 16; return __uint_as_float(x); }
__device__ __forceinline__ u16 f2b(float f) {
  unsigned x = __float_as_uint(f);
  x += 0x7FFFu + ((x >> 16) & 1u);
  return (u16)(x >> 16);
}
__device__ __forceinline__ v4f mfma16(v8s a, v8s b, v4f c) {
  return __builtin_amdgcn_mfma_f32_16x16x32_bf16(a, b, c, 0, 0, 0);
}
__device__ __forceinline__ void gl_lds16(const void* g, void* l) {
  __builtin_amdgcn_global_load_lds((const __attribute__((address_space(1))) uint32_t*)g,
                                   (__attribute__((address_space(3))) uint32_t*)l, 16, 0, 0);
}

// ==== fused prep: x->bf16, Wq/Wk/Wv/Wo transposes, Wc transpose hi/lo, Ws pad(128) ====
__global__ __launch_bounds__(256) void prep_kernel(
    const float* __restrict__ x, const float* __restrict__ Wq, const float* __restrict__ Wk,
    const float* __restrict__ Wv, const float* __restrict__ Wo, const float* __restrict__ Wc,
    const float* __restrict__ Wsp,
    u16* __restrict__ xh,
    u16* __restrict__ WqtH, u16* __restrict__ WktH,
    u16* __restrict__ WvtH, u16* __restrict__ WotH, u16* __restrict__ WctH, u16* __restrict__ WctL,
    u16* __restrict__ Wst) {
  __shared__ float tbuf[32][33];
  int bid = blockIdx.x;
  const int tid = threadIdx.x;
  if (bid < 1024) {                        // x -> bf16: 8 elems/thread
    int i = bid * 2048 + tid * 8;
    float4 a = *(const float4*)(x + i), b = *(const float4*)(x + i + 4);
    float tv[8] = {a.x, a.y, a.z, a.w, b.x, b.y, b.z, b.w};
    union { u16 s[8]; uint4 u; } hs;
#pragma unroll
    for (int e = 0; e < 8; ++e) hs.s[e] = f2b(tv[e]);
    *(uint4*)(xh + i) = hs.u;
    return;
  }
  bid -= 1024;
  const float* W; u16* Hh; u16* Ll; int Kd, Nd, bx, by;
  if (bid < 4096) {                        // 1024x1024 weight transposes
    int wsel = bid >> 10, sub = bid & 1023;
    W  = wsel == 0 ? Wq : wsel == 1 ? Wk : wsel == 2 ? Wv : Wo;
    Hh = wsel == 0 ? WqtH : wsel == 1 ? WktH : wsel == 2 ? WvtH : WotH;
    Ll = nullptr;
    Kd = 1024; Nd = 1024;
    bx = (sub & 31) * 32; by = (sub >> 5) * 32;
  } else if (bid < 4096 + 256) {           // Wc (4096x64), hi/lo
    int sub = bid - 4096;
    W = Wc; Hh = WctH; Ll = WctL;
    Kd = 4096; Nd = 64;
    bx = (sub & 1) * 32; by = (sub >> 1) * 32;
  } else {                                 // Wst pad: 128x1024
    int i = (bid - 4096 - 256) * 256 + tid;
    int n = i >> 10, k2 = i & 1023;
    float v = (n < 48) ? Wsp[(size_t)k2 * 48 + n] : 0.f;
    Wst[(size_t)n * 1024 + k2] = f2b(v);
    return;
  }
  const int lx = tid & 31, ly = tid >> 5;
  for (int i2 = ly; i2 < 32; i2 += 8) tbuf[i2][lx] = W[(size_t)(by + i2) * Nd + bx + lx];
  __syncthreads();
  for (int i2 = ly; i2 < 32; i2 += 8) {
    float xv = tbuf[lx][i2];
    size_t idx = (size_t)(bx + i2) * Kd + by + lx;
    u16 h = f2b(xv);
    Hh[idx] = h;
    if (Ll) Ll[idx] = f2b(xv - b2f(h));
  }
}

// ==== unified projection GEMM, single-combo bf16, BM=128 BN=128 BK=64 ====
// role-colocated XCD swizzle: each XCD keeps ~3 B-panels L2-hot, streams xh
// role<8: K -> kbf; <16: Q -> qh; <24: V -> vbf; 24: strat (sigmoid epilogue)
__global__ __launch_bounds__(256) void proj_gemm(const u16* __restrict__ xh,
                                                 const u16* __restrict__ WkH, const u16* __restrict__ WqH,
                                                 const u16* __restrict__ WvH, const u16* __restrict__ Wst,
                                                 const float* __restrict__ bsp,
                                                 u16* __restrict__ kbf, u16* __restrict__ qh,
                                                 u16* __restrict__ vbf, float* __restrict__ strat) {
  __shared__ u16 AsH[128 * 64], BsH[128 * 64];   // 32 KB
  const int b = blockIdx.x;                       // 400 blocks
  const int g = (b & 7) * 50 + (b >> 3);          // bijective; b&7 = XCD -> role-colocated
  const int role = g >> 4, bmi = g & 15;
  int z, bni;
  if (role < 8)       { z = 0; bni = role; }
  else if (role < 16) { z = 1; bni = role - 8; }
  else if (role < 24) { z = 2; bni = role - 16; }
  else                { z = 3; bni = 0; }
  const int bm = bmi * 128, bn = bni * 128;
  const u16* Bh = (z == 0) ? WkH : (z == 1) ? WqH : (z == 2) ? WvH : Wst;
  const int tid = threadIdx.x, w = tid >> 6, lane = tid & 63;
  const int lg = lane >> 4, l16 = lane & 15;
  const int wr = w >> 1, wc = w & 1;
  v4f acc[4][4] = {};
  for (int k0 = 0; k0 < kHID; k0 += 64) {
    __syncthreads();
#pragma unroll
    for (int p = 0; p < 4; ++p) {
      int s = tid + p * 256, row = s >> 3, sf = (s & 7) ^ (row & 7);
      gl_lds16(xh + (size_t)(bm + row) * kHID + k0 + sf * 8, (char*)AsH + s * 16);
      gl_lds16(Bh + (size_t)(bn + row) * kHID + k0 + sf * 8, (char*)BsH + s * 16);
    }
    __syncthreads();
#pragma unroll
    for (int kk = 0; kk < 2; ++kk) {
      v8s bh4[4];
#pragma unroll
      for (int j = 0; j < 4; ++j) {
        int col = wc * 64 + j * 16 + l16;
        bh4[j] = *(const v8s*)((const char*)BsH + col * 128 + (((kk * 4 + lg) ^ (col & 7)) * 16));
      }
#pragma unroll
      for (int i = 0; i < 4; ++i) {
        int row = wr * 64 + i * 16 + l16;
        v8s ah = *(const v8s*)((const char*)AsH + row * 128 + (((kk * 4 + lg) ^ (row & 7)) * 16));
#pragma unroll
        for (int j = 0; j < 4; ++j) acc[i][j] = mfma16(ah, bh4[j], acc[i][j]);
      }
    }
  }
#pragma unroll
  for (int i = 0; i < 4; ++i)
#pragma unroll
    for (int j = 0; j < 4; ++j)
#pragma unroll
      for (int r = 0; r < 4; ++r) {
        int row = bm + wr * 64 + i * 16 + lg * 4 + r;
        int col = bn + wc * 64 + j * 16 + l16;
        float val = acc[i][j][r];
        if (z == 3) {
          if (col < 48) strat[(size_t)row * 48 + col] = 1.f / (1.f + expf(-(val + bsp[col])));
        } else {
          u16 hh = f2b(val);
          size_t idx = (size_t)row * kHID + col;
          if (z == 0) kbf[idx] = hh;
          else if (z == 1) qh[idx] = hh;
          else vbf[idx] = hh;
        }
      }
}

// ==== compress GEMM: K-path 2-combo (k·WcH + k·WcL), V-path single; split-K partials ====
__global__ __launch_bounds__(256) void cgemm_fused(const u16* __restrict__ kbf,
                                                   const u16* __restrict__ vbf,
                                                   const u16* __restrict__ WcH, const u16* __restrict__ WcL,
                                                   float* __restrict__ Pk, float* __restrict__ Pv) {
  __shared__ u16 AsH[64 * 64], BsH[64 * 64], BsL[64 * 64];   // 24 KB
  const int bm = blockIdx.y * 64;
  const int isK = (blockIdx.z < 8);
  const int ks = isK ? blockIdx.z : blockIdx.z - 8;
  const u16* Asrc = isK ? kbf : vbf;
  float* P = isK ? Pk : Pv;
  const int tid = threadIdx.x;
  const int w = tid >> 6, lane = tid & 63;
  const int lg = lane >> 4, l16 = lane & 15;
  const int wr = w >> 1, wc = w & 1;
  v4f acc[2][2] = {};
  for (int k0 = ks * 512; k0 < ks * 512 + 512; k0 += 64) {
    __syncthreads();
#pragma unroll
    for (int ss = 0; ss < 2; ++ss) {
      int s = tid + ss * 256, row = s >> 3, sf = (s & 7) ^ (row & 7);
      int r = bm + row;                              // (h*32+nb)
      size_t abase = ((size_t)((r & 31) * 64 + (k0 >> 6))) * kHID + (r >> 5) * 64 + sf * 8;
      gl_lds16(Asrc + abase, (char*)AsH + s * 16);
      gl_lds16(WcH + (size_t)row * 4096 + k0 + sf * 8, (char*)BsH + s * 16);
      if (isK) gl_lds16(WcL + (size_t)row * 4096 + k0 + sf * 8, (char*)BsL + s * 16);
    }
    __syncthreads();
    v8s ah[2][2], bh[2][2];
#pragma unroll
    for (int i = 0; i < 2; ++i)
#pragma unroll
      for (int kk = 0; kk < 2; ++kk) {
        int row = wr * 32 + i * 16 + l16;
        ah[i][kk] = *(const v8s*)((const char*)AsH + row * 128 + (((kk * 4 + lg) ^ (row & 7)) * 16));
        int col = wc * 32 + i * 16 + l16;
        bh[i][kk] = *(const v8s*)((const char*)BsH + col * 128 + (((kk * 4 + lg) ^ (col & 7)) * 16));
      }
#pragma unroll
    for (int i = 0; i < 2; ++i)
#pragma unroll
      for (int j = 0; j < 2; ++j) {
        acc[i][j] = mfma16(ah[i][0], bh[j][0], acc[i][j]);
        acc[i][j] = mfma16(ah[i][1], bh[j][1], acc[i][j]);
      }
    if (isK) {
      v8s bl[2][2];
#pragma unroll
      for (int i = 0; i < 2; ++i)
#pragma unroll
        for (int kk = 0; kk < 2; ++kk) {
          int col = wc * 32 + i * 16 + l16;
          bl[i][kk] = *(const v8s*)((const char*)BsL + col * 128 + (((kk * 4 + lg) ^ (col & 7)) * 16));
        }
#pragma unroll
      for (int i = 0; i < 2; ++i)
#pragma unroll
        for (int j = 0; j < 2; ++j) {
          acc[i][j] = mfma16(ah[i][0], bl[j][0], acc[i][j]);
          acc[i][j] = mfma16(ah[i][1], bl[j][1], acc[i][j]);
        }
    }
  }
#pragma unroll
  for (int i = 0; i < 2; ++i)
#pragma unroll
    for (int j = 0; j < 2; ++j)
#pragma unroll
      for (int r = 0; r < 4; ++r) {
        int row = bm + wr * 32 + i * 16 + lg * 4 + r;
        int col = wc * 32 + j * 16 + l16;
        P[(size_t)ks * 32768 + (size_t)row * 64 + col] = acc[i][j][r];
      }
}

// ---- reduce split-K + bias + exact-erf GELU -> kch/kcl (hi/lo), vct (transposed) ----
__global__ __launch_bounds__(256) void creduce_kernel(const float* __restrict__ Pk,
                                                      const float* __restrict__ Pv,
                                                      const float* __restrict__ bc,
                                                      u16* __restrict__ kch, u16* __restrict__ kcl,
                                                      u16* __restrict__ vct) {
  int idx = blockIdx.x * 256 + threadIdx.x;   // 0..65535
  int which = idx >> 15;
  int e = idx & 32767;
  const float* P = which ? Pv : Pk;
  float s = 0.f;
#pragma unroll
  for (int ks = 0; ks < 8; ++ks) s += P[(size_t)ks * 32768 + e];
  s += bc[e & 63];
  float g = 0.5f * s * (1.f + erff(s * 0.70710678118654752f));
  if (!which) {
    u16 hh = f2b(g);
    kch[e] = hh;
    kcl[e] = f2b(g - b2f(hh));
  } else {
    int h2 = e >> 11, j = (e >> 6) & 31, d = e & 63;
    vct[(size_t)h2 * 2048 + d * 32 + j] = f2b(g);
  }
}

// ==== importance + comp attention + block selection, fused; merged = st1*comp ====
__global__ __launch_bounds__(256) void impsel_mfma(const u16* __restrict__ qh,
                                                   const u16* __restrict__ kch,
                                                   const u16* __restrict__ kcl,
                                                   const u16* __restrict__ vct,
                                                   const float* __restrict__ strat,
                                                   const float* __restrict__ kscale_p,
                                                   const float* __restrict__ kbias_p,
                                                   unsigned* __restrict__ maskb,
                                                   float* __restrict__ krb,
                                                   float* __restrict__ neb,
                                                   int* __restrict__ dkb,
                                                   u16* __restrict__ merged) {
  __shared__ u16 Pl[4][16 * 32];
  __shared__ float red[4][32];
  const int tt = blockIdx.x, h = blockIdx.y;
  const int tid = threadIdx.x, w = tid >> 6, lane = tid & 63;
  const int lg = lane >> 4, l16 = lane & 15;
  const size_t qoff = (size_t)(tt * 64 + w * 16 + l16) * kHID + h * 64;
  v8s ah[2];
  ah[0] = *(const v8s*)(qh + qoff + lg * 8);
  ah[1] = *(const v8s*)(qh + qoff + 32 + lg * 8);
  v4f sa[2] = {};
#pragma unroll
  for (int ct = 0; ct < 2; ++ct) {
    int col = ct * 16 + l16;
#pragma unroll
    for (int kk = 0; kk < 2; ++kk) {
      v8s bh = *(const v8s*)(kch + ((size_t)h * 32 + col) * 64 + kk * 32 + lg * 8);
      v8s bl = *(const v8s*)(kcl + ((size_t)h * 32 + col) * 64 + kk * 32 + lg * 8);
      sa[ct] = mfma16(ah[kk], bh, sa[ct]);
      sa[ct] = mfma16(ah[kk], bl, sa[ct]);
    }
  }
#pragma unroll
  for (int ct = 0; ct < 2; ++ct)
#pragma unroll
    for (int j = 0; j < 4; ++j) sa[ct][j] *= 0.125f;
  // block-score partial
#pragma unroll
  for (int ct = 0; ct < 2; ++ct) {
    float v = sa[ct][0] + sa[ct][1] + sa[ct][2] + sa[ct][3];
    v += __shfl_xor(v, 16, 64);
    v += __shfl_xor(v, 32, 64);
    if (lg == 0) red[w][ct * 16 + l16] = v;
  }
  // comp-attention softmax (per-wave)
  float linv[4];
#pragma unroll
  for (int j = 0; j < 4; ++j) {
    float m = fmaxf(sa[0][j], sa[1][j]);
#pragma unroll
    for (int mm = 1; mm < 16; mm <<= 1) m = fmaxf(m, __shfl_xor(m, mm, 64));
    float e0 = __expf(sa[0][j] - m), e1 = __expf(sa[1][j] - m);
    float s = e0 + e1;
#pragma unroll
    for (int mm = 1; mm < 16; mm <<= 1) s += __shfl_xor(s, mm, 64);
    linv[j] = 1.f / s;
    int row = lg * 4 + j;
    Pl[w][row * 32 + l16] = f2b(e0);
    Pl[w][row * 32 + 16 + l16] = f2b(e1);
  }
  v8s pa = *(const v8s*)(&Pl[w][l16 * 32 + lg * 8]);
  v4f o[4] = {};
#pragma unroll
  for (int dt = 0; dt < 4; ++dt) {
    v8s b = *(const v8s*)(vct + ((size_t)h * 64 + dt * 16 + l16) * 32 + lg * 8);
    o[dt] = mfma16(pa, b, o[dt]);
  }
#pragma unroll
  for (int dt = 0; dt < 4; ++dt)
#pragma unroll
    for (int j = 0; j < 4; ++j) {
      int t = tt * 64 + w * 16 + lg * 4 + j;
      int d = dt * 16 + l16;
      size_t mi = (size_t)t * kHID + h * 64 + d;
      merged[mi] = f2b(strat[t * 48 + h * 3 + 1] * (o[dt][j] * linv[j]));
    }
  __syncthreads();
  // block selection by wave 0
  if (w == 0) {
    const int j = lane & 31;
    float bsj = (red[0][j] + red[1][j] + red[2][j] + red[3][j]) * (1.f / 64.f);
    float mx = bsj;
#pragma unroll
    for (int m = 1; m < 32; m <<= 1) mx = fmaxf(mx, __shfl_xor(mx, m, 64));
    float e = expf(bsj - mx);
    float lsum = e;
#pragma unroll
    for (int m = 1; m < 32; m <<= 1) lsum += __shfl_xor(lsum, m, 64);
    float p = e / lsum;
    float ent = p * logf(p + 1e-9f);
#pragma unroll
    for (int m = 1; m < 32; m <<= 1) ent += __shfl_xor(ent, m, 64);
    ent = -ent;
    float ne = ent / (logf(32.f) + 1e-9f);
    float kr = 1.f / (1.f + expf(-(kscale_p[0] * ne + kbias_p[0])));
    int dk = (int)fminf(fmaxf(8.f * kr, 1.f), 8.f);
    unsigned mword = 1u << tt;
    int taken = 0;
    for (int r = 0; r < dk; ++r) {
      float v2 = taken ? -3.4e38f : bsj;
      int idx2 = j;
#pragma unroll
      for (int m = 1; m < 32; m <<= 1) {
        float ov = __shfl_xor(v2, m, 64);
        int oi = __shfl_xor(idx2, m, 64);
        if (ov > v2 || (ov == v2 && oi < idx2)) { v2 = ov; idx2 = oi; }
      }
      mword |= (1u << idx2);
      if (j == idx2) taken = 1;
    }
    if (lane == 0) {
      maskb[h * kNB + tt] = mword;
      krb[h * kNB + tt] = kr;
      neb[h * kNB + tt] = ne;
      dkb[h * kNB + tt] = dk;
    }
  }
}

// ---------------- scalar outputs: avg_k, aux_loss ----------------
__global__ void finalize_kernel(const int* __restrict__ dkb, const float* __restrict__ krb,
                                const float* __restrict__ neb, float* __restrict__ out) {
  __shared__ float s1[512], s2[512], s3[512];
  int t2 = threadIdx.x;
  float fdk = (float)dkb[t2], kr = krb[t2], ne = neb[t2];
  float d = kr - ne;
  s1[t2] = fdk; s2[t2] = d * d; s3[t2] = kr;
  __syncthreads();
  for (int st = 256; st > 0; st >>= 1) {
    if (t2 < st) { s1[t2] += s1[t2 + st]; s2[t2] += s2[t2 + st]; s3[t2] += s3[t2 + st]; }
    __syncthreads();
  }
  if (t2 == 0) {
    out[(size_t)kT * kHID + 0] = s1[0] * (1.f / 512.f);
    out[(size_t)kT * kHID + 1] = 0.01f * (s2[0] * (1.f / 512.f)) + 0.01f * (s3[0] * (1.f / 512.f));
  }
}

// ------- merged fine (block-sparse) + sliding attention, XCD-swizzled by head -------
__global__ __launch_bounds__(256) void fineslide_mfma(const u16* __restrict__ qh,
                                                      const u16* __restrict__ kb_,
                                                      const u16* __restrict__ vb_,
                                                      const float* __restrict__ strat,
                                                      const unsigned* __restrict__ maskb,
                                                      u16* __restrict__ merged) {
  __shared__ u16 Kb[64 * 64];
  __shared__ u16 Vt[64 * 64];
  __shared__ u16 Pl[4][16 * 64];
  const int b = blockIdx.x;
  const int xcd = b & 7, slot = b >> 3;
  const int h = xcd + 8 * (slot >> 5);
  const int qb = slot & 31;
  const unsigned mword = maskb[h * kNB + qb];
  unsigned uni = mword | (1u << qb);
  if (qb > 0) uni |= 1u << (qb - 1);
  const int tid = threadIdx.x, w = tid >> 6, lane = tid & 63;
  const int lg = lane >> 4, l16 = lane & 15;
  v8s aq[2];
  {
    const u16* qrow = qh + (size_t)(qb * 64 + w * 16 + l16) * kHID + h * 64;
    aq[0] = *(const v8s*)(qrow + lg * 8);
    aq[1] = *(const v8s*)(qrow + 32 + lg * 8);
  }
  float mF[4], lF[4], mS[4], lS[4];
  v4f oF[4] = {}, oS[4] = {};
#pragma unroll
  for (int j = 0; j < 4; ++j) { mF[j] = -1e30f; lF[j] = 0.f; mS[j] = -1e30f; lS[j] = 0.f; }

  auto upd = [&](v4f* sa, float* m_run, float* l_run, v4f* o_acc) {
    float corr[4];
#pragma unroll
    for (int j = 0; j < 4; ++j) {
      float t = fmaxf(fmaxf(sa[0][j], sa[1][j]), fmaxf(sa[2][j], sa[3][j]));
#pragma unroll
      for (int mm = 1; mm < 16; mm <<= 1) t = fmaxf(t, __shfl_xor(t, mm, 64));
      float mn = fmaxf(m_run[j], t);
      corr[j] = __expf(m_run[j] - mn);
      m_run[j] = mn;
    }
    float rs[4] = {0.f, 0.f, 0.f, 0.f};
    float pv[4][4];
#pragma unroll
    for (int ct = 0; ct < 4; ++ct)
#pragma unroll
      for (int j = 0; j < 4; ++j) {
        float e = __expf(sa[ct][j] - m_run[j]);
        pv[ct][j] = e;
        rs[j] += e;
      }
#pragma unroll
    for (int j = 0; j < 4; ++j) {
#pragma unroll
      for (int mm = 1; mm < 16; mm <<= 1) rs[j] += __shfl_xor(rs[j], mm, 64);
      l_run[j] = l_run[j] * corr[j] + rs[j];
    }
#pragma unroll
    for (int ct = 0; ct < 4; ++ct)
#pragma unroll
      for (int j = 0; j < 4; ++j) {
        int row = lg * 4 + j;
        int seg = ct * 2 + (l16 >> 3);
        *((u16*)((char*)Pl + w * 2048 + row * 128 + ((seg ^ (row & 7)) * 16)) + (l16 & 7)) = f2b(pv[ct][j]);
      }
#pragma unroll
    for (int dt = 0; dt < 4; ++dt)
#pragma unroll
      for (int j = 0; j < 4; ++j) o_acc[dt][j] *= corr[j];
#pragma unroll
    for (int dt = 0; dt < 4; ++dt) {
      int d = dt * 16 + l16;
#pragma unroll
      for (int kk = 0; kk < 2; ++kk) {
        v8s pa = *(const v8s*)((const char*)Pl + w * 2048 + l16 * 128 + (((kk * 4 + lg) ^ (l16 & 7)) * 16));
        v8s vb2 = *(const v8s*)((const char*)Vt + d * 128 + (((kk * 4 + lg) ^ (d & 7)) * 16));
        o_acc[dt] = mfma16(pa, vb2, o_acc[dt]);
      }
    }
  };

  for (int jb = 0; jb < 32; ++jb) {
    if (!((uni >> jb) & 1u)) continue;
    __syncthreads();
#pragma unroll
    for (int ss = 0; ss < 2; ++ss) {
      int s = tid + ss * 256;
      int key = s >> 3, sf = (s & 7) ^ (key & 7);
      gl_lds16(kb_ + (size_t)(jb * 64 + key) * kHID + h * 64 + sf * 8, (char*)Kb + s * 16);
    }
    {
      int key = tid & 63, d0 = (tid >> 6) * 16;
      const u16* vsrc = vb_ + (size_t)(jb * 64 + key) * kHID + h * 64 + d0;
      union { uint4 u[2]; u16 s[16]; } c;
      c.u[0] = *(const uint4*)(vsrc);
      c.u[1] = *(const uint4*)(vsrc + 8);
#pragma unroll
      for (int i = 0; i < 16; ++i) {
        int d = d0 + i;
        *((u16*)((char*)Vt + d * 128 + (((key >> 3) ^ (d & 7)) * 16)) + (key & 7)) = c.s[i];
      }
    }
    __syncthreads();
    v4f sa[4] = {};
#pragma unroll
    for (int ct = 0; ct < 4; ++ct) {
      int key = ct * 16 + l16;
#pragma unroll
      for (int kk = 0; kk < 2; ++kk) {
        v8s bk = *(const v8s*)((const char*)Kb + key * 128 + (((kk * 4 + lg) ^ (key & 7)) * 16));
        sa[ct] = mfma16(aq[kk], bk, sa[ct]);
      }
    }
#pragma unroll
    for (int ct = 0; ct < 4; ++ct)
#pragma unroll
      for (int j = 0; j < 4; ++j) sa[ct][j] *= 0.125f;
    const bool inF = (mword >> jb) & 1u;
    const bool inS = (jb == qb) || (jb + 1 == qb);
    if (inF) upd(sa, mF, lF, oF);
    if (inS) {
      v4f sb[4];
#pragma unroll
      for (int ct = 0; ct < 4; ++ct) sb[ct] = sa[ct];
      if (jb == qb) {
#pragma unroll
        for (int ct = 0; ct < 4; ++ct) {
          int key = ct * 16 + l16;
#pragma unroll
          for (int j = 0; j < 4; ++j) {
            int qp = w * 16 + lg * 4 + j;
            if (key > qp) sb[ct][j] = -1e30f;
          }
        }
      }
      upd(sb, mS, lS, oS);
    }
  }
#pragma unroll
  for (int dt = 0; dt < 4; ++dt)
#pragma unroll
    for (int j = 0; j < 4; ++j) {
      int row = lg * 4 + j;
      int t = qb * 64 + w * 16 + row;
      int d = dt * 16 + l16;
      size_t idx = (size_t)t * kHID + h * 64 + d;
      float add = strat[t * 48 + h * 3 + 0] * (oS[dt][j] / lS[j]) +
                  strat[t * 48 + h * 3 + 2] * (oF[dt][j] / lF[j]);
      merged[idx] = f2b(b2f(merged[idx]) + add);
    }
}

// ==== output projection: out(T,HID) fp32 = merged(bf16) @ WotH^T, bn-colocated swizzle ====
__global__ __launch_bounds__(256) void gemm_out(const u16* __restrict__ A, const u16* __restrict__ Bt,
                                                float* __restrict__ Cf) {
  __shared__ u16 As[128 * 64], Bs[64 * 64];
  // 256 blocks; colocate bn-panels per XCD (B hot), stream merged
  const int b = blockIdx.x;
  const int g = (b & 7) * 32 + (b >> 3);
  const int bn = (g >> 4) * 64;
  const int bm = (g & 15) * 128;
  const int tid = threadIdx.x, w = tid >> 6, lane = tid & 63;
  const int lg = lane >> 4, l16 = lane & 15;
  const int K = kHID;
  v4f acc[2][4] = {};
  for (int k0 = 0; k0 < K; k0 += 64) {
    __syncthreads();
#pragma unroll
    for (int p = 0; p < 4; ++p) {
      int s = tid + p * 256, row = s >> 3, sf = (s & 7) ^ (row & 7);
      gl_lds16(A + (size_t)(bm + row) * K + k0 + sf * 8, (char*)As + s * 16);
    }
#pragma unroll
    for (int p = 0; p < 2; ++p) {
      int s = tid + p * 256, row = s >> 3, sf = (s & 7) ^ (row & 7);
      gl_lds16(Bt + (size_t)(bn + row) * K + k0 + sf * 8, (char*)Bs + s * 16);
    }
    __syncthreads();
    v8s a[2][2], bfr[4][2];
#pragma unroll
    for (int i = 0; i < 2; ++i)
#pragma unroll
      for (int kk = 0; kk < 2; ++kk) {
        int row = w * 32 + i * 16 + l16;
        a[i][kk] = *(const v8s*)((const char*)As + row * 128 + (((kk * 4 + lg) ^ (row & 7)) * 16));
      }
#pragma unroll
    for (int j = 0; j < 4; ++j)
#pragma unroll
      for (int kk = 0; kk < 2; ++kk) {
        int col = j * 16 + l16;
        bfr[j][kk] = *(const v8s*)((const char*)Bs + col * 128 + (((kk * 4 + lg) ^ (col & 7)) * 16));
      }
#pragma unroll
    for (int i = 0; i < 2; ++i)
#pragma unroll
      for (int j = 0; j < 4; ++j) {
        acc[i][j] = mfma16(a[i][0], bfr[j][0], acc[i][j]);
        acc[i][j] = mfma16(a[i][1], bfr[j][1], acc[i][j]);
      }
  }
#pragma unroll
  for (int i = 0; i < 2; ++i)
#pragma unroll
    for (int j = 0; j < 4; ++j)
#pragma unroll
      for (int r = 0; r < 4; ++r) {
        int row = bm + w * 32 + i * 16 + lg * 4 + r;
        int col = bn + j * 16 + l16;
        Cf[(size_t)row * kHID + col] = acc[i][j][r];
      }
}

// ---------------- launch ----------------
extern "C" void kernel_launch(void* const* d_in, const int* in_sizes, int n_in,
                              void* d_out, int out_size, void* d_ws, size_t ws_size,
                              hipStream_t stream) {
  const float* x      = (const float*)d_in[0];
  const float* Wq     = (const float*)d_in[1];
  const float* Wk     = (const float*)d_in[2];
  const float* Wv     = (const float*)d_in[3];
  const float* Wo     = (const float*)d_in[4];
  const float* Wc     = (const float*)d_in[5];
  const float* bc     = (const float*)d_in[6];
  const float* kscale = (const float*)d_in[7];
  const float* kbias  = (const float*)d_in[8];
  const float* Wsp    = (const float*)d_in[9];
  const float* bsp    = (const float*)d_in[10];
  float* out = (float*)d_out;
  char* W = (char*)d_ws;

  u16* qh     = (u16*)(W + 0 * MB);
  u16* kbf    = (u16*)(W + 8 * MB);
  u16* vbf    = (u16*)(W + 16 * MB);
  u16* merged = (u16*)(W + 20 * MB);
  u16* xh     = (u16*)(W + 24 * MB);
  u16* WqtH   = (u16*)(W + 32 * MB);
  u16* WktH   = (u16*)(W + 36 * MB);
  u16* WvtH   = (u16*)(W + 40 * MB);
  u16* WotH   = (u16*)(W + 42 * MB);
  u16* WctH   = (u16*)(W + 44 * MB);
  u16* WctL   = (u16*)(W + 44 * MB + 512 * 1024);
  u16* Wst    = (u16*)(W + 45 * MB);          // 256 KB (padded 128x1024)
  float* strat= (float*)(W + 46 * MB);
  float* Pk   = (float*)(W + 47 * MB);
  float* Pv   = (float*)(W + 48 * MB);
  u16* kchb   = (u16*)(W + 49 * MB);
  u16* kclb   = (u16*)(W + 49 * MB + 64 * 1024);
  u16* vctb   = (u16*)(W + 49 * MB + 128 * 1024);
  unsigned* maskb = (unsigned*)(W + 49 * MB + 192 * 1024);
  float* krb  = (float*)(W + 49 * MB + 196 * 1024);
  float* neb  = (float*)(W + 49 * MB + 200 * 1024);
  int*   dkb  = (int*)(W + 49 * MB + 204 * 1024);

  dim3 b256(256);
  // 1: all input prep
  prep_kernel<<<5888, b256, 0, stream>>>(x, Wq, Wk, Wv, Wo, Wc, Wsp,
                                         xh, WqtH, WktH, WvtH, WotH, WctH, WctL, Wst);
  // 2: Q,K,V,strat projections (single-combo, role-colocated XCD swizzle)
  proj_gemm<<<400, b256, 0, stream>>>(xh, WktH, WqtH, WvtH, Wst,
                                      bsp, kbf, qh, vbf, strat);
  // 3-4: compress MLP + reduce+GELU
  cgemm_fused<<<dim3(1, 8, 16), b256, 0, stream>>>(kbf, vbf, WctH, WctL, Pk, Pv);
  creduce_kernel<<<256, b256, 0, stream>>>(Pk, Pv, bc, kchb, kclb, vctb);
  // 5: importance + comp attention + block selection
  impsel_mfma<<<dim3(32, kH), b256, 0, stream>>>(qh, kchb, kclb, vctb, strat,
                                                 kscale, kbias, maskb, krb, neb, dkb, merged);
  // 6: scalar outputs
  finalize_kernel<<<1, 512, 0, stream>>>(dkb, krb, neb, out);
  // 7: fine + sliding attention (RMW merged)
  fineslide_mfma<<<512, b256, 0, stream>>>(qh, kbf, vbf, strat, maskb, merged);
  // 8: output projection
  gemm_out<<<256, b256, 0, stream>>>(merged, WotH, out);
}

// Round 9
// 96.202 us; speedup vs baseline: 10.6951x; 1.0849x over previous
//
#include <hip/hip_runtime.h>
#include <math.h>
#include <stdint.h>

typedef unsigned short u16;
typedef short v8s __attribute__((ext_vector_type(8)));
typedef float v4f __attribute__((ext_vector_type(4)));

constexpr int kT   = 2048;
constexpr int kHID = 1024;
constexpr int kH   = 16;
constexpr int kNB  = 32;
constexpr size_t MB = 1ull << 20;

__device__ __forceinline__ float b2f(u16 u) { unsigned x = ((unsigned)u) << 16; return __uint_as_float(x); }
__device__ __forceinline__ u16 f2b(float f) {
  unsigned x = __float_as_uint(f);
  x += 0x7FFFu + ((x >> 16) & 1u);
  return (u16)(x >> 16);
}
__device__ __forceinline__ v4f mfma16(v8s a, v8s b, v4f c) {
  return __builtin_amdgcn_mfma_f32_16x16x32_bf16(a, b, c, 0, 0, 0);
}
__device__ __forceinline__ void gl_lds16(const void* g, void* l) {
  __builtin_amdgcn_global_load_lds((const __attribute__((address_space(1))) uint32_t*)g,
                                   (__attribute__((address_space(3))) uint32_t*)l, 16, 0, 0);
}

// ==== fused prep: x->bf16, Wq/Wk/Wv/Wo transposes, Wc transpose hi/lo, Ws pad(128) ====
__global__ __launch_bounds__(256) void prep_kernel(
    const float* __restrict__ x, const float* __restrict__ Wq, const float* __restrict__ Wk,
    const float* __restrict__ Wv, const float* __restrict__ Wo, const float* __restrict__ Wc,
    const float* __restrict__ Wsp,
    u16* __restrict__ xh,
    u16* __restrict__ WqtH, u16* __restrict__ WktH,
    u16* __restrict__ WvtH, u16* __restrict__ WotH, u16* __restrict__ WctH, u16* __restrict__ WctL,
    u16* __restrict__ Wst) {
  __shared__ float tbuf[32][33];
  int bid = blockIdx.x;
  const int tid = threadIdx.x;
  if (bid < 1024) {                        // x -> bf16: 8 elems/thread
    int i = bid * 2048 + tid * 8;
    float4 a = *(const float4*)(x + i), b = *(const float4*)(x + i + 4);
    float tv[8] = {a.x, a.y, a.z, a.w, b.x, b.y, b.z, b.w};
    union { u16 s[8]; uint4 u; } hs;
#pragma unroll
    for (int e = 0; e < 8; ++e) hs.s[e] = f2b(tv[e]);
    *(uint4*)(xh + i) = hs.u;
    return;
  }
  bid -= 1024;
  const float* W; u16* Hh; u16* Ll; int Kd, Nd, bx, by;
  if (bid < 4096) {                        // 1024x1024 weight transposes
    int wsel = bid >> 10, sub = bid & 1023;
    W  = wsel == 0 ? Wq : wsel == 1 ? Wk : wsel == 2 ? Wv : Wo;
    Hh = wsel == 0 ? WqtH : wsel == 1 ? WktH : wsel == 2 ? WvtH : WotH;
    Ll = nullptr;
    Kd = 1024; Nd = 1024;
    bx = (sub & 31) * 32; by = (sub >> 5) * 32;
  } else if (bid < 4096 + 256) {           // Wc (4096x64), hi/lo
    int sub = bid - 4096;
    W = Wc; Hh = WctH; Ll = WctL;
    Kd = 4096; Nd = 64;
    bx = (sub & 1) * 32; by = (sub >> 1) * 32;
  } else {                                 // Wst pad: 128x1024
    int i = (bid - 4096 - 256) * 256 + tid;
    int n = i >> 10, k2 = i & 1023;
    float v = (n < 48) ? Wsp[(size_t)k2 * 48 + n] : 0.f;
    Wst[(size_t)n * 1024 + k2] = f2b(v);
    return;
  }
  const int lx = tid & 31, ly = tid >> 5;
  for (int i2 = ly; i2 < 32; i2 += 8) tbuf[i2][lx] = W[(size_t)(by + i2) * Nd + bx + lx];
  __syncthreads();
  for (int i2 = ly; i2 < 32; i2 += 8) {
    float xv = tbuf[lx][i2];
    size_t idx = (size_t)(bx + i2) * Kd + by + lx;
    u16 h = f2b(xv);
    Hh[idx] = h;
    if (Ll) Ll[idx] = f2b(xv - b2f(h));
  }
}

// ==== unified projection GEMM, single-combo bf16, BM=64 BN=128 BK=64 ====
// 800 blocks = 25 panels (K:8, Q:8, V:8, strat:1) x 32 bm slabs; panel-colocated per XCD
__global__ __launch_bounds__(256) void proj_gemm(const u16* __restrict__ xh,
                                                 const u16* __restrict__ WkH, const u16* __restrict__ WqH,
                                                 const u16* __restrict__ WvH, const u16* __restrict__ Wst,
                                                 const float* __restrict__ bsp,
                                                 u16* __restrict__ kbf, u16* __restrict__ qh,
                                                 u16* __restrict__ vbf, float* __restrict__ strat) {
  __shared__ u16 AsH[64 * 64], BsH[128 * 64];   // 24 KB
  const int b = blockIdx.x;                      // 800 blocks
  const int slot = (b & 7) * 100 + (b >> 3);     // bijective [0,800)
  const int panel = slot >> 5, bmi = slot & 31;
  int z, bni;
  if (panel < 8)       { z = 0; bni = panel; }
  else if (panel < 16) { z = 1; bni = panel - 8; }
  else if (panel < 24) { z = 2; bni = panel - 16; }
  else                 { z = 3; bni = 0; }
  const int bm = bmi * 64, bn = bni * 128;
  const u16* Bh = (z == 0) ? WkH : (z == 1) ? WqH : (z == 2) ? WvH : Wst;
  const int tid = threadIdx.x, w = tid >> 6, lane = tid & 63;
  const int lg = lane >> 4, l16 = lane & 15;
  const int wr = w >> 1, wc = w & 1;
  v4f acc[2][4] = {};
  for (int k0 = 0; k0 < kHID; k0 += 64) {
    __syncthreads();
#pragma unroll
    for (int p = 0; p < 2; ++p) {
      int s = tid + p * 256, row = s >> 3, sf = (s & 7) ^ (row & 7);
      gl_lds16(xh + (size_t)(bm + row) * kHID + k0 + sf * 8, (char*)AsH + s * 16);
    }
#pragma unroll
    for (int p = 0; p < 4; ++p) {
      int s = tid + p * 256, row = s >> 3, sf = (s & 7) ^ (row & 7);
      gl_lds16(Bh + (size_t)(bn + row) * kHID + k0 + sf * 8, (char*)BsH + s * 16);
    }
    __syncthreads();
#pragma unroll
    for (int kk = 0; kk < 2; ++kk) {
      v8s bh4[4];
#pragma unroll
      for (int j = 0; j < 4; ++j) {
        int col = wc * 64 + j * 16 + l16;
        bh4[j] = *(const v8s*)((const char*)BsH + col * 128 + (((kk * 4 + lg) ^ (col & 7)) * 16));
      }
#pragma unroll
      for (int i = 0; i < 2; ++i) {
        int row = wr * 32 + i * 16 + l16;
        v8s ah = *(const v8s*)((const char*)AsH + row * 128 + (((kk * 4 + lg) ^ (row & 7)) * 16));
#pragma unroll
        for (int j = 0; j < 4; ++j) acc[i][j] = mfma16(ah, bh4[j], acc[i][j]);
      }
    }
  }
#pragma unroll
  for (int i = 0; i < 2; ++i)
#pragma unroll
    for (int j = 0; j < 4; ++j)
#pragma unroll
      for (int r = 0; r < 4; ++r) {
        int row = bm + wr * 32 + i * 16 + lg * 4 + r;
        int col = bn + wc * 64 + j * 16 + l16;
        float val = acc[i][j][r];
        if (z == 3) {
          if (col < 48) strat[(size_t)row * 48 + col] = 1.f / (1.f + expf(-(val + bsp[col])));
        } else {
          u16 hh = f2b(val);
          size_t idx = (size_t)row * kHID + col;
          if (z == 0) kbf[idx] = hh;
          else if (z == 1) qh[idx] = hh;
          else vbf[idx] = hh;
        }
      }
}

// ==== compress GEMM: K-path 2-combo (k·WcH + k·WcL), V-path single; split-K partials ====
__global__ __launch_bounds__(256) void cgemm_fused(const u16* __restrict__ kbf,
                                                   const u16* __restrict__ vbf,
                                                   const u16* __restrict__ WcH, const u16* __restrict__ WcL,
                                                   float* __restrict__ Pk, float* __restrict__ Pv) {
  __shared__ u16 AsH[64 * 64], BsH[64 * 64], BsL[64 * 64];   // 24 KB
  const int bm = blockIdx.y * 64;
  const int isK = (blockIdx.z < 8);
  const int ks = isK ? blockIdx.z : blockIdx.z - 8;
  const u16* Asrc = isK ? kbf : vbf;
  float* P = isK ? Pk : Pv;
  const int tid = threadIdx.x;
  const int w = tid >> 6, lane = tid & 63;
  const int lg = lane >> 4, l16 = lane & 15;
  const int wr = w >> 1, wc = w & 1;
  v4f acc[2][2] = {};
  for (int k0 = ks * 512; k0 < ks * 512 + 512; k0 += 64) {
    __syncthreads();
#pragma unroll
    for (int ss = 0; ss < 2; ++ss) {
      int s = tid + ss * 256, row = s >> 3, sf = (s & 7) ^ (row & 7);
      int r = bm + row;                              // (h*32+nb)
      size_t abase = ((size_t)((r & 31) * 64 + (k0 >> 6))) * kHID + (r >> 5) * 64 + sf * 8;
      gl_lds16(Asrc + abase, (char*)AsH + s * 16);
      gl_lds16(WcH + (size_t)row * 4096 + k0 + sf * 8, (char*)BsH + s * 16);
      if (isK) gl_lds16(WcL + (size_t)row * 4096 + k0 + sf * 8, (char*)BsL + s * 16);
    }
    __syncthreads();
    v8s ah[2][2], bh[2][2];
#pragma unroll
    for (int i = 0; i < 2; ++i)
#pragma unroll
      for (int kk = 0; kk < 2; ++kk) {
        int row = wr * 32 + i * 16 + l16;
        ah[i][kk] = *(const v8s*)((const char*)AsH + row * 128 + (((kk * 4 + lg) ^ (row & 7)) * 16));
        int col = wc * 32 + i * 16 + l16;
        bh[i][kk] = *(const v8s*)((const char*)BsH + col * 128 + (((kk * 4 + lg) ^ (col & 7)) * 16));
      }
#pragma unroll
    for (int i = 0; i < 2; ++i)
#pragma unroll
      for (int j = 0; j < 2; ++j) {
        acc[i][j] = mfma16(ah[i][0], bh[j][0], acc[i][j]);
        acc[i][j] = mfma16(ah[i][1], bh[j][1], acc[i][j]);
      }
    if (isK) {
      v8s bl[2][2];
#pragma unroll
      for (int i = 0; i < 2; ++i)
#pragma unroll
        for (int kk = 0; kk < 2; ++kk) {
          int col = wc * 32 + i * 16 + l16;
          bl[i][kk] = *(const v8s*)((const char*)BsL + col * 128 + (((kk * 4 + lg) ^ (col & 7)) * 16));
        }
#pragma unroll
      for (int i = 0; i < 2; ++i)
#pragma unroll
        for (int j = 0; j < 2; ++j) {
          acc[i][j] = mfma16(ah[i][0], bl[j][0], acc[i][j]);
          acc[i][j] = mfma16(ah[i][1], bl[j][1], acc[i][j]);
        }
    }
  }
#pragma unroll
  for (int i = 0; i < 2; ++i)
#pragma unroll
    for (int j = 0; j < 2; ++j)
#pragma unroll
      for (int r = 0; r < 4; ++r) {
        int row = bm + wr * 32 + i * 16 + lg * 4 + r;
        int col = wc * 32 + j * 16 + l16;
        P[(size_t)ks * 32768 + (size_t)row * 64 + col] = acc[i][j][r];
      }
}

// ---- reduce split-K + bias + exact-erf GELU -> kch/kcl (hi/lo), vct (transposed) ----
__global__ __launch_bounds__(256) void creduce_kernel(const float* __restrict__ Pk,
                                                      const float* __restrict__ Pv,
                                                      const float* __restrict__ bc,
                                                      u16* __restrict__ kch, u16* __restrict__ kcl,
                                                      u16* __restrict__ vct) {
  int idx = blockIdx.x * 256 + threadIdx.x;   // 0..65535
  int which = idx >> 15;
  int e = idx & 32767;
  const float* P = which ? Pv : Pk;
  float s = 0.f;
#pragma unroll
  for (int ks = 0; ks < 8; ++ks) s += P[(size_t)ks * 32768 + e];
  s += bc[e & 63];
  float g = 0.5f * s * (1.f + erff(s * 0.70710678118654752f));
  if (!which) {
    u16 hh = f2b(g);
    kch[e] = hh;
    kcl[e] = f2b(g - b2f(hh));
  } else {
    int h2 = e >> 11, j = (e >> 6) & 31, d = e & 63;
    vct[(size_t)h2 * 2048 + d * 32 + j] = f2b(g);
  }
}

// ==== importance + comp attention + block selection, fused; merged = st1*comp ====
__global__ __launch_bounds__(256) void impsel_mfma(const u16* __restrict__ qh,
                                                   const u16* __restrict__ kch,
                                                   const u16* __restrict__ kcl,
                                                   const u16* __restrict__ vct,
                                                   const float* __restrict__ strat,
                                                   const float* __restrict__ kscale_p,
                                                   const float* __restrict__ kbias_p,
                                                   unsigned* __restrict__ maskb,
                                                   float* __restrict__ krb,
                                                   float* __restrict__ neb,
                                                   int* __restrict__ dkb,
                                                   u16* __restrict__ merged) {
  __shared__ u16 Pl[4][16 * 32];
  __shared__ float red[4][32];
  const int tt = blockIdx.x, h = blockIdx.y;
  const int tid = threadIdx.x, w = tid >> 6, lane = tid & 63;
  const int lg = lane >> 4, l16 = lane & 15;
  const size_t qoff = (size_t)(tt * 64 + w * 16 + l16) * kHID + h * 64;
  v8s ah[2];
  ah[0] = *(const v8s*)(qh + qoff + lg * 8);
  ah[1] = *(const v8s*)(qh + qoff + 32 + lg * 8);
  v4f sa[2] = {};
#pragma unroll
  for (int ct = 0; ct < 2; ++ct) {
    int col = ct * 16 + l16;
#pragma unroll
    for (int kk = 0; kk < 2; ++kk) {
      v8s bh = *(const v8s*)(kch + ((size_t)h * 32 + col) * 64 + kk * 32 + lg * 8);
      v8s bl = *(const v8s*)(kcl + ((size_t)h * 32 + col) * 64 + kk * 32 + lg * 8);
      sa[ct] = mfma16(ah[kk], bh, sa[ct]);
      sa[ct] = mfma16(ah[kk], bl, sa[ct]);
    }
  }
#pragma unroll
  for (int ct = 0; ct < 2; ++ct)
#pragma unroll
    for (int j = 0; j < 4; ++j) sa[ct][j] *= 0.125f;
  // block-score partial
#pragma unroll
  for (int ct = 0; ct < 2; ++ct) {
    float v = sa[ct][0] + sa[ct][1] + sa[ct][2] + sa[ct][3];
    v += __shfl_xor(v, 16, 64);
    v += __shfl_xor(v, 32, 64);
    if (lg == 0) red[w][ct * 16 + l16] = v;
  }
  // comp-attention softmax (per-wave)
  float linv[4];
#pragma unroll
  for (int j = 0; j < 4; ++j) {
    float m = fmaxf(sa[0][j], sa[1][j]);
#pragma unroll
    for (int mm = 1; mm < 16; mm <<= 1) m = fmaxf(m, __shfl_xor(m, mm, 64));
    float e0 = __expf(sa[0][j] - m), e1 = __expf(sa[1][j] - m);
    float s = e0 + e1;
#pragma unroll
    for (int mm = 1; mm < 16; mm <<= 1) s += __shfl_xor(s, mm, 64);
    linv[j] = 1.f / s;
    int row = lg * 4 + j;
    Pl[w][row * 32 + l16] = f2b(e0);
    Pl[w][row * 32 + 16 + l16] = f2b(e1);
  }
  v8s pa = *(const v8s*)(&Pl[w][l16 * 32 + lg * 8]);
  v4f o[4] = {};
#pragma unroll
  for (int dt = 0; dt < 4; ++dt) {
    v8s b = *(const v8s*)(vct + ((size_t)h * 64 + dt * 16 + l16) * 32 + lg * 8);
    o[dt] = mfma16(pa, b, o[dt]);
  }
#pragma unroll
  for (int dt = 0; dt < 4; ++dt)
#pragma unroll
    for (int j = 0; j < 4; ++j) {
      int t = tt * 64 + w * 16 + lg * 4 + j;
      int d = dt * 16 + l16;
      size_t mi = (size_t)t * kHID + h * 64 + d;
      merged[mi] = f2b(strat[t * 48 + h * 3 + 1] * (o[dt][j] * linv[j]));
    }
  __syncthreads();
  // block selection by wave 0
  if (w == 0) {
    const int j = lane & 31;
    float bsj = (red[0][j] + red[1][j] + red[2][j] + red[3][j]) * (1.f / 64.f);
    float mx = bsj;
#pragma unroll
    for (int m = 1; m < 32; m <<= 1) mx = fmaxf(mx, __shfl_xor(mx, m, 64));
    float e = expf(bsj - mx);
    float lsum = e;
#pragma unroll
    for (int m = 1; m < 32; m <<= 1) lsum += __shfl_xor(lsum, m, 64);
    float p = e / lsum;
    float ent = p * logf(p + 1e-9f);
#pragma unroll
    for (int m = 1; m < 32; m <<= 1) ent += __shfl_xor(ent, m, 64);
    ent = -ent;
    float ne = ent / (logf(32.f) + 1e-9f);
    float kr = 1.f / (1.f + expf(-(kscale_p[0] * ne + kbias_p[0])));
    int dk = (int)fminf(fmaxf(8.f * kr, 1.f), 8.f);
    unsigned mword = 1u << tt;
    int taken = 0;
    for (int r = 0; r < dk; ++r) {
      float v2 = taken ? -3.4e38f : bsj;
      int idx2 = j;
#pragma unroll
      for (int m = 1; m < 32; m <<= 1) {
        float ov = __shfl_xor(v2, m, 64);
        int oi = __shfl_xor(idx2, m, 64);
        if (ov > v2 || (ov == v2 && oi < idx2)) { v2 = ov; idx2 = oi; }
      }
      mword |= (1u << idx2);
      if (j == idx2) taken = 1;
    }
    if (lane == 0) {
      maskb[h * kNB + tt] = mword;
      krb[h * kNB + tt] = kr;
      neb[h * kNB + tt] = ne;
      dkb[h * kNB + tt] = dk;
    }
  }
}

// ---------------- scalar outputs: avg_k, aux_loss ----------------
__global__ void finalize_kernel(const int* __restrict__ dkb, const float* __restrict__ krb,
                                const float* __restrict__ neb, float* __restrict__ out) {
  __shared__ float s1[512], s2[512], s3[512];
  int t2 = threadIdx.x;
  float fdk = (float)dkb[t2], kr = krb[t2], ne = neb[t2];
  float d = kr - ne;
  s1[t2] = fdk; s2[t2] = d * d; s3[t2] = kr;
  __syncthreads();
  for (int st = 256; st > 0; st >>= 1) {
    if (t2 < st) { s1[t2] += s1[t2 + st]; s2[t2] += s2[t2 + st]; s3[t2] += s3[t2 + st]; }
    __syncthreads();
  }
  if (t2 == 0) {
    out[(size_t)kT * kHID + 0] = s1[0] * (1.f / 512.f);
    out[(size_t)kT * kHID + 1] = 0.01f * (s2[0] * (1.f / 512.f)) + 0.01f * (s3[0] * (1.f / 512.f));
  }
}

// ------- merged fine (block-sparse) + sliding attention, double-buffered (T14 split) -------
__global__ __launch_bounds__(256) void fineslide_mfma(const u16* __restrict__ qh,
                                                      const u16* __restrict__ kb_,
                                                      const u16* __restrict__ vb_,
                                                      const float* __restrict__ strat,
                                                      const unsigned* __restrict__ maskb,
                                                      u16* __restrict__ merged) {
  __shared__ u16 Kb[2][64 * 64];
  __shared__ u16 Vt[2][64 * 64];
  __shared__ u16 Pl[4][16 * 64];
  const int b = blockIdx.x;
  const int xcd = b & 7, slot = b >> 3;
  const int h = xcd + 8 * (slot >> 5);
  const int qb = slot & 31;
  const unsigned mword = maskb[h * kNB + qb];
  unsigned uni = mword | (1u << qb);
  if (qb > 0) uni |= 1u << (qb - 1);
  const int tid = threadIdx.x, w = tid >> 6, lane = tid & 63;
  const int lg = lane >> 4, l16 = lane & 15;
  v8s aq[2];
  {
    const u16* qrow = qh + (size_t)(qb * 64 + w * 16 + l16) * kHID + h * 64;
    aq[0] = *(const v8s*)(qrow + lg * 8);
    aq[1] = *(const v8s*)(qrow + 32 + lg * 8);
  }
  float mF[4], lF[4], mS[4], lS[4];
  v4f oF[4] = {}, oS[4] = {};
#pragma unroll
  for (int j = 0; j < 4; ++j) { mF[j] = -1e30f; lF[j] = 0.f; mS[j] = -1e30f; lS[j] = 0.f; }

  const int vkey = tid & 63, vd0 = (tid >> 6) * 16;

  auto k_stage = [&](int buf, int jb) {
#pragma unroll
    for (int ss = 0; ss < 2; ++ss) {
      int s = tid + ss * 256;
      int key = s >> 3, sf = (s & 7) ^ (key & 7);
      gl_lds16(kb_ + (size_t)(jb * 64 + key) * kHID + h * 64 + sf * 8, (char*)Kb[buf] + s * 16);
    }
  };
  auto v_issue = [&](int jb, uint4& c0, uint4& c1) {
    const u16* vsrc = vb_ + (size_t)(jb * 64 + vkey) * kHID + h * 64 + vd0;
    c0 = *(const uint4*)(vsrc);
    c1 = *(const uint4*)(vsrc + 8);
  };
  auto v_write = [&](int buf, uint4 c0, uint4 c1) {
    union { uint4 u[2]; u16 s[16]; } c;
    c.u[0] = c0; c.u[1] = c1;
#pragma unroll
    for (int i = 0; i < 16; ++i) {
      int d = vd0 + i;
      *((u16*)((char*)Vt[buf] + d * 128 + (((vkey >> 3) ^ (d & 7)) * 16)) + (vkey & 7)) = c.s[i];
    }
  };

  auto upd = [&](const v4f* sa, float* m_run, float* l_run, v4f* o_acc, int buf) {
    float corr[4];
#pragma unroll
    for (int j = 0; j < 4; ++j) {
      float t = fmaxf(fmaxf(sa[0][j], sa[1][j]), fmaxf(sa[2][j], sa[3][j]));
#pragma unroll
      for (int mm = 1; mm < 16; mm <<= 1) t = fmaxf(t, __shfl_xor(t, mm, 64));
      float mn = fmaxf(m_run[j], t);
      corr[j] = __expf(m_run[j] - mn);
      m_run[j] = mn;
    }
    float rs[4] = {0.f, 0.f, 0.f, 0.f};
    float pv[4][4];
#pragma unroll
    for (int ct = 0; ct < 4; ++ct)
#pragma unroll
      for (int j = 0; j < 4; ++j) {
        float e = __expf(sa[ct][j] - m_run[j]);
        pv[ct][j] = e;
        rs[j] += e;
      }
#pragma unroll
    for (int j = 0; j < 4; ++j) {
#pragma unroll
      for (int mm = 1; mm < 16; mm <<= 1) rs[j] += __shfl_xor(rs[j], mm, 64);
      l_run[j] = l_run[j] * corr[j] + rs[j];
    }
#pragma unroll
    for (int ct = 0; ct < 4; ++ct)
#pragma unroll
      for (int j = 0; j < 4; ++j) {
        int row = lg * 4 + j;
        int seg = ct * 2 + (l16 >> 3);
        *((u16*)((char*)Pl + w * 2048 + row * 128 + ((seg ^ (row & 7)) * 16)) + (l16 & 7)) = f2b(pv[ct][j]);
      }
#pragma unroll
    for (int dt = 0; dt < 4; ++dt)
#pragma unroll
      for (int j = 0; j < 4; ++j) o_acc[dt][j] *= corr[j];
#pragma unroll
    for (int dt = 0; dt < 4; ++dt) {
      int d = dt * 16 + l16;
#pragma unroll
      for (int kk = 0; kk < 2; ++kk) {
        v8s pa = *(const v8s*)((const char*)Pl + w * 2048 + l16 * 128 + (((kk * 4 + lg) ^ (l16 & 7)) * 16));
        v8s vb2 = *(const v8s*)((const char*)Vt[buf] + d * 128 + (((kk * 4 + lg) ^ (d & 7)) * 16));
        o_acc[dt] = mfma16(pa, vb2, o_acc[dt]);
      }
    }
  };

  // prologue: stage first tile
  int jb_cur = __builtin_ctz(uni);
  unsigned rem = uni & (uni - 1);
  uint4 vc0, vc1;
  v_issue(jb_cur, vc0, vc1);
  k_stage(0, jb_cur);
  v_write(0, vc0, vc1);
  int buf = 0;
  while (jb_cur >= 0) {
    int jb_next = -1;
    if (rem) { jb_next = __builtin_ctz(rem); rem &= rem - 1; }
    __syncthreads();                       // tile (jb_cur, buf) fully staged
    if (jb_next >= 0) { v_issue(jb_next, vc0, vc1); k_stage(buf ^ 1, jb_next); }
    // ---- compute on (jb_cur, buf) ----
    v4f sa[4] = {};
#pragma unroll
    for (int ct = 0; ct < 4; ++ct) {
      int key = ct * 16 + l16;
#pragma unroll
      for (int kk = 0; kk < 2; ++kk) {
        v8s bk = *(const v8s*)((const char*)Kb[buf] + key * 128 + (((kk * 4 + lg) ^ (key & 7)) * 16));
        sa[ct] = mfma16(aq[kk], bk, sa[ct]);
      }
    }
#pragma unroll
    for (int ct = 0; ct < 4; ++ct)
#pragma unroll
      for (int j = 0; j < 4; ++j) sa[ct][j] *= 0.125f;
    const bool inF = (mword >> jb_cur) & 1u;
    const bool inS = (jb_cur == qb) || (jb_cur + 1 == qb);
    if (inF) upd(sa, mF, lF, oF, buf);
    if (inS) {
      v4f sb[4];
#pragma unroll
      for (int ct = 0; ct < 4; ++ct) sb[ct] = sa[ct];
      if (jb_cur == qb) {
#pragma unroll
        for (int ct = 0; ct < 4; ++ct) {
          int key = ct * 16 + l16;
#pragma unroll
          for (int j = 0; j < 4; ++j) {
            int qp = w * 16 + lg * 4 + j;
            if (key > qp) sb[ct][j] = -1e30f;
          }
        }
      }
      upd(sb, mS, lS, oS, buf);
    }
    // late V write for next tile (T14: hides HBM latency under compute)
    if (jb_next >= 0) v_write(buf ^ 1, vc0, vc1);
    jb_cur = jb_next;
    buf ^= 1;
  }
#pragma unroll
  for (int dt = 0; dt < 4; ++dt)
#pragma unroll
    for (int j = 0; j < 4; ++j) {
      int row = lg * 4 + j;
      int t = qb * 64 + w * 16 + row;
      int d = dt * 16 + l16;
      size_t idx = (size_t)t * kHID + h * 64 + d;
      float add = strat[t * 48 + h * 3 + 0] * (oS[dt][j] / lS[j]) +
                  strat[t * 48 + h * 3 + 2] * (oF[dt][j] / lF[j]);
      merged[idx] = f2b(b2f(merged[idx]) + add);
    }
}

// ==== output projection: out(T,HID) fp32 = merged(bf16) @ WotH^T, bn-colocated swizzle ====
__global__ __launch_bounds__(256) void gemm_out(const u16* __restrict__ A, const u16* __restrict__ Bt,
                                                float* __restrict__ Cf) {
  __shared__ u16 As[128 * 64], Bs[64 * 64];
  const int b = blockIdx.x;
  const int g = (b & 7) * 32 + (b >> 3);
  const int bn = (g >> 4) * 64;
  const int bm = (g & 15) * 128;
  const int tid = threadIdx.x, w = tid >> 6, lane = tid & 63;
  const int lg = lane >> 4, l16 = lane & 15;
  const int K = kHID;
  v4f acc[2][4] = {};
  for (int k0 = 0; k0 < K; k0 += 64) {
    __syncthreads();
#pragma unroll
    for (int p = 0; p < 4; ++p) {
      int s = tid + p * 256, row = s >> 3, sf = (s & 7) ^ (row & 7);
      gl_lds16(A + (size_t)(bm + row) * K + k0 + sf * 8, (char*)As + s * 16);
    }
#pragma unroll
    for (int p = 0; p < 2; ++p) {
      int s = tid + p * 256, row = s >> 3, sf = (s & 7) ^ (row & 7);
      gl_lds16(Bt + (size_t)(bn + row) * K + k0 + sf * 8, (char*)Bs + s * 16);
    }
    __syncthreads();
    v8s a[2][2], bfr[4][2];
#pragma unroll
    for (int i = 0; i < 2; ++i)
#pragma unroll
      for (int kk = 0; kk < 2; ++kk) {
        int row = w * 32 + i * 16 + l16;
        a[i][kk] = *(const v8s*)((const char*)As + row * 128 + (((kk * 4 + lg) ^ (row & 7)) * 16));
      }
#pragma unroll
    for (int j = 0; j < 4; ++j)
#pragma unroll
      for (int kk = 0; kk < 2; ++kk) {
        int col = j * 16 + l16;
        bfr[j][kk] = *(const v8s*)((const char*)Bs + col * 128 + (((kk * 4 + lg) ^ (col & 7)) * 16));
      }
#pragma unroll
    for (int i = 0; i < 2; ++i)
#pragma unroll
      for (int j = 0; j < 4; ++j) {
        acc[i][j] = mfma16(a[i][0], bfr[j][0], acc[i][j]);
        acc[i][j] = mfma16(a[i][1], bfr[j][1], acc[i][j]);
      }
  }
#pragma unroll
  for (int i = 0; i < 2; ++i)
#pragma unroll
    for (int j = 0; j < 4; ++j)
#pragma unroll
      for (int r = 0; r < 4; ++r) {
        int row = bm + w * 32 + i * 16 + lg * 4 + r;
        int col = bn + j * 16 + l16;
        Cf[(size_t)row * kHID + col] = acc[i][j][r];
      }
}

// ---------------- launch ----------------
extern "C" void kernel_launch(void* const* d_in, const int* in_sizes, int n_in,
                              void* d_out, int out_size, void* d_ws, size_t ws_size,
                              hipStream_t stream) {
  const float* x      = (const float*)d_in[0];
  const float* Wq     = (const float*)d_in[1];
  const float* Wk     = (const float*)d_in[2];
  const float* Wv     = (const float*)d_in[3];
  const float* Wo     = (const float*)d_in[4];
  const float* Wc     = (const float*)d_in[5];
  const float* bc     = (const float*)d_in[6];
  const float* kscale = (const float*)d_in[7];
  const float* kbias  = (const float*)d_in[8];
  const float* Wsp    = (const float*)d_in[9];
  const float* bsp    = (const float*)d_in[10];
  float* out = (float*)d_out;
  char* W = (char*)d_ws;

  u16* qh     = (u16*)(W + 0 * MB);
  u16* kbf    = (u16*)(W + 8 * MB);
  u16* vbf    = (u16*)(W + 16 * MB);
  u16* merged = (u16*)(W + 20 * MB);
  u16* xh     = (u16*)(W + 24 * MB);
  u16* WqtH   = (u16*)(W + 32 * MB);
  u16* WktH   = (u16*)(W + 36 * MB);
  u16* WvtH   = (u16*)(W + 40 * MB);
  u16* WotH   = (u16*)(W + 42 * MB);
  u16* WctH   = (u16*)(W + 44 * MB);
  u16* WctL   = (u16*)(W + 44 * MB + 512 * 1024);
  u16* Wst    = (u16*)(W + 45 * MB);          // 256 KB (padded 128x1024)
  float* strat= (float*)(W + 46 * MB);
  float* Pk   = (float*)(W + 47 * MB);
  float* Pv   = (float*)(W + 48 * MB);
  u16* kchb   = (u16*)(W + 49 * MB);
  u16* kclb   = (u16*)(W + 49 * MB + 64 * 1024);
  u16* vctb   = (u16*)(W + 49 * MB + 128 * 1024);
  unsigned* maskb = (unsigned*)(W + 49 * MB + 192 * 1024);
  float* krb  = (float*)(W + 49 * MB + 196 * 1024);
  float* neb  = (float*)(W + 49 * MB + 200 * 1024);
  int*   dkb  = (int*)(W + 49 * MB + 204 * 1024);

  dim3 b256(256);
  // 1: all input prep
  prep_kernel<<<5888, b256, 0, stream>>>(x, Wq, Wk, Wv, Wo, Wc, Wsp,
                                         xh, WqtH, WktH, WvtH, WotH, WctH, WctL, Wst);
  // 2: Q,K,V,strat projections (BM=64 BN=128, 800 blocks)
  proj_gemm<<<800, b256, 0, stream>>>(xh, WktH, WqtH, WvtH, Wst,
                                      bsp, kbf, qh, vbf, strat);
  // 3-4: compress MLP + reduce+GELU
  cgemm_fused<<<dim3(1, 8, 16), b256, 0, stream>>>(kbf, vbf, WctH, WctL, Pk, Pv);
  creduce_kernel<<<256, b256, 0, stream>>>(Pk, Pv, bc, kchb, kclb, vctb);
  // 5: importance + comp attention + block selection
  impsel_mfma<<<dim3(32, kH), b256, 0, stream>>>(qh, kchb, kclb, vctb, strat,
                                                 kscale, kbias, maskb, krb, neb, dkb, merged);
  // 6: scalar outputs
  finalize_kernel<<<1, 512, 0, stream>>>(dkb, krb, neb, out);
  // 7: fine + sliding attention (double-buffered, RMW merged)
  fineslide_mfma<<<512, b256, 0, stream>>>(qh, kbf, vbf, strat, maskb, merged);
  // 8: output projection
  gemm_out<<<256, b256, 0, stream>>>(merged, WotH, out);
}

// Round 10
// 93.906 us; speedup vs baseline: 10.9567x; 1.0245x over previous
//
#include <hip/hip_runtime.h>
#include <math.h>
#include <stdint.h>

typedef unsigned short u16;
typedef short v8s __attribute__((ext_vector_type(8)));
typedef float v4f __attribute__((ext_vector_type(4)));

constexpr int kT   = 2048;
constexpr int kHID = 1024;
constexpr int kH   = 16;
constexpr int kNB  = 32;
constexpr size_t MB = 1ull << 20;

__device__ __forceinline__ float b2f(u16 u) { unsigned x = ((unsigned)u) << 16; return __uint_as_float(x); }
__device__ __forceinline__ u16 f2b(float f) {
  unsigned x = __float_as_uint(f);
  x += 0x7FFFu + ((x >> 16) & 1u);
  return (u16)(x >> 16);
}
__device__ __forceinline__ v4f mfma16(v8s a, v8s b, v4f c) {
  return __builtin_amdgcn_mfma_f32_16x16x32_bf16(a, b, c, 0, 0, 0);
}
__device__ __forceinline__ void gl_lds16(const void* g, void* l) {
  __builtin_amdgcn_global_load_lds((const __attribute__((address_space(1))) uint32_t*)g,
                                   (__attribute__((address_space(3))) uint32_t*)l, 16, 0, 0);
}

// ==== fused prep: x->bf16, Wq/Wk/Wv/Wo transposes, Wc transpose hi/lo, Ws pad(128) ====
__global__ __launch_bounds__(256) void prep_kernel(
    const float* __restrict__ x, const float* __restrict__ Wq, const float* __restrict__ Wk,
    const float* __restrict__ Wv, const float* __restrict__ Wo, const float* __restrict__ Wc,
    const float* __restrict__ Wsp,
    u16* __restrict__ xh,
    u16* __restrict__ WqtH, u16* __restrict__ WktH,
    u16* __restrict__ WvtH, u16* __restrict__ WotH, u16* __restrict__ WctH, u16* __restrict__ WctL,
    u16* __restrict__ Wst) {
  __shared__ float tbuf[32][33];
  int bid = blockIdx.x;
  const int tid = threadIdx.x;
  if (bid < 1024) {                        // x -> bf16: 8 elems/thread
    int i = bid * 2048 + tid * 8;
    float4 a = *(const float4*)(x + i), b = *(const float4*)(x + i + 4);
    float tv[8] = {a.x, a.y, a.z, a.w, b.x, b.y, b.z, b.w};
    union { u16 s[8]; uint4 u; } hs;
#pragma unroll
    for (int e = 0; e < 8; ++e) hs.s[e] = f2b(tv[e]);
    *(uint4*)(xh + i) = hs.u;
    return;
  }
  bid -= 1024;
  const float* W; u16* Hh; u16* Ll; int Kd, Nd, bx, by;
  if (bid < 4096) {                        // 1024x1024 weight transposes
    int wsel = bid >> 10, sub = bid & 1023;
    W  = wsel == 0 ? Wq : wsel == 1 ? Wk : wsel == 2 ? Wv : Wo;
    Hh = wsel == 0 ? WqtH : wsel == 1 ? WktH : wsel == 2 ? WvtH : WotH;
    Ll = nullptr;
    Kd = 1024; Nd = 1024;
    bx = (sub & 31) * 32; by = (sub >> 5) * 32;
  } else if (bid < 4096 + 256) {           // Wc (4096x64), hi/lo
    int sub = bid - 4096;
    W = Wc; Hh = WctH; Ll = WctL;
    Kd = 4096; Nd = 64;
    bx = (sub & 1) * 32; by = (sub >> 1) * 32;
  } else {                                 // Wst pad: 128x1024
    int i = (bid - 4096 - 256) * 256 + tid;
    int n = i >> 10, k2 = i & 1023;
    float v = (n < 48) ? Wsp[(size_t)k2 * 48 + n] : 0.f;
    Wst[(size_t)n * 1024 + k2] = f2b(v);
    return;
  }
  const int lx = tid & 31, ly = tid >> 5;
  for (int i2 = ly; i2 < 32; i2 += 8) tbuf[i2][lx] = W[(size_t)(by + i2) * Nd + bx + lx];
  __syncthreads();
  for (int i2 = ly; i2 < 32; i2 += 8) {
    float xv = tbuf[lx][i2];
    size_t idx = (size_t)(bx + i2) * Kd + by + lx;
    u16 h = f2b(xv);
    Hh[idx] = h;
    if (Ll) Ll[idx] = f2b(xv - b2f(h));
  }
}

// ==== unified projection GEMM, single-combo bf16, BM=64 BN=128 BK=64 ====
__global__ __launch_bounds__(256) void proj_gemm(const u16* __restrict__ xh,
                                                 const u16* __restrict__ WkH, const u16* __restrict__ WqH,
                                                 const u16* __restrict__ WvH, const u16* __restrict__ Wst,
                                                 const float* __restrict__ bsp,
                                                 u16* __restrict__ kbf, u16* __restrict__ qh,
                                                 u16* __restrict__ vbf, float* __restrict__ strat) {
  __shared__ u16 AsH[64 * 64], BsH[128 * 64];   // 24 KB
  const int b = blockIdx.x;                      // 800 blocks
  const int slot = (b & 7) * 100 + (b >> 3);     // bijective [0,800)
  const int panel = slot >> 5, bmi = slot & 31;
  int z, bni;
  if (panel < 8)       { z = 0; bni = panel; }
  else if (panel < 16) { z = 1; bni = panel - 8; }
  else if (panel < 24) { z = 2; bni = panel - 16; }
  else                 { z = 3; bni = 0; }
  const int bm = bmi * 64, bn = bni * 128;
  const u16* Bh = (z == 0) ? WkH : (z == 1) ? WqH : (z == 2) ? WvH : Wst;
  const int tid = threadIdx.x, w = tid >> 6, lane = tid & 63;
  const int lg = lane >> 4, l16 = lane & 15;
  const int wr = w >> 1, wc = w & 1;
  v4f acc[2][4] = {};
  for (int k0 = 0; k0 < kHID; k0 += 64) {
    __syncthreads();
#pragma unroll
    for (int p = 0; p < 2; ++p) {
      int s = tid + p * 256, row = s >> 3, sf = (s & 7) ^ (row & 7);
      gl_lds16(xh + (size_t)(bm + row) * kHID + k0 + sf * 8, (char*)AsH + s * 16);
    }
#pragma unroll
    for (int p = 0; p < 4; ++p) {
      int s = tid + p * 256, row = s >> 3, sf = (s & 7) ^ (row & 7);
      gl_lds16(Bh + (size_t)(bn + row) * kHID + k0 + sf * 8, (char*)BsH + s * 16);
    }
    __syncthreads();
#pragma unroll
    for (int kk = 0; kk < 2; ++kk) {
      v8s bh4[4];
#pragma unroll
      for (int j = 0; j < 4; ++j) {
        int col = wc * 64 + j * 16 + l16;
        bh4[j] = *(const v8s*)((const char*)BsH + col * 128 + (((kk * 4 + lg) ^ (col & 7)) * 16));
      }
#pragma unroll
      for (int i = 0; i < 2; ++i) {
        int row = wr * 32 + i * 16 + l16;
        v8s ah = *(const v8s*)((const char*)AsH + row * 128 + (((kk * 4 + lg) ^ (row & 7)) * 16));
#pragma unroll
        for (int j = 0; j < 4; ++j) acc[i][j] = mfma16(ah, bh4[j], acc[i][j]);
      }
    }
  }
#pragma unroll
  for (int i = 0; i < 2; ++i)
#pragma unroll
    for (int j = 0; j < 4; ++j)
#pragma unroll
      for (int r = 0; r < 4; ++r) {
        int row = bm + wr * 32 + i * 16 + lg * 4 + r;
        int col = bn + wc * 64 + j * 16 + l16;
        float val = acc[i][j][r];
        if (z == 3) {
          if (col < 48) strat[(size_t)row * 48 + col] = 1.f / (1.f + expf(-(val + bsp[col])));
        } else {
          u16 hh = f2b(val);
          size_t idx = (size_t)row * kHID + col;
          if (z == 0) kbf[idx] = hh;
          else if (z == 1) qh[idx] = hh;
          else vbf[idx] = hh;
        }
      }
}

// ==== compress GEMM: K-path 2-combo (k·WcH + k·WcL), V-path single; split-K partials ====
__global__ __launch_bounds__(256) void cgemm_fused(const u16* __restrict__ kbf,
                                                   const u16* __restrict__ vbf,
                                                   const u16* __restrict__ WcH, const u16* __restrict__ WcL,
                                                   float* __restrict__ Pk, float* __restrict__ Pv) {
  __shared__ u16 AsH[64 * 64], BsH[64 * 64], BsL[64 * 64];   // 24 KB
  const int bm = blockIdx.y * 64;
  const int isK = (blockIdx.z < 8);
  const int ks = isK ? blockIdx.z : blockIdx.z - 8;
  const u16* Asrc = isK ? kbf : vbf;
  float* P = isK ? Pk : Pv;
  const int tid = threadIdx.x;
  const int w = tid >> 6, lane = tid & 63;
  const int lg = lane >> 4, l16 = lane & 15;
  const int wr = w >> 1, wc = w & 1;
  v4f acc[2][2] = {};
  for (int k0 = ks * 512; k0 < ks * 512 + 512; k0 += 64) {
    __syncthreads();
#pragma unroll
    for (int ss = 0; ss < 2; ++ss) {
      int s = tid + ss * 256, row = s >> 3, sf = (s & 7) ^ (row & 7);
      int r = bm + row;                              // (h*32+nb)
      size_t abase = ((size_t)((r & 31) * 64 + (k0 >> 6))) * kHID + (r >> 5) * 64 + sf * 8;
      gl_lds16(Asrc + abase, (char*)AsH + s * 16);
      gl_lds16(WcH + (size_t)row * 4096 + k0 + sf * 8, (char*)BsH + s * 16);
      if (isK) gl_lds16(WcL + (size_t)row * 4096 + k0 + sf * 8, (char*)BsL + s * 16);
    }
    __syncthreads();
    v8s ah[2][2], bh[2][2];
#pragma unroll
    for (int i = 0; i < 2; ++i)
#pragma unroll
      for (int kk = 0; kk < 2; ++kk) {
        int row = wr * 32 + i * 16 + l16;
        ah[i][kk] = *(const v8s*)((const char*)AsH + row * 128 + (((kk * 4 + lg) ^ (row & 7)) * 16));
        int col = wc * 32 + i * 16 + l16;
        bh[i][kk] = *(const v8s*)((const char*)BsH + col * 128 + (((kk * 4 + lg) ^ (col & 7)) * 16));
      }
#pragma unroll
    for (int i = 0; i < 2; ++i)
#pragma unroll
      for (int j = 0; j < 2; ++j) {
        acc[i][j] = mfma16(ah[i][0], bh[j][0], acc[i][j]);
        acc[i][j] = mfma16(ah[i][1], bh[j][1], acc[i][j]);
      }
    if (isK) {
      v8s bl[2][2];
#pragma unroll
      for (int i = 0; i < 2; ++i)
#pragma unroll
        for (int kk = 0; kk < 2; ++kk) {
          int col = wc * 32 + i * 16 + l16;
          bl[i][kk] = *(const v8s*)((const char*)BsL + col * 128 + (((kk * 4 + lg) ^ (col & 7)) * 16));
        }
#pragma unroll
      for (int i = 0; i < 2; ++i)
#pragma unroll
        for (int j = 0; j < 2; ++j) {
          acc[i][j] = mfma16(ah[i][0], bl[j][0], acc[i][j]);
          acc[i][j] = mfma16(ah[i][1], bl[j][1], acc[i][j]);
        }
    }
  }
#pragma unroll
  for (int i = 0; i < 2; ++i)
#pragma unroll
    for (int j = 0; j < 2; ++j)
#pragma unroll
      for (int r = 0; r < 4; ++r) {
        int row = bm + wr * 32 + i * 16 + lg * 4 + r;
        int col = wc * 32 + j * 16 + l16;
        P[(size_t)ks * 32768 + (size_t)row * 64 + col] = acc[i][j][r];
      }
}

// ==== importance + comp attention + block selection; folds split-K reduce+GELU ====
__global__ __launch_bounds__(256) void impsel_mfma(const u16* __restrict__ qh,
                                                   const float* __restrict__ Pk,
                                                   const float* __restrict__ Pv,
                                                   const float* __restrict__ bc,
                                                   const float* __restrict__ strat,
                                                   const float* __restrict__ kscale_p,
                                                   const float* __restrict__ kbias_p,
                                                   unsigned* __restrict__ maskb,
                                                   float* __restrict__ krb,
                                                   float* __restrict__ neb,
                                                   int* __restrict__ dkb,
                                                   u16* __restrict__ merged) {
  __shared__ u16 KCH[32 * 64], KCL[32 * 64], VCT[64 * 32];
  __shared__ u16 Pl[4][16 * 32];
  __shared__ float red[4][32];
  const int tt = blockIdx.x, h = blockIdx.y;
  const int tid = threadIdx.x, w = tid >> 6, lane = tid & 63;
  const int lg = lane >> 4, l16 = lane & 15;
  // ---- phase 0: reduce split-K partials + bias + exact-erf GELU into LDS ----
  {
    int nb = tid >> 3, seg = tid & 7;
    // kc -> hi/lo, swizzled rows [nb][64]
    {
      const float* base = Pk + ((size_t)(h * 32 + nb) * 64 + seg * 8);
      float v[8] = {};
#pragma unroll
      for (int ks = 0; ks < 8; ++ks) {
        const float* p = base + (size_t)ks * 32768;
        float4 a = *(const float4*)p, bq = *(const float4*)(p + 4);
        v[0] += a.x; v[1] += a.y; v[2] += a.z; v[3] += a.w;
        v[4] += bq.x; v[5] += bq.y; v[6] += bq.z; v[7] += bq.w;
      }
      v8s hi, lo;
#pragma unroll
      for (int e = 0; e < 8; ++e) {
        float s = v[e] + bc[seg * 8 + e];
        float g = 0.5f * s * (1.f + erff(s * 0.70710678118654752f));
        u16 hh = f2b(g);
        hi[e] = (short)hh;
        lo[e] = (short)f2b(g - b2f(hh));
      }
      *(v8s*)((char*)KCH + nb * 128 + ((seg ^ (nb & 7)) * 16)) = hi;
      *(v8s*)((char*)KCL + nb * 128 + ((seg ^ (nb & 7)) * 16)) = lo;
    }
    // vc -> transposed [d][nb], chunk-swizzled
    {
      const float* base = Pv + ((size_t)(h * 32 + nb) * 64 + seg * 8);
      float v[8] = {};
#pragma unroll
      for (int ks = 0; ks < 8; ++ks) {
        const float* p = base + (size_t)ks * 32768;
        float4 a = *(const float4*)p, bq = *(const float4*)(p + 4);
        v[0] += a.x; v[1] += a.y; v[2] += a.z; v[3] += a.w;
        v[4] += bq.x; v[5] += bq.y; v[6] += bq.z; v[7] += bq.w;
      }
#pragma unroll
      for (int e = 0; e < 8; ++e) {
        int d = seg * 8 + e;
        float s = v[e] + bc[d];
        float g = 0.5f * s * (1.f + erff(s * 0.70710678118654752f));
        *((u16*)((char*)VCT + d * 64 + (((nb >> 3) ^ (d & 3)) * 16) + (nb & 7) * 2)) = f2b(g);
      }
    }
  }
  __syncthreads();
  // ---- phase 1: QK^T (Q bf16 x kc 2-combo hi/lo) ----
  const size_t qoff = (size_t)(tt * 64 + w * 16 + l16) * kHID + h * 64;
  v8s ah[2];
  ah[0] = *(const v8s*)(qh + qoff + lg * 8);
  ah[1] = *(const v8s*)(qh + qoff + 32 + lg * 8);
  v4f sa[2] = {};
#pragma unroll
  for (int ct = 0; ct < 2; ++ct) {
    int col = ct * 16 + l16;
#pragma unroll
    for (int kk = 0; kk < 2; ++kk) {
      int bo = col * 128 + (((kk * 4 + lg) ^ (col & 7)) * 16);
      v8s bh = *(const v8s*)((const char*)KCH + bo);
      v8s bl = *(const v8s*)((const char*)KCL + bo);
      sa[ct] = mfma16(ah[kk], bh, sa[ct]);
      sa[ct] = mfma16(ah[kk], bl, sa[ct]);
    }
  }
#pragma unroll
  for (int ct = 0; ct < 2; ++ct)
#pragma unroll
    for (int j = 0; j < 4; ++j) sa[ct][j] *= 0.125f;
  // block-score partial
#pragma unroll
  for (int ct = 0; ct < 2; ++ct) {
    float v = sa[ct][0] + sa[ct][1] + sa[ct][2] + sa[ct][3];
    v += __shfl_xor(v, 16, 64);
    v += __shfl_xor(v, 32, 64);
    if (lg == 0) red[w][ct * 16 + l16] = v;
  }
  // comp-attention softmax (per-wave)
  float linv[4];
#pragma unroll
  for (int j = 0; j < 4; ++j) {
    float m = fmaxf(sa[0][j], sa[1][j]);
#pragma unroll
    for (int mm = 1; mm < 16; mm <<= 1) m = fmaxf(m, __shfl_xor(m, mm, 64));
    float e0 = __expf(sa[0][j] - m), e1 = __expf(sa[1][j] - m);
    float s = e0 + e1;
#pragma unroll
    for (int mm = 1; mm < 16; mm <<= 1) s += __shfl_xor(s, mm, 64);
    linv[j] = 1.f / s;
    int row = lg * 4 + j;
    Pl[w][row * 32 + l16] = f2b(e0);
    Pl[w][row * 32 + 16 + l16] = f2b(e1);
  }
  v8s pa = *(const v8s*)(&Pl[w][l16 * 32 + lg * 8]);
  v4f o[4] = {};
#pragma unroll
  for (int dt = 0; dt < 4; ++dt) {
    int d = dt * 16 + l16;
    v8s b = *(const v8s*)((const char*)VCT + d * 64 + ((lg ^ (d & 3)) * 16));
    o[dt] = mfma16(pa, b, o[dt]);
  }
#pragma unroll
  for (int dt = 0; dt < 4; ++dt)
#pragma unroll
    for (int j = 0; j < 4; ++j) {
      int t = tt * 64 + w * 16 + lg * 4 + j;
      int d = dt * 16 + l16;
      size_t mi = (size_t)t * kHID + h * 64 + d;
      merged[mi] = f2b(strat[t * 48 + h * 3 + 1] * (o[dt][j] * linv[j]));
    }
  __syncthreads();
  // block selection by wave 0
  if (w == 0) {
    const int j = lane & 31;
    float bsj = (red[0][j] + red[1][j] + red[2][j] + red[3][j]) * (1.f / 64.f);
    float mx = bsj;
#pragma unroll
    for (int m = 1; m < 32; m <<= 1) mx = fmaxf(mx, __shfl_xor(mx, m, 64));
    float e = expf(bsj - mx);
    float lsum = e;
#pragma unroll
    for (int m = 1; m < 32; m <<= 1) lsum += __shfl_xor(lsum, m, 64);
    float p = e / lsum;
    float ent = p * logf(p + 1e-9f);
#pragma unroll
    for (int m = 1; m < 32; m <<= 1) ent += __shfl_xor(ent, m, 64);
    ent = -ent;
    float ne = ent / (logf(32.f) + 1e-9f);
    float kr = 1.f / (1.f + expf(-(kscale_p[0] * ne + kbias_p[0])));
    int dk = (int)fminf(fmaxf(8.f * kr, 1.f), 8.f);
    unsigned mword = 1u << tt;
    int taken = 0;
    for (int r = 0; r < dk; ++r) {
      float v2 = taken ? -3.4e38f : bsj;
      int idx2 = j;
#pragma unroll
      for (int m = 1; m < 32; m <<= 1) {
        float ov = __shfl_xor(v2, m, 64);
        int oi = __shfl_xor(idx2, m, 64);
        if (ov > v2 || (ov == v2 && oi < idx2)) { v2 = ov; idx2 = oi; }
      }
      mword |= (1u << idx2);
      if (j == idx2) taken = 1;
    }
    if (lane == 0) {
      maskb[h * kNB + tt] = mword;
      krb[h * kNB + tt] = kr;
      neb[h * kNB + tt] = ne;
      dkb[h * kNB + tt] = dk;
    }
  }
}

// ------- merged fine + sliding attention, double-buffered; block 0 also does finalize -------
__global__ __launch_bounds__(256) void fineslide_mfma(const u16* __restrict__ qh,
                                                      const u16* __restrict__ kb_,
                                                      const u16* __restrict__ vb_,
                                                      const float* __restrict__ strat,
                                                      const unsigned* __restrict__ maskb,
                                                      const float* __restrict__ krb,
                                                      const float* __restrict__ neb,
                                                      const int* __restrict__ dkb,
                                                      float* __restrict__ outp,
                                                      u16* __restrict__ merged) {
  __shared__ u16 Kb[2][64 * 64];
  __shared__ u16 Vt[2][64 * 64];
  __shared__ u16 Pl[4][16 * 64];
  const int b = blockIdx.x;
  const int xcd = b & 7, slot = b >> 3;
  const int h = xcd + 8 * (slot >> 5);
  const int qb = slot & 31;
  const unsigned mword = maskb[h * kNB + qb];
  unsigned uni = mword | (1u << qb);
  if (qb > 0) uni |= 1u << (qb - 1);
  const int tid = threadIdx.x, w = tid >> 6, lane = tid & 63;
  const int lg = lane >> 4, l16 = lane & 15;
  // finalize (scalar outputs) on block 0, wave 0
  if (b == 0 && w == 0) {
    float s1 = 0.f, s2 = 0.f, s3 = 0.f;
    for (int i = lane; i < 512; i += 64) {
      float fdk = (float)dkb[i], kr = krb[i], ne = neb[i];
      float d2 = kr - ne;
      s1 += fdk; s2 += d2 * d2; s3 += kr;
    }
#pragma unroll
    for (int m = 1; m < 64; m <<= 1) {
      s1 += __shfl_xor(s1, m, 64);
      s2 += __shfl_xor(s2, m, 64);
      s3 += __shfl_xor(s3, m, 64);
    }
    if (lane == 0) {
      outp[(size_t)kT * kHID + 0] = s1 * (1.f / 512.f);
      outp[(size_t)kT * kHID + 1] = 0.01f * (s2 * (1.f / 512.f)) + 0.01f * (s3 * (1.f / 512.f));
    }
  }
  v8s aq[2];
  {
    const u16* qrow = qh + (size_t)(qb * 64 + w * 16 + l16) * kHID + h * 64;
    aq[0] = *(const v8s*)(qrow + lg * 8);
    aq[1] = *(const v8s*)(qrow + 32 + lg * 8);
  }
  float mF[4], lF[4], mS[4], lS[4];
  v4f oF[4] = {}, oS[4] = {};
#pragma unroll
  for (int j = 0; j < 4; ++j) { mF[j] = -1e30f; lF[j] = 0.f; mS[j] = -1e30f; lS[j] = 0.f; }

  const int vkey = tid & 63, vd0 = (tid >> 6) * 16;

  auto k_stage = [&](int buf, int jb) {
#pragma unroll
    for (int ss = 0; ss < 2; ++ss) {
      int s = tid + ss * 256;
      int key = s >> 3, sf = (s & 7) ^ (key & 7);
      gl_lds16(kb_ + (size_t)(jb * 64 + key) * kHID + h * 64 + sf * 8, (char*)Kb[buf] + s * 16);
    }
  };
  auto v_issue = [&](int jb, uint4& c0, uint4& c1) {
    const u16* vsrc = vb_ + (size_t)(jb * 64 + vkey) * kHID + h * 64 + vd0;
    c0 = *(const uint4*)(vsrc);
    c1 = *(const uint4*)(vsrc + 8);
  };
  auto v_write = [&](int buf, uint4 c0, uint4 c1) {
    union { uint4 u[2]; u16 s[16]; } c;
    c.u[0] = c0; c.u[1] = c1;
#pragma unroll
    for (int i = 0; i < 16; ++i) {
      int d = vd0 + i;
      *((u16*)((char*)Vt[buf] + d * 128 + (((vkey >> 3) ^ (d & 7)) * 16)) + (vkey & 7)) = c.s[i];
    }
  };

  auto upd = [&](const v4f* sa, float* m_run, float* l_run, v4f* o_acc, int buf) {
    float corr[4];
#pragma unroll
    for (int j = 0; j < 4; ++j) {
      float t = fmaxf(fmaxf(sa[0][j], sa[1][j]), fmaxf(sa[2][j], sa[3][j]));
#pragma unroll
      for (int mm = 1; mm < 16; mm <<= 1) t = fmaxf(t, __shfl_xor(t, mm, 64));
      float mn = fmaxf(m_run[j], t);
      corr[j] = __expf(m_run[j] - mn);
      m_run[j] = mn;
    }
    float rs[4] = {0.f, 0.f, 0.f, 0.f};
    float pv[4][4];
#pragma unroll
    for (int ct = 0; ct < 4; ++ct)
#pragma unroll
      for (int j = 0; j < 4; ++j) {
        float e = __expf(sa[ct][j] - m_run[j]);
        pv[ct][j] = e;
        rs[j] += e;
      }
#pragma unroll
    for (int j = 0; j < 4; ++j) {
#pragma unroll
      for (int mm = 1; mm < 16; mm <<= 1) rs[j] += __shfl_xor(rs[j], mm, 64);
      l_run[j] = l_run[j] * corr[j] + rs[j];
    }
#pragma unroll
    for (int ct = 0; ct < 4; ++ct)
#pragma unroll
      for (int j = 0; j < 4; ++j) {
        int row = lg * 4 + j;
        int seg = ct * 2 + (l16 >> 3);
        *((u16*)((char*)Pl + w * 2048 + row * 128 + ((seg ^ (row & 7)) * 16)) + (l16 & 7)) = f2b(pv[ct][j]);
      }
#pragma unroll
    for (int dt = 0; dt < 4; ++dt)
#pragma unroll
      for (int j = 0; j < 4; ++j) o_acc[dt][j] *= corr[j];
#pragma unroll
    for (int dt = 0; dt < 4; ++dt) {
      int d = dt * 16 + l16;
#pragma unroll
      for (int kk = 0; kk < 2; ++kk) {
        v8s pa = *(const v8s*)((const char*)Pl + w * 2048 + l16 * 128 + (((kk * 4 + lg) ^ (l16 & 7)) * 16));
        v8s vb2 = *(const v8s*)((const char*)Vt[buf] + d * 128 + (((kk * 4 + lg) ^ (d & 7)) * 16));
        o_acc[dt] = mfma16(pa, vb2, o_acc[dt]);
      }
    }
  };

  // prologue: stage first tile
  int jb_cur = __builtin_ctz(uni);
  unsigned rem = uni & (uni - 1);
  uint4 vc0, vc1;
  v_issue(jb_cur, vc0, vc1);
  k_stage(0, jb_cur);
  v_write(0, vc0, vc1);
  int buf = 0;
  while (jb_cur >= 0) {
    int jb_next = -1;
    if (rem) { jb_next = __builtin_ctz(rem); rem &= rem - 1; }
    __syncthreads();                       // tile (jb_cur, buf) fully staged
    if (jb_next >= 0) { v_issue(jb_next, vc0, vc1); k_stage(buf ^ 1, jb_next); }
    v4f sa[4] = {};
#pragma unroll
    for (int ct = 0; ct < 4; ++ct) {
      int key = ct * 16 + l16;
#pragma unroll
      for (int kk = 0; kk < 2; ++kk) {
        v8s bk = *(const v8s*)((const char*)Kb[buf] + key * 128 + (((kk * 4 + lg) ^ (key & 7)) * 16));
        sa[ct] = mfma16(aq[kk], bk, sa[ct]);
      }
    }
#pragma unroll
    for (int ct = 0; ct < 4; ++ct)
#pragma unroll
      for (int j = 0; j < 4; ++j) sa[ct][j] *= 0.125f;
    const bool inF = (mword >> jb_cur) & 1u;
    const bool inS = (jb_cur == qb) || (jb_cur + 1 == qb);
    if (inF) upd(sa, mF, lF, oF, buf);
    if (inS) {
      v4f sb[4];
#pragma unroll
      for (int ct = 0; ct < 4; ++ct) sb[ct] = sa[ct];
      if (jb_cur == qb) {
#pragma unroll
        for (int ct = 0; ct < 4; ++ct) {
          int key = ct * 16 + l16;
#pragma unroll
          for (int j = 0; j < 4; ++j) {
            int qp = w * 16 + lg * 4 + j;
            if (key > qp) sb[ct][j] = -1e30f;
          }
        }
      }
      upd(sb, mS, lS, oS, buf);
    }
    if (jb_next >= 0) v_write(buf ^ 1, vc0, vc1);
    jb_cur = jb_next;
    buf ^= 1;
  }
#pragma unroll
  for (int dt = 0; dt < 4; ++dt)
#pragma unroll
    for (int j = 0; j < 4; ++j) {
      int row = lg * 4 + j;
      int t = qb * 64 + w * 16 + row;
      int d = dt * 16 + l16;
      size_t idx = (size_t)t * kHID + h * 64 + d;
      float add = strat[t * 48 + h * 3 + 0] * (oS[dt][j] / lS[j]) +
                  strat[t * 48 + h * 3 + 2] * (oF[dt][j] / lF[j]);
      merged[idx] = f2b(b2f(merged[idx]) + add);
    }
}

// ==== output projection: BM=64 BN=64, 512 blocks, bn-colocated swizzle ====
__global__ __launch_bounds__(256) void gemm_out(const u16* __restrict__ A, const u16* __restrict__ Bt,
                                                float* __restrict__ Cf) {
  __shared__ u16 As[64 * 64], Bs[64 * 64];   // 16 KB
  const int b = blockIdx.x;                   // 512 blocks
  const int g = (b & 7) * 64 + (b >> 3);      // bijective; 2 bn-panels per XCD
  const int bn = (g >> 5) * 64;
  const int bm = (g & 31) * 64;
  const int tid = threadIdx.x, w = tid >> 6, lane = tid & 63;
  const int lg = lane >> 4, l16 = lane & 15;
  v4f acc[4] = {};
  for (int k0 = 0; k0 < kHID; k0 += 64) {
    __syncthreads();
#pragma unroll
    for (int p = 0; p < 2; ++p) {
      int s = tid + p * 256, row = s >> 3, sf = (s & 7) ^ (row & 7);
      gl_lds16(A + (size_t)(bm + row) * kHID + k0 + sf * 8, (char*)As + s * 16);
      gl_lds16(Bt + (size_t)(bn + row) * kHID + k0 + sf * 8, (char*)Bs + s * 16);
    }
    __syncthreads();
#pragma unroll
    for (int kk = 0; kk < 2; ++kk) {
      int row = w * 16 + l16;
      v8s a = *(const v8s*)((const char*)As + row * 128 + (((kk * 4 + lg) ^ (row & 7)) * 16));
#pragma unroll
      for (int j = 0; j < 4; ++j) {
        int col = j * 16 + l16;
        v8s bb = *(const v8s*)((const char*)Bs + col * 128 + (((kk * 4 + lg) ^ (col & 7)) * 16));
        acc[j] = mfma16(a, bb, acc[j]);
      }
    }
  }
#pragma unroll
  for (int j = 0; j < 4; ++j)
#pragma unroll
    for (int r = 0; r < 4; ++r) {
      int row = bm + w * 16 + lg * 4 + r;
      int col = bn + j * 16 + l16;
      Cf[(size_t)row * kHID + col] = acc[j][r];
    }
}

// ---------------- launch ----------------
extern "C" void kernel_launch(void* const* d_in, const int* in_sizes, int n_in,
                              void* d_out, int out_size, void* d_ws, size_t ws_size,
                              hipStream_t stream) {
  const float* x      = (const float*)d_in[0];
  const float* Wq     = (const float*)d_in[1];
  const float* Wk     = (const float*)d_in[2];
  const float* Wv     = (const float*)d_in[3];
  const float* Wo     = (const float*)d_in[4];
  const float* Wc     = (const float*)d_in[5];
  const float* bc     = (const float*)d_in[6];
  const float* kscale = (const float*)d_in[7];
  const float* kbias  = (const float*)d_in[8];
  const float* Wsp    = (const float*)d_in[9];
  const float* bsp    = (const float*)d_in[10];
  float* out = (float*)d_out;
  char* W = (char*)d_ws;

  u16* qh     = (u16*)(W + 0 * MB);
  u16* kbf    = (u16*)(W + 8 * MB);
  u16* vbf    = (u16*)(W + 16 * MB);
  u16* merged = (u16*)(W + 20 * MB);
  u16* xh     = (u16*)(W + 24 * MB);
  u16* WqtH   = (u16*)(W + 32 * MB);
  u16* WktH   = (u16*)(W + 36 * MB);
  u16* WvtH   = (u16*)(W + 40 * MB);
  u16* WotH   = (u16*)(W + 42 * MB);
  u16* WctH   = (u16*)(W + 44 * MB);
  u16* WctL   = (u16*)(W + 44 * MB + 512 * 1024);
  u16* Wst    = (u16*)(W + 45 * MB);          // 256 KB (padded 128x1024)
  float* strat= (float*)(W + 46 * MB);
  float* Pk   = (float*)(W + 47 * MB);
  float* Pv   = (float*)(W + 48 * MB);
  unsigned* maskb = (unsigned*)(W + 49 * MB);
  float* krb  = (float*)(W + 49 * MB + 4 * 1024);
  float* neb  = (float*)(W + 49 * MB + 8 * 1024);
  int*   dkb  = (int*)(W + 49 * MB + 12 * 1024);

  dim3 b256(256);
  // 1: all input prep
  prep_kernel<<<5888, b256, 0, stream>>>(x, Wq, Wk, Wv, Wo, Wc, Wsp,
                                         xh, WqtH, WktH, WvtH, WotH, WctH, WctL, Wst);
  // 2: Q,K,V,strat projections
  proj_gemm<<<800, b256, 0, stream>>>(xh, WktH, WqtH, WvtH, Wst,
                                      bsp, kbf, qh, vbf, strat);
  // 3: compress MLP split-K partials
  cgemm_fused<<<dim3(1, 8, 16), b256, 0, stream>>>(kbf, vbf, WctH, WctL, Pk, Pv);
  // 4: reduce+GELU (folded) + importance + comp attention + block selection
  impsel_mfma<<<dim3(32, kH), b256, 0, stream>>>(qh, Pk, Pv, bc, strat,
                                                 kscale, kbias, maskb, krb, neb, dkb, merged);
  // 5: fine + sliding attention (dbuf) + finalize scalars
  fineslide_mfma<<<512, b256, 0, stream>>>(qh, kbf, vbf, strat, maskb,
                                           krb, neb, dkb, out, merged);
  // 6: output projection
  gemm_out<<<512, b256, 0, stream>>>(merged, WotH, out);
}